// Round 1
// 884.214 us; speedup vs baseline: 1.0405x; 1.0405x over previous
//
#include <hip/hip_runtime.h>
#include <cstdint>
#include <cmath>

// Problem constants (B=4, S=1024)
#define T_TOK 4096
#define H_DIM 1024
#define QKV_N 3072
#define S_LEN 1024
#define INTER_DIM 2048
#define MAXROWS 9216   // 2*T + 8*127 padding, rounded

typedef unsigned short u16;
using f32x4 = __attribute__((ext_vector_type(4))) float;
using h16x8 = __attribute__((ext_vector_type(8))) _Float16;
using h16x4 = __attribute__((ext_vector_type(4))) _Float16;
using i32x4 = __attribute__((ext_vector_type(4))) int;
using u16x4 = __attribute__((ext_vector_type(4))) u16;
using u16x8 = __attribute__((ext_vector_type(8))) u16;

__device__ __forceinline__ float bf2f(u16 u){ return __uint_as_float(((uint32_t)u)<<16); }
__device__ __forceinline__ u16 f2bf(float f){
  uint32_t x = __float_as_uint(f);
  uint32_t r = x + 0x7FFFu + ((x>>16)&1u);
  return (u16)(r>>16);
}
__device__ __forceinline__ f32x4 mfma16(h16x8 a, h16x8 b, f32x4 c){
  return __builtin_amdgcn_mfma_f32_16x16x32_f16(a,b,c,0,0,0);
}
__device__ __forceinline__ float rsqrt_acc(float v){
  float r = rsqrtf(v);
  r = r*(1.5f - 0.5f*v*r*r);
  r = r*(1.5f - 0.5f*v*r*r);
  return r;
}
// dual-dtype scalar input read
__device__ __forceinline__ float ldin(const void* p, size_t i, int is32){
  return is32 ? ((const float*)p)[i] : bf2f(((const u16*)p)[i]);
}
// swizzled k-slot for stride-40 B tiles (legacy path)
__device__ __forceinline__ int kslot_sw(int k, int noct){
  return (k&7) | (((k>>3) ^ (noct&3))<<3);
}
// async global->LDS, 16B per lane; lds base must be wave-uniform, lanes land at base+lane*16
__device__ __forceinline__ void gll16(const void* g, void* l){
  __builtin_amdgcn_global_load_lds(
      (const __attribute__((address_space(1))) void*)g,
      (__attribute__((address_space(3))) void*)l, 16, 0, 0);
}

// ---------------- dtype detection: fp32 exponent fields of N(0,1) data ----------------
__global__ void k_detect(const uint32_t* __restrict__ x, int* __restrict__ dflag){
  uint32_t u = x[threadIdx.x];
  int e = (u>>23)&0xFF;
  int ok = (e>=103 && e<=150);            // |f| in [2^-24, 2^23]
  unsigned long long m = __ballot(ok);
  if (threadIdx.x==0) *dflag = (__popcll(m) >= 48) ? 1 : 0;
}

// ---------------- vectorized transpose + cast to f16: src [R][C] -> dst [C][R] ------
// 64x64 tiles; conflict-free LDS (stride 65); 16B global loads/stores
__global__ __launch_bounds__(256) void k_trans2(const void* __restrict__ src,
    _Float16* __restrict__ dst, int R, int C, const int* __restrict__ df){
  const int is32 = *df;
  __shared__ _Float16 t[64][65];
  size_t bo = (size_t)blockIdx.z * R * C;
  int c0 = blockIdx.x<<6, r0 = blockIdx.y<<6;
  int ty = threadIdx.x>>3, tx = threadIdx.x&7;   // ty 0..31, tx 0..7
  #pragma unroll
  for (int rr=0; rr<2; rr++){
    int r = rr*32 + ty;
    size_t gi = bo + (size_t)(r0+r)*C + c0 + tx*8;
    _Float16 v[8];
    if (is32){
      f32x4 a0 = *(const f32x4*)&((const float*)src)[gi];
      f32x4 a1 = *(const f32x4*)&((const float*)src)[gi+4];
      #pragma unroll
      for (int i=0;i<4;i++){ v[i]=(_Float16)a0[i]; v[4+i]=(_Float16)a1[i]; }
    } else {
      u16x8 a = *(const u16x8*)&((const u16*)src)[gi];
      #pragma unroll
      for (int i=0;i<8;i++) v[i]=(_Float16)bf2f(a[i]);
    }
    #pragma unroll
    for (int i=0;i<8;i++) t[r][tx*8+i] = v[i];
  }
  __syncthreads();
  #pragma unroll
  for (int rr=0; rr<2; rr++){
    int n = rr*32 + ty;
    h16x8 v;
    #pragma unroll
    for (int i=0;i<8;i++) v[i] = t[tx*8+i][n];
    *(h16x8*)&dst[bo + (size_t)(c0+n)*R + r0 + tx*8] = v;
  }
}

// ---------------- mask all-zero check ----------------
__global__ __launch_bounds__(256) void k_maskchk(const void* __restrict__ m, int* __restrict__ flag,
                                                 const int* __restrict__ df){
  const int is32 = *df;
  int i = (blockIdx.x*256 + threadIdx.x)*4;
  int nz = 0;
  if (is32){
    f32x4 v = *(const f32x4*)&((const float*)m)[i];
    nz = (v[0]!=0.f)||(v[1]!=0.f)||(v[2]!=0.f)||(v[3]!=0.f);
  } else {
    u16x4 v = *(const u16x4*)&((const u16*)m)[i];
    nz = ((v[0]|v[1]|v[2]|v[3]) & 0x7FFF) != 0;
  }
  if (nz) atomicOr(flag, 1);
}

// ---------------- RMSNorm #1: x -> pre-split f16 hi/lo h ----------------
__global__ __launch_bounds__(256) void k_rms1(const void* __restrict__ x, const void* __restrict__ w,
                                              _Float16* __restrict__ hhi, _Float16* __restrict__ hlo,
                                              const int* __restrict__ df){
  const int is32 = *df;
  int t = blockIdx.x, tid = threadIdx.x;
  size_t base = (size_t)t*H_DIM + tid*4;
  float f[4];
  #pragma unroll
  for (int m=0;m<4;m++) f[m] = ldin(x, base+m, is32);
  float ss = f[0]*f[0] + f[1]*f[1] + f[2]*f[2] + f[3]*f[3];
  #pragma unroll
  for (int off=32; off>0; off>>=1) ss += __shfl_down(ss, off, 64);
  __shared__ float red[4];
  if ((tid & 63) == 0) red[tid>>6] = ss;
  __syncthreads();
  float rstd = rsqrt_acc((red[0]+red[1]+red[2]+red[3]) * (1.0f/H_DIM) + 1e-6f);
  h16x4 oh, ol;
  #pragma unroll
  for (int m=0;m<4;m++){
    float v = f[m]*rstd*ldin(w, tid*4+m, is32);
    _Float16 hh = (_Float16)v;
    oh[m] = hh;
    ol[m] = (_Float16)(v - (float)hh);
  }
  *(h16x4*)&hhi[base] = oh;
  *(h16x4*)&hlo[base] = ol;
}

// ---------------- high-precision GEMM: pre-split f16 hi/lo A, f16 B^T --------------
// EPI==0: write C as f16 hi/lo pair. EPI==1: fp32 C with residual add.
template<int EPI>
__global__ __launch_bounds__(256) void k_gemm_hl(const _Float16* __restrict__ Ah,
    const _Float16* __restrict__ Al, const _Float16* __restrict__ Bt,
    float* __restrict__ C, _Float16* __restrict__ Chi, _Float16* __restrict__ Clo,
    const void* __restrict__ res, int N, int K, const int* __restrict__ df){
  const int is32 = (EPI==1) ? *df : 0;
  __shared__ __align__(16) _Float16 AhS[128*32];
  __shared__ __align__(16) _Float16 AlS[128*32];
  __shared__ __align__(16) _Float16 Bs[128*32];
  int tid = threadIdx.x, lane = tid&63, wvx = tid>>6;
  int wr = wvx>>1, wc = wvx&1, quad = lane>>4, lrow = lane&15;
  int m0 = blockIdx.y<<7, n0 = blockIdx.x<<7;
  int ar = tid>>2, acg = (tid&3)*8;
  const _Float16* a0h = &Ah[(size_t)(m0+ar)*K + acg];
  const _Float16* a1h = &Ah[(size_t)(m0+64+ar)*K + acg];
  const _Float16* a0l = &Al[(size_t)(m0+ar)*K + acg];
  const _Float16* a1l = &Al[(size_t)(m0+64+ar)*K + acg];
  const _Float16* b0  = &Bt[(size_t)(n0+ar)*K + acg];
  const _Float16* b1  = &Bt[(size_t)(n0+64+ar)*K + acg];
  f32x4 acc[4][4] = {};
  for (int k0=0; k0<K; k0+=32){
    gll16(a0h + k0, &AhS[wvx*512]);
    gll16(a1h + k0, &AhS[2048 + wvx*512]);
    gll16(a0l + k0, &AlS[wvx*512]);
    gll16(a1l + k0, &AlS[2048 + wvx*512]);
    gll16(b0  + k0, &Bs[wvx*512]);
    gll16(b1  + k0, &Bs[2048 + wvx*512]);
    __syncthreads();
    h16x8 ah[4], al[4], bb[4];
    #pragma unroll
    for (int i=0;i<4;i++){
      ah[i] = *(const h16x8*)&AhS[(wr*64 + i*16 + lrow)*32 + quad*8];
      al[i] = *(const h16x8*)&AlS[(wr*64 + i*16 + lrow)*32 + quad*8];
    }
    #pragma unroll
    for (int j=0;j<4;j++) bb[j] = *(const h16x8*)&Bs[(wc*64 + j*16 + lrow)*32 + quad*8];
    #pragma unroll
    for (int i=0;i<4;i++)
      #pragma unroll
      for (int j=0;j<4;j++){
        acc[i][j] = mfma16(ah[i], bb[j], acc[i][j]);
        acc[i][j] = mfma16(al[i], bb[j], acc[i][j]);
      }
    __syncthreads();
  }
  #pragma unroll
  for (int i=0;i<4;i++)
    #pragma unroll
    for (int j=0;j<4;j++){
      int col = n0 + wc*64 + j*16 + lrow;
      #pragma unroll
      for (int r=0;r<4;r++){
        int row = m0 + wr*64 + i*16 + quad*4 + r;
        size_t idx = (size_t)row*N + col;
        float v = acc[i][j][r];
        if (EPI==1){
          v += ldin(res, idx, is32);
          C[idx] = v;
        } else {
          _Float16 hh = (_Float16)v;
          Chi[idx] = hh;
          Clo[idx] = (_Float16)(v - (float)hh);
        }
      }
    }
}

// ---------------- V^T prep: qkv hi/lo V-slice -> [bh][64 d][1024 keys] f16 hi/lo ----
__global__ __launch_bounds__(256) void k_vt(const _Float16* __restrict__ qh,
    const _Float16* __restrict__ ql, _Float16* __restrict__ vth, _Float16* __restrict__ vtl){
  __shared__ _Float16 th[64][72];
  __shared__ _Float16 tl[64][72];
  int bh = blockIdx.y;           // 0..63
  int b = bh>>4, h = bh&15;
  int key0 = blockIdx.x<<6;      // 16 tiles of 64 keys
  size_t tok0 = (size_t)b*S_LEN;
  int ty = threadIdx.x>>3, tx = threadIdx.x&7;  // ty 0..31, tx 0..7
  #pragma unroll
  for (int rr=0; rr<2; rr++){
    int r = rr*32 + ty;          // key within tile
    size_t gi = (tok0 + key0 + r)*(size_t)QKV_N + 2048 + h*64 + tx*8;
    h16x8 vh_ = *(const h16x8*)&qh[gi];
    h16x8 vl_ = *(const h16x8*)&ql[gi];
    #pragma unroll
    for (int i=0;i<8;i++){ th[r][tx*8+i] = vh_[i]; tl[r][tx*8+i] = vl_[i]; }
  }
  __syncthreads();
  size_t dbase = (size_t)bh*64*1024;
  #pragma unroll
  for (int rr=0; rr<2; rr++){
    int d = rr*32 + ty;
    h16x8 oh, ol;
    #pragma unroll
    for (int i=0;i<8;i++){ oh[i] = th[tx*8+i][d]; ol[i] = tl[tx*8+i][d]; }
    *(h16x8*)&vth[dbase + (size_t)d*1024 + key0 + tx*8] = oh;
    *(h16x8*)&vtl[dbase + (size_t)d*1024 + key0 + tx*8] = ol;
  }
}

// ---------------- flash attention v2: pre-split inputs, Q in regs, 32KB LDS --------
__global__ __launch_bounds__(256, 3) void k_attn(const _Float16* __restrict__ qkvh,
    const _Float16* __restrict__ qkvl, const _Float16* __restrict__ vth_g,
    const _Float16* __restrict__ vtl_g, const void* __restrict__ mask,
    const int* __restrict__ mflag, _Float16* __restrict__ ohi, _Float16* __restrict__ olo,
    const int* __restrict__ df){
  const int is32 = *df;
  __shared__ __align__(16) _Float16 pool[16384];   // 32 KB
  int qt = blockIdx.x, bh = blockIdx.y;
  int b = bh>>4, h = bh&15;
  int tid = threadIdx.x, lane = tid&63, wvx = tid>>6, quad = lane>>4, lrow = lane&15;
  size_t tok0 = (size_t)b*S_LEN;
  int q0 = qt<<7;
  // stage Q hi/lo (16KB+16KB) into pool, then pull fragments into registers
  {
    int r = tid>>2, cg = (tid&3)*8;
    #pragma unroll
    for (int p=0;p<2;p++)
      #pragma unroll
      for (int g=0;g<2;g++){
        size_t src = (tok0 + q0 + g*64 + r)*(size_t)QKV_N + h*64 + p*32 + cg;
        gll16(&qkvh[src], &pool[p*4096 + g*2048 + wvx*512]);
        gll16(&qkvl[src], &pool[8192 + p*4096 + g*2048 + wvx*512]);
      }
  }
  __syncthreads();
  h16x8 qfh[2][2], qfl[2][2];
  #pragma unroll
  for (int p=0;p<2;p++)
    #pragma unroll
    for (int i=0;i<2;i++){
      qfh[p][i] = *(const h16x8*)&pool[(p*128 + wvx*32 + i*16 + lrow)*32 + quad*8];
      qfl[p][i] = *(const h16x8*)&pool[8192 + (p*128 + wvx*32 + i*16 + lrow)*32 + quad*8];
    }
  // pool carve for main loop (after Q frags are in regs)
  _Float16* Khi = pool;            // [2][32][32]
  _Float16* Klo = pool + 2048;
  _Float16* Vth = pool + 4096;     // [64][32]
  _Float16* Vtl = pool + 6144;
  _Float16* Phi = pool + 8192;     // [128][32]
  _Float16* Plo = pool + 12288;
  int useMask = *mflag;
  float mrun[2][4], lrun[2][4];
  f32x4 oacc[2][4] = {};
  #pragma unroll
  for (int i=0;i<2;i++)
    #pragma unroll
    for (int r=0;r<4;r++){ mrun[i][r] = -INFINITY; lrun[i][r] = 0.f; }
  size_t vbase = (size_t)bh*64*1024;
  int kr = (tid>>2)&31, kp = tid>>7, kcg = (tid&3)*8;
  int vd = tid>>2;

  for (int kt=0; kt<32; kt++){
    int key0 = kt*32;
    __syncthreads();   // prior-iteration P/V reads done (and Q-frag reads at kt=0)
    {
      size_t ks = (tok0 + key0 + kr)*(size_t)QKV_N + 1024 + h*64 + kp*32 + kcg;
      gll16(&qkvh[ks], &Khi[wvx*512]);
      gll16(&qkvl[ks], &Klo[wvx*512]);
      size_t vs = vbase + (size_t)vd*1024 + key0 + (tid&3)*8;
      gll16(&vth_g[vs], &Vth[wvx*512]);
      gll16(&vtl_g[vs], &Vtl[wvx*512]);
    }
    __syncthreads();
    f32x4 sacc[2][2] = {};
    __builtin_amdgcn_s_setprio(1);
    #pragma unroll
    for (int p=0;p<2;p++){
      h16x8 kh[2], kl[2];
      #pragma unroll
      for (int j=0;j<2;j++){
        kh[j] = *(const h16x8*)&Khi[(p*32 + j*16 + lrow)*32 + quad*8];
        kl[j] = *(const h16x8*)&Klo[(p*32 + j*16 + lrow)*32 + quad*8];
      }
      #pragma unroll
      for (int i=0;i<2;i++)
        #pragma unroll
        for (int j=0;j<2;j++){
          sacc[i][j] = mfma16(qfh[p][i], kh[j], sacc[i][j]);
          sacc[i][j] = mfma16(qfh[p][i], kl[j], sacc[i][j]);
          sacc[i][j] = mfma16(qfl[p][i], kh[j], sacc[i][j]);
        }
    }
    __builtin_amdgcn_s_setprio(0);
    #pragma unroll
    for (int i=0;i<2;i++){
      #pragma unroll
      for (int r=0;r<4;r++){
        int qrow = q0 + wvx*32 + i*16 + quad*4 + r;
        #pragma unroll
        for (int j=0;j<2;j++){
          float s = sacc[i][j][r] * 0.125f;
          if (useMask) s += ldin(mask, (size_t)qrow*S_LEN + key0 + j*16 + lrow, is32);
          sacc[i][j][r] = s;
        }
        float mx = fmaxf(sacc[i][0][r], sacc[i][1][r]);
        #pragma unroll
        for (int mm=1; mm<=8; mm<<=1) mx = fmaxf(mx, __shfl_xor(mx, mm, 64));
        float mnew = fmaxf(mrun[i][r], mx);
        float alpha = __expf(mrun[i][r] - mnew);
        float ps = 0.f;
        #pragma unroll
        for (int j=0;j<2;j++){
          float p = __expf(sacc[i][j][r] - mnew);
          sacc[i][j][r] = p;
          ps += p;
        }
        #pragma unroll
        for (int mm=1; mm<=8; mm<<=1) ps += __shfl_xor(ps, mm, 64);
        lrun[i][r] = lrun[i][r]*alpha + ps;
        mrun[i][r] = mnew;
        #pragma unroll
        for (int j=0;j<4;j++) oacc[i][j][r] *= alpha;
        int prow = wvx*32 + i*16 + quad*4 + r;
        #pragma unroll
        for (int j=0;j<2;j++){
          int key = j*16 + lrow;
          float pv = sacc[i][j][r];
          _Float16 ph = (_Float16)pv;
          Phi[prow*32 + key] = ph;
          Plo[prow*32 + key] = (_Float16)(pv - (float)ph);
        }
      }
    }
    __syncthreads();
    {
      h16x8 pf[2], pl[2], vh[4], vl[4];
      #pragma unroll
      for (int i=0;i<2;i++){
        pf[i] = *(const h16x8*)&Phi[(wvx*32 + i*16 + lrow)*32 + quad*8];
        pl[i] = *(const h16x8*)&Plo[(wvx*32 + i*16 + lrow)*32 + quad*8];
      }
      #pragma unroll
      for (int j=0;j<4;j++){
        vh[j] = *(const h16x8*)&Vth[(j*16 + lrow)*32 + quad*8];
        vl[j] = *(const h16x8*)&Vtl[(j*16 + lrow)*32 + quad*8];
      }
      __builtin_amdgcn_s_setprio(1);
      #pragma unroll
      for (int i=0;i<2;i++)
        #pragma unroll
        for (int j=0;j<4;j++){
          oacc[i][j] = mfma16(pf[i], vh[j], oacc[i][j]);
          oacc[i][j] = mfma16(pf[i], vl[j], oacc[i][j]);
          oacc[i][j] = mfma16(pl[i], vh[j], oacc[i][j]);
        }
      __builtin_amdgcn_s_setprio(0);
    }
  }
  #pragma unroll
  for (int i=0;i<2;i++)
    #pragma unroll
    for (int j=0;j<4;j++)
      #pragma unroll
      for (int r=0;r<4;r++){
        int row = q0 + wvx*32 + i*16 + quad*4 + r;
        int col = h*64 + j*16 + lrow;
        size_t idx = (tok0 + row)*H_DIM + col;
        float v = oacc[i][j][r] / lrun[i][r];
        _Float16 hh = (_Float16)v;
        ohi[idx] = hh;
        olo[idx] = (_Float16)(v - (float)hh);
      }
}

// ---------------- RMSNorm #2 + router (fp32 logits, top-2) ----------------
__global__ __launch_bounds__(256) void k_rms2_router(const float* __restrict__ x1, const void* __restrict__ w,
    const void* __restrict__ rw, _Float16* __restrict__ h2,
    int* __restrict__ tok_e, float* __restrict__ tok_w, int* __restrict__ counts,
    const int* __restrict__ df){
  const int is32 = *df;
  int t = blockIdx.x, tid = threadIdx.x;
  f32x4 v = *(const f32x4*)&x1[(size_t)t*H_DIM + tid*4];
  float ss = v[0]*v[0]+v[1]*v[1]+v[2]*v[2]+v[3]*v[3];
  #pragma unroll
  for (int off=32; off>0; off>>=1) ss += __shfl_down(ss, off, 64);
  __shared__ float red[4];
  __shared__ float lgs[32];
  if ((tid&63)==0) red[tid>>6] = ss;
  __syncthreads();
  float rstd = rsqrt_acc((red[0]+red[1]+red[2]+red[3])*(1.0f/H_DIM) + 1e-6f);
  float hv[4];
  h16x4 hst;
  #pragma unroll
  for (int m=0;m<4;m++){ hv[m] = v[m]*rstd*ldin(w, tid*4+m, is32); hst[m] = (_Float16)hv[m]; }
  *(h16x4*)&h2[(size_t)t*H_DIM + tid*4] = hst;
  float part[8] = {0,0,0,0,0,0,0,0};
  #pragma unroll
  for (int m=0;m<4;m++){
    size_t c = (size_t)(tid*4 + m)*8;
    #pragma unroll
    for (int e=0;e<8;e++) part[e] += hv[m]*ldin(rw, c+e, is32);
  }
  #pragma unroll
  for (int e=0;e<8;e++){
    #pragma unroll
    for (int off=32; off>0; off>>=1) part[e] += __shfl_down(part[e], off, 64);
  }
  if ((tid&63)==0){
    #pragma unroll
    for (int e=0;e<8;e++) lgs[(tid>>6)*8 + e] = part[e];
  }
  __syncthreads();
  if (tid==0){
    float lg[8];
    #pragma unroll
    for (int e=0;e<8;e++) lg[e] = lgs[e] + lgs[8+e] + lgs[16+e] + lgs[24+e];
    int e0 = 0;
    #pragma unroll
    for (int e=1;e<8;e++) if (lg[e] > lg[e0]) e0 = e;
    int e1 = (e0==0) ? 1 : 0;
    #pragma unroll
    for (int e=0;e<8;e++) if (e != e0 && lg[e] > lg[e1]) e1 = e;
    float d = expf(lg[e1] - lg[e0]);
    float w0 = 1.0f/(1.0f + d);
    float w1 = d * w0;
    tok_e[t*2] = e0; tok_e[t*2+1] = e1;
    tok_w[t*2] = w0; tok_w[t*2+1] = w1;
    atomicAdd(&counts[e0], 1);
    atomicAdd(&counts[e1], 1);
  }
}

// ---------------- expert offsets (padded prefix) ----------------
__global__ void k_offsets(const int* __restrict__ counts, int* __restrict__ offs, int* __restrict__ fillpos){
  if (threadIdx.x == 0 && blockIdx.x == 0){
    int o = 0;
    for (int e=0;e<8;e++){
      offs[e] = o; fillpos[e] = o;
      o += (counts[e] + 127) & ~127;
    }
    offs[8] = o;
  }
}

// ---------------- fill compact token lists ----------------
__global__ __launch_bounds__(256) void k_fill(const int* __restrict__ tok_e, const float* __restrict__ tok_w,
    int* __restrict__ fillpos, int* __restrict__ list_ts, float* __restrict__ list_w){
  int t = blockIdx.x*256 + threadIdx.x;
  if (t >= T_TOK) return;
  #pragma unroll
  for (int s=0;s<2;s++){
    int e = tok_e[t*2+s];
    int p = atomicAdd(&fillpos[e], 1);
    list_ts[p] = t*2 + s;
    list_w[p] = tok_w[t*2+s];
  }
}

// ======== HOT PATH: pre-transposed f16 weights + global_load_lds staging ========

// gate+up GEMM, B^T [e][n=4096][k=1024] f16; tile 128m x (64 gate + 64 up), BK=32
__global__ __launch_bounds__(256) void k_gemm_gu_t(const _Float16* __restrict__ h2,
    const _Float16* __restrict__ gwt, _Float16* __restrict__ act, const int* __restrict__ list_ts,
    const int* __restrict__ counts, const int* __restrict__ offs){
  int m0 = blockIdx.y<<7;
  if (m0 >= offs[8]) return;
  int e = 0;
  while (m0 >= offs[e+1]) e++;
  int base = offs[e], cnt = counts[e];
  if (m0 >= base + cnt) return;
  __shared__ __align__(16) _Float16 As[128*32], Bg[64*32], Bu[64*32];
  __shared__ int rowtok[128];
  int tid = threadIdx.x;
  if (tid < 128) rowtok[tid] = list_ts[min(m0 + tid, base + cnt - 1)] >> 1;
  __syncthreads();
  int lane = tid&63, wvx = tid>>6, wr = wvx>>1, wc = wvx&1, quad = lane>>4, lrow = lane&15;
  int n0 = blockIdx.x<<6;
  const _Float16* Bge = gwt + (size_t)e*4096*1024 + (size_t)n0*1024;
  const _Float16* Bue = gwt + (size_t)e*4096*1024 + (size_t)(2048+n0)*1024;
  // hoist gathered A row bases (k0-independent)
  const _Float16* arow0 = &h2[(size_t)rowtok[tid>>2]*H_DIM + (tid&3)*8];
  const _Float16* arow1 = &h2[(size_t)rowtok[(256+tid)>>2]*H_DIM + (tid&3)*8];
  int bR = tid>>2, bG = tid&3;
  f32x4 ag[4][2] = {}, au[4][2] = {};
  for (int k0=0; k0<1024; k0+=32){
    gll16(arow0 + k0, &As[(size_t)(wvx*64)*8]);
    gll16(arow1 + k0, &As[(size_t)(256 + wvx*64)*8]);
    gll16(&Bge[(size_t)bR*1024 + k0 + bG*8], &Bg[(size_t)(wvx*64)*8]);
    gll16(&Bue[(size_t)bR*1024 + k0 + bG*8], &Bu[(size_t)(wvx*64)*8]);
    __syncthreads();
    h16x8 a[4], bg[2], bu[2];
    #pragma unroll
    for (int i=0;i<4;i++) a[i] = *(const h16x8*)&As[(wr*64 + i*16 + lrow)*32 + quad*8];
    #pragma unroll
    for (int j=0;j<2;j++){
      bg[j] = *(const h16x8*)&Bg[(wc*32 + j*16 + lrow)*32 + quad*8];
      bu[j] = *(const h16x8*)&Bu[(wc*32 + j*16 + lrow)*32 + quad*8];
    }
    #pragma unroll
    for (int i=0;i<4;i++)
      #pragma unroll
      for (int j=0;j<2;j++){
        ag[i][j] = mfma16(a[i], bg[j], ag[i][j]);
        au[i][j] = mfma16(a[i], bu[j], au[i][j]);
      }
    __syncthreads();
  }
  #pragma unroll
  for (int i=0;i<4;i++)
    #pragma unroll
    for (int j=0;j<2;j++)
      #pragma unroll
      for (int r=0;r<4;r++){
        int row = m0 + wr*64 + i*16 + quad*4 + r;
        int col = n0 + wc*32 + j*16 + lrow;
        float g = ag[i][j][r], u = au[i][j][r];
        float sv = g / (1.0f + __expf(-g));
        act[(size_t)row*INTER_DIM + col] = (_Float16)(sv * u);
      }
}

// down GEMM, B^T [e][n=1024][k=2048] f16; tile 128x128, BK=32; scatter epilogue
__global__ __launch_bounds__(256) void k_gemm_down_t(const _Float16* __restrict__ act,
    const _Float16* __restrict__ dwt, _Float16* __restrict__ slotbuf, const int* __restrict__ list_ts,
    const float* __restrict__ list_w, const int* __restrict__ counts, const int* __restrict__ offs){
  int m0 = blockIdx.y<<7;
  if (m0 >= offs[8]) return;
  int e = 0;
  while (m0 >= offs[e+1]) e++;
  int base = offs[e], cnt = counts[e];
  if (m0 >= base + cnt) return;
  __shared__ __align__(16) _Float16 As[128*32], Bs[128*32];
  int tid = threadIdx.x, lane = tid&63, wvx = tid>>6;
  int wr = wvx>>1, wc = wvx&1, quad = lane>>4, lrow = lane&15;
  int n0 = blockIdx.x<<7;
  const _Float16* Be = dwt + (size_t)e*1024*2048 + (size_t)n0*2048;
  f32x4 acc[4][4] = {};
  for (int k0=0; k0<2048; k0+=32){
    #pragma unroll
    for (int it=0; it<2; it++){
      int c2 = it*256 + tid;
      int r = c2>>2, g = c2&3;
      gll16(&act[(size_t)(m0+r)*INTER_DIM + k0 + g*8], &As[(size_t)(it*256 + wvx*64)*8]);
      gll16(&Be[(size_t)r*2048 + k0 + g*8], &Bs[(size_t)(it*256 + wvx*64)*8]);
    }
    __syncthreads();
    h16x8 a[4], b[4];
    #pragma unroll
    for (int i=0;i<4;i++) a[i] = *(const h16x8*)&As[(wr*64 + i*16 + lrow)*32 + quad*8];
    #pragma unroll
    for (int j=0;j<4;j++) b[j] = *(const h16x8*)&Bs[(wc*64 + j*16 + lrow)*32 + quad*8];
    #pragma unroll
    for (int i=0;i<4;i++)
      #pragma unroll
      for (int j=0;j<4;j++)
        acc[i][j] = mfma16(a[i], b[j], acc[i][j]);
    __syncthreads();
  }
  #pragma unroll
  for (int i=0;i<4;i++)
    #pragma unroll
    for (int r=0;r<4;r++){
      int m = m0 + wr*64 + i*16 + quad*4 + r;
      if (m < base + cnt){
        int ts = list_ts[m];
        float wgt = list_w[m];
        #pragma unroll
        for (int j=0;j<4;j++){
          int col = n0 + wc*64 + j*16 + lrow;
          slotbuf[(size_t)ts*H_DIM + col] = (_Float16)(wgt * acc[i][j][r]);
        }
      }
    }
}

// ======== LEGACY PATH (ws too small for weight transposes) ========

__global__ __launch_bounds__(256) void k_gemm_gu(const _Float16* __restrict__ h2, const void* __restrict__ guw,
    _Float16* __restrict__ act, const int* __restrict__ list_ts,
    const int* __restrict__ counts, const int* __restrict__ offs, const int* __restrict__ df){
  const int is32 = *df;
  int m0 = blockIdx.y<<7;
  if (m0 >= offs[8]) return;
  int e = 0;
  while (m0 >= offs[e+1]) e++;
  int base = offs[e], cnt = counts[e];
  if (m0 >= base + cnt) return;
  __shared__ __align__(16) _Float16 As[128*32], Bg[64*40], Bu[64*40];
  __shared__ int rowtok[128];
  int tid = threadIdx.x;
  if (tid < 128){
    int mc = min(m0 + tid, base + cnt - 1);
    rowtok[tid] = list_ts[mc] >> 1;
  }
  __syncthreads();
  int lane = tid&63, wvx = tid>>6, wr = wvx>>1, wc = wvx&1, quad = lane>>4, lrow = lane&15;
  int n0 = blockIdx.x<<6;
  size_t ebase = (size_t)e*H_DIM*4096;
  f32x4 ag[4][2] = {}, au[4][2] = {};
  for (int k0=0; k0<1024; k0+=32){
    #pragma unroll
    for (int it=0; it<2; it++){
      int ch = it*256 + tid;
      int r = ch>>2, c = ch&3;
      *(i32x4*)&As[ch*8] = *(const i32x4*)&h2[(size_t)rowtok[r]*H_DIM + k0 + c*8];
    }
    {
      int k = tid>>3, g = tid&7;
      size_t rowb = ebase + (size_t)(k0+k)*4096;
      int ks = kslot_sw(k, g);
      _Float16 tg[8], tu[8];
      if (is32){
        const float* gf = (const float*)guw;
        f32x4 a0 = *(const f32x4*)&gf[rowb + n0 + g*8];
        f32x4 a1 = *(const f32x4*)&gf[rowb + n0 + g*8 + 4];
        f32x4 b0 = *(const f32x4*)&gf[rowb + 2048 + n0 + g*8];
        f32x4 b1 = *(const f32x4*)&gf[rowb + 2048 + n0 + g*8 + 4];
        #pragma unroll
        for (int i=0;i<4;i++){ tg[i]=(_Float16)a0[i]; tg[4+i]=(_Float16)a1[i];
                               tu[i]=(_Float16)b0[i]; tu[4+i]=(_Float16)b1[i]; }
      } else {
        const u16* gb = (const u16*)guw;
        u16x4 a0 = *(const u16x4*)&gb[rowb + n0 + g*8];
        u16x4 a1 = *(const u16x4*)&gb[rowb + n0 + g*8 + 4];
        u16x4 b0 = *(const u16x4*)&gb[rowb + 2048 + n0 + g*8];
        u16x4 b1 = *(const u16x4*)&gb[rowb + 2048 + n0 + g*8 + 4];
        #pragma unroll
        for (int i=0;i<4;i++){ tg[i]=(_Float16)bf2f(a0[i]); tg[4+i]=(_Float16)bf2f(a1[i]);
                               tu[i]=(_Float16)bf2f(b0[i]); tu[4+i]=(_Float16)bf2f(b1[i]); }
      }
      #pragma unroll
      for (int i=0;i<8;i++){
        int n = g*8 + i;
        Bg[n*40 + ks] = tg[i];
        Bu[n*40 + ks] = tu[i];
      }
    }
    __syncthreads();
    h16x8 a[4], bg[2], bu[2];
    #pragma unroll
    for (int i=0;i<4;i++) a[i] = *(const h16x8*)&As[(wr*64 + i*16 + lrow)*32 + quad*8];
    #pragma unroll
    for (int j=0;j<2;j++){
      int n = wc*32 + j*16 + lrow;
      int oct = (quad ^ ((n>>3)&3))*8;
      bg[j] = *(const h16x8*)&Bg[n*40 + oct];
      bu[j] = *(const h16x8*)&Bu[n*40 + oct];
    }
    #pragma unroll
    for (int i=0;i<4;i++)
      #pragma unroll
      for (int j=0;j<2;j++){
        ag[i][j] = mfma16(a[i], bg[j], ag[i][j]);
        au[i][j] = mfma16(a[i], bu[j], au[i][j]);
      }
    __syncthreads();
  }
  #pragma unroll
  for (int i=0;i<4;i++)
    #pragma unroll
    for (int j=0;j<2;j++)
      #pragma unroll
      for (int r=0;r<4;r++){
        int row = m0 + wr*64 + i*16 + quad*4 + r;
        int col = n0 + wc*32 + j*16 + lrow;
        float g = ag[i][j][r], u = au[i][j][r];
        float sv = g / (1.0f + __expf(-g));
        act[(size_t)row*INTER_DIM + col] = (_Float16)(sv * u);
      }
}

__global__ __launch_bounds__(256) void k_gemm_down(const _Float16* __restrict__ act, const void* __restrict__ dw,
    _Float16* __restrict__ slotbuf, const int* __restrict__ list_ts, const float* __restrict__ list_w,
    const int* __restrict__ counts, const int* __restrict__ offs, const int* __restrict__ df){
  const int is32 = *df;
  int m0 = blockIdx.y<<7;
  if (m0 >= offs[8]) return;
  int e = 0;
  while (m0 >= offs[e+1]) e++;
  int base = offs[e], cnt = counts[e];
  if (m0 >= base + cnt) return;
  __shared__ __align__(16) _Float16 As[128*32], Bs[128*40];
  int tid = threadIdx.x, lane = tid&63, wvx = tid>>6;
  int wr = wvx>>1, wc = wvx&1, quad = lane>>4, lrow = lane&15;
  int n0 = blockIdx.x<<7;
  size_t ebase = (size_t)e*INTER_DIM*H_DIM;
  f32x4 acc[4][4] = {};
  for (int k0=0; k0<2048; k0+=32){
    #pragma unroll
    for (int it=0; it<2; it++){
      int ch = it*256 + tid;
      int r = ch>>2, c = ch&3;
      *(i32x4*)&As[ch*8] = *(const i32x4*)&act[(size_t)(m0+r)*INTER_DIM + k0 + c*8];
    }
    {
      int k = tid>>3, g = tid&7;
      size_t rowb = ebase + (size_t)(k0+k)*H_DIM;
      int ks = kslot_sw(k, g);
      #pragma unroll
      for (int p=0;p<2;p++){
        _Float16 tb[8];
        if (is32){
          const float* bf = (const float*)dw;
          f32x4 a0 = *(const f32x4*)&bf[rowb + n0 + p*64 + g*8];
          f32x4 a1 = *(const f32x4*)&bf[rowb + n0 + p*64 + g*8 + 4];
          #pragma unroll
          for (int i=0;i<4;i++){ tb[i]=(_Float16)a0[i]; tb[4+i]=(_Float16)a1[i]; }
        } else {
          const u16* bb = (const u16*)dw;
          u16x4 a0 = *(const u16x4*)&bb[rowb + n0 + p*64 + g*8];
          u16x4 a1 = *(const u16x4*)&bb[rowb + n0 + p*64 + g*8 + 4];
          #pragma unroll
          for (int i=0;i<4;i++){ tb[i]=(_Float16)bf2f(a0[i]); tb[4+i]=(_Float16)bf2f(a1[i]); }
        }
        #pragma unroll
        for (int i=0;i<8;i++){
          int n = p*64 + g*8 + i;
          Bs[n*40 + ks] = tb[i];
        }
      }
    }
    __syncthreads();
    h16x8 a[4], b[4];
    #pragma unroll
    for (int i=0;i<4;i++) a[i] = *(const h16x8*)&As[(wr*64 + i*16 + lrow)*32 + quad*8];
    #pragma unroll
    for (int j=0;j<4;j++){
      int n = wc*64 + j*16 + lrow;
      b[j] = *(const h16x8*)&Bs[n*40 + ((quad ^ ((n>>3)&3))*8)];
    }
    #pragma unroll
    for (int i=0;i<4;i++)
      #pragma unroll
      for (int j=0;j<4;j++)
        acc[i][j] = mfma16(a[i], b[j], acc[i][j]);
    __syncthreads();
  }
  #pragma unroll
  for (int i=0;i<4;i++)
    #pragma unroll
    for (int r=0;r<4;r++){
      int m = m0 + wr*64 + i*16 + quad*4 + r;
      if (m < base + cnt){
        int ts = list_ts[m];
        float wgt = list_w[m];
        #pragma unroll
        for (int j=0;j<4;j++){
          int col = n0 + wc*64 + j*16 + lrow;
          slotbuf[(size_t)ts*H_DIM + col] = (_Float16)(wgt * acc[i][j][r]);
        }
      }
    }
}

// ---------------- final residual add -> dual-dtype out ----------------
__global__ __launch_bounds__(256) void k_final(const float* __restrict__ x1, const _Float16* __restrict__ slot,
                                               void* __restrict__ outv, const int* __restrict__ df){
  const int is32 = *df;
  int i4 = (blockIdx.x*256 + threadIdx.x)*4;
  int t = i4 >> 10, c = i4 & 1023;
  f32x4 a = *(const f32x4*)&x1[i4];
  h16x4 s0 = *(const h16x4*)&slot[(size_t)(t*2)*H_DIM + c];
  h16x4 s1 = *(const h16x4*)&slot[(size_t)(t*2+1)*H_DIM + c];
  if (is32){
    f32x4 o;
    #pragma unroll
    for (int m=0;m<4;m++) o[m] = a[m] + (float)s0[m] + (float)s1[m];
    *(f32x4*)&((float*)outv)[i4] = o;
  } else {
    u16x4 o;
    #pragma unroll
    for (int m=0;m<4;m++) o[m] = f2bf(a[m] + (float)s0[m] + (float)s1[m]);
    *(u16x4*)&((u16*)outv)[i4] = o;
  }
}

extern "C" void kernel_launch(void* const* d_in, const int* in_sizes, int n_in,
                              void* d_out, int out_size, void* d_ws, size_t ws_size,
                              hipStream_t stream){
  (void)in_sizes; (void)n_in; (void)out_size;
  const void* x    = d_in[0];
  const void* mask = d_in[1];
  const void* ln1  = d_in[2];
  const void* ln2  = d_in[3];
  const void* qkvw = d_in[4];
  const void* ow   = d_in[5];
  const void* rw   = d_in[6];
  const void* guw  = d_in[7];
  const void* dww  = d_in[8];

  char* ws = (char*)d_ws;
  size_t off = 0;
  auto alloc = [&](size_t b)->void*{ void* p = ws + off; off = (off + b + 255) & ~(size_t)255; return p; };
  int* meta            = (int*)alloc(32*sizeof(int));
  _Float16* qkv_wt     = (_Float16*)alloc((size_t)3072*1024*2);
  _Float16* o_wt       = (_Float16*)alloc((size_t)1024*1024*2);
  _Float16* hpair      = (_Float16*)alloc((size_t)2*4096*1024*2);  // h hi/lo; later aout hi/lo; later slotbuf
  _Float16* qkvpair    = (_Float16*)alloc((size_t)2*4096*3072*2);  // qkv hi/lo; later h2+act
  float* x1            = (float*)alloc((size_t)4096*1024*4);       // V^T hi/lo during attn; then x1
  int* list_ts         = (int*)alloc(MAXROWS*4);
  float* list_w        = (float*)alloc(MAXROWS*4);
  int* tok_e           = (int*)alloc((size_t)4096*2*4);
  float* tok_w         = (float*)alloc((size_t)4096*2*4);
  size_t base_end = off;                                           // ~92 MB
  _Float16* gu_wt      = (_Float16*)alloc((size_t)8*4096*1024*2);  // 67 MB
  _Float16* down_wt    = (_Float16*)alloc((size_t)8*1024*2048*2);  // 34 MB
  const int big = (ws_size >= off) ? 1 : 0;                        // need ~193 MB for hot path
  (void)base_end;

  int* counts = meta;
  int* offs   = meta + 8;
  int* fillpos= meta + 17;
  int* flag   = meta + 25;
  int* dflag  = meta + 26;

  _Float16* h_hi   = hpair;
  _Float16* h_lo   = hpair + (size_t)4096*1024;
  _Float16* qkv_hi = qkvpair;
  _Float16* qkv_lo = qkvpair + (size_t)4096*3072;
  _Float16* vth    = (_Float16*)x1;                     // 8 MB
  _Float16* vtl    = vth + (size_t)64*64*1024;          // 8 MB
  _Float16* ahi    = hpair;                             // aout hi (h dead)
  _Float16* alo    = hpair + (size_t)4096*1024;         // aout lo
  _Float16* h2     = qkvpair;                           // qkv dead after attn
  _Float16* act    = qkvpair + (size_t)4096*1024;
  _Float16* slotbuf= hpair;                             // aout dead after o-proj

  hipMemsetAsync(meta, 0, 32*sizeof(int), stream);
  k_detect<<<dim3(1), dim3(64), 0, stream>>>((const uint32_t*)x, dflag);
  k_trans2<<<dim3(48, 16, 1), 256, 0, stream>>>(qkvw, qkv_wt, 1024, 3072, dflag);
  k_trans2<<<dim3(16, 16, 1), 256, 0, stream>>>(ow, o_wt, 1024, 1024, dflag);
  if (big){
    k_trans2<<<dim3(64, 16, 8), 256, 0, stream>>>(guw, gu_wt, 1024, 4096, dflag);
    k_trans2<<<dim3(16, 32, 8), 256, 0, stream>>>(dww, down_wt, 2048, 1024, dflag);
  }
  k_maskchk<<<dim3(1024), 256, 0, stream>>>(mask, flag, dflag);
  k_rms1<<<dim3(4096), 256, 0, stream>>>(x, ln1, h_hi, h_lo, dflag);
  k_gemm_hl<0><<<dim3(24, 32), 256, 0, stream>>>(h_hi, h_lo, qkv_wt, nullptr, qkv_hi, qkv_lo,
                                                 nullptr, 3072, 1024, dflag);
  k_vt<<<dim3(16, 64), 256, 0, stream>>>(qkv_hi, qkv_lo, vth, vtl);
  k_attn<<<dim3(8, 64), 256, 0, stream>>>(qkv_hi, qkv_lo, vth, vtl, mask, flag, ahi, alo, dflag);
  k_gemm_hl<1><<<dim3(8, 32), 256, 0, stream>>>(ahi, alo, o_wt, x1, nullptr, nullptr,
                                                x, 1024, 1024, dflag);
  k_rms2_router<<<dim3(4096), 256, 0, stream>>>(x1, ln2, rw, h2, tok_e, tok_w, counts, dflag);
  k_offsets<<<dim3(1), dim3(64), 0, stream>>>(counts, offs, fillpos);
  k_fill<<<dim3(16), 256, 0, stream>>>(tok_e, tok_w, fillpos, list_ts, list_w);
  if (big){
    k_gemm_gu_t<<<dim3(32, 72), 256, 0, stream>>>(h2, gu_wt, act, list_ts, counts, offs);
    k_gemm_down_t<<<dim3(8, 72), 256, 0, stream>>>(act, down_wt, slotbuf, list_ts, list_w, counts, offs);
  } else {
    k_gemm_gu<<<dim3(32, 72), 256, 0, stream>>>(h2, guw, act, list_ts, counts, offs, dflag);
    k_gemm_down<<<dim3(8, 72), 256, 0, stream>>>(act, dww, slotbuf, list_ts, list_w, counts, offs, dflag);
  }
  k_final<<<dim3(4096), 256, 0, stream>>>(x1, slotbuf, d_out, dflag);
}

// Round 2
// 849.323 us; speedup vs baseline: 1.0832x; 1.0411x over previous
//
#include <hip/hip_runtime.h>
#include <cstdint>
#include <cmath>

// Problem constants (B=4, S=1024)
#define T_TOK 4096
#define H_DIM 1024
#define QKV_N 3072
#define S_LEN 1024
#define INTER_DIM 2048
#define MAXROWS 9216   // 2*T + 8*127 padding, rounded

typedef unsigned short u16;
using f32x4 = __attribute__((ext_vector_type(4))) float;
using h16x8 = __attribute__((ext_vector_type(8))) _Float16;
using h16x4 = __attribute__((ext_vector_type(4))) _Float16;
using i32x4 = __attribute__((ext_vector_type(4))) int;
using u16x4 = __attribute__((ext_vector_type(4))) u16;
using u16x8 = __attribute__((ext_vector_type(8))) u16;

__device__ __forceinline__ float bf2f(u16 u){ return __uint_as_float(((uint32_t)u)<<16); }
__device__ __forceinline__ u16 f2bf(float f){
  uint32_t x = __float_as_uint(f);
  uint32_t r = x + 0x7FFFu + ((x>>16)&1u);
  return (u16)(r>>16);
}
__device__ __forceinline__ f32x4 mfma16(h16x8 a, h16x8 b, f32x4 c){
  return __builtin_amdgcn_mfma_f32_16x16x32_f16(a,b,c,0,0,0);
}
__device__ __forceinline__ float rsqrt_acc(float v){
  float r = rsqrtf(v);
  r = r*(1.5f - 0.5f*v*r*r);
  r = r*(1.5f - 0.5f*v*r*r);
  return r;
}
// dual-dtype scalar input read
__device__ __forceinline__ float ldin(const void* p, size_t i, int is32){
  return is32 ? ((const float*)p)[i] : bf2f(((const u16*)p)[i]);
}
// swizzled k-slot for stride-40 B tiles (legacy path)
__device__ __forceinline__ int kslot_sw(int k, int noct){
  return (k&7) | (((k>>3) ^ (noct&3))<<3);
}
// async global->LDS, 16B per lane; lds base must be wave-uniform, lanes land at base+lane*16
__device__ __forceinline__ void gll16(const void* g, void* l){
  __builtin_amdgcn_global_load_lds(
      (const __attribute__((address_space(1))) void*)g,
      (__attribute__((address_space(3))) void*)l, 16, 0, 0);
}

// ---------------- dtype detection: fp32 exponent fields of N(0,1) data ----------------
__global__ void k_detect(const uint32_t* __restrict__ x, int* __restrict__ dflag){
  uint32_t u = x[threadIdx.x];
  int e = (u>>23)&0xFF;
  int ok = (e>=103 && e<=150);            // |f| in [2^-24, 2^23]
  unsigned long long m = __ballot(ok);
  if (threadIdx.x==0) *dflag = (__popcll(m) >= 48) ? 1 : 0;
}

// ---------------- vectorized transpose + cast to f16: src [R][C] -> dst [C][R] ------
// 64x64 tiles; conflict-free LDS (stride 65); 16B global loads/stores
__global__ __launch_bounds__(256) void k_trans2(const void* __restrict__ src,
    _Float16* __restrict__ dst, int R, int C, const int* __restrict__ df){
  const int is32 = *df;
  __shared__ _Float16 t[64][65];
  size_t bo = (size_t)blockIdx.z * R * C;
  int c0 = blockIdx.x<<6, r0 = blockIdx.y<<6;
  int ty = threadIdx.x>>3, tx = threadIdx.x&7;   // ty 0..31, tx 0..7
  #pragma unroll
  for (int rr=0; rr<2; rr++){
    int r = rr*32 + ty;
    size_t gi = bo + (size_t)(r0+r)*C + c0 + tx*8;
    _Float16 v[8];
    if (is32){
      f32x4 a0 = *(const f32x4*)&((const float*)src)[gi];
      f32x4 a1 = *(const f32x4*)&((const float*)src)[gi+4];
      #pragma unroll
      for (int i=0;i<4;i++){ v[i]=(_Float16)a0[i]; v[4+i]=(_Float16)a1[i]; }
    } else {
      u16x8 a = *(const u16x8*)&((const u16*)src)[gi];
      #pragma unroll
      for (int i=0;i<8;i++) v[i]=(_Float16)bf2f(a[i]);
    }
    #pragma unroll
    for (int i=0;i<8;i++) t[r][tx*8+i] = v[i];
  }
  __syncthreads();
  #pragma unroll
  for (int rr=0; rr<2; rr++){
    int n = rr*32 + ty;
    h16x8 v;
    #pragma unroll
    for (int i=0;i<8;i++) v[i] = t[tx*8+i][n];
    *(h16x8*)&dst[bo + (size_t)(c0+n)*R + r0 + tx*8] = v;
  }
}

// ---------------- mask all-zero check ----------------
__global__ __launch_bounds__(256) void k_maskchk(const void* __restrict__ m, int* __restrict__ flag,
                                                 const int* __restrict__ df){
  const int is32 = *df;
  int i = (blockIdx.x*256 + threadIdx.x)*4;
  int nz = 0;
  if (is32){
    f32x4 v = *(const f32x4*)&((const float*)m)[i];
    nz = (v[0]!=0.f)||(v[1]!=0.f)||(v[2]!=0.f)||(v[3]!=0.f);
  } else {
    u16x4 v = *(const u16x4*)&((const u16*)m)[i];
    nz = ((v[0]|v[1]|v[2]|v[3]) & 0x7FFF) != 0;
  }
  if (nz) atomicOr(flag, 1);
}

// ---------------- RMSNorm #1: x -> pre-split f16 hi/lo h ----------------
__global__ __launch_bounds__(256) void k_rms1(const void* __restrict__ x, const void* __restrict__ w,
                                              _Float16* __restrict__ hhi, _Float16* __restrict__ hlo,
                                              const int* __restrict__ df){
  const int is32 = *df;
  int t = blockIdx.x, tid = threadIdx.x;
  size_t base = (size_t)t*H_DIM + tid*4;
  float f[4];
  #pragma unroll
  for (int m=0;m<4;m++) f[m] = ldin(x, base+m, is32);
  float ss = f[0]*f[0] + f[1]*f[1] + f[2]*f[2] + f[3]*f[3];
  #pragma unroll
  for (int off=32; off>0; off>>=1) ss += __shfl_down(ss, off, 64);
  __shared__ float red[4];
  if ((tid & 63) == 0) red[tid>>6] = ss;
  __syncthreads();
  float rstd = rsqrt_acc((red[0]+red[1]+red[2]+red[3]) * (1.0f/H_DIM) + 1e-6f);
  h16x4 oh, ol;
  #pragma unroll
  for (int m=0;m<4;m++){
    float v = f[m]*rstd*ldin(w, tid*4+m, is32);
    _Float16 hh = (_Float16)v;
    oh[m] = hh;
    ol[m] = (_Float16)(v - (float)hh);
  }
  *(h16x4*)&hhi[base] = oh;
  *(h16x4*)&hlo[base] = ol;
}

// ---------------- high-precision GEMM: pre-split f16 hi/lo A, f16 B^T --------------
// EPI==0: write C as f16 hi/lo pair. EPI==1: fp32 C with residual add.
template<int EPI>
__global__ __launch_bounds__(256) void k_gemm_hl(const _Float16* __restrict__ Ah,
    const _Float16* __restrict__ Al, const _Float16* __restrict__ Bt,
    float* __restrict__ C, _Float16* __restrict__ Chi, _Float16* __restrict__ Clo,
    const void* __restrict__ res, int N, int K, const int* __restrict__ df){
  const int is32 = (EPI==1) ? *df : 0;
  __shared__ __align__(16) _Float16 AhS[128*32];
  __shared__ __align__(16) _Float16 AlS[128*32];
  __shared__ __align__(16) _Float16 Bs[128*32];
  int tid = threadIdx.x, lane = tid&63, wvx = tid>>6;
  int wr = wvx>>1, wc = wvx&1, quad = lane>>4, lrow = lane&15;
  int m0 = blockIdx.y<<7, n0 = blockIdx.x<<7;
  int ar = tid>>2, acg = (tid&3)*8;
  const _Float16* a0h = &Ah[(size_t)(m0+ar)*K + acg];
  const _Float16* a1h = &Ah[(size_t)(m0+64+ar)*K + acg];
  const _Float16* a0l = &Al[(size_t)(m0+ar)*K + acg];
  const _Float16* a1l = &Al[(size_t)(m0+64+ar)*K + acg];
  const _Float16* b0  = &Bt[(size_t)(n0+ar)*K + acg];
  const _Float16* b1  = &Bt[(size_t)(n0+64+ar)*K + acg];
  f32x4 acc[4][4] = {};
  for (int k0=0; k0<K; k0+=32){
    gll16(a0h + k0, &AhS[wvx*512]);
    gll16(a1h + k0, &AhS[2048 + wvx*512]);
    gll16(a0l + k0, &AlS[wvx*512]);
    gll16(a1l + k0, &AlS[2048 + wvx*512]);
    gll16(b0  + k0, &Bs[wvx*512]);
    gll16(b1  + k0, &Bs[2048 + wvx*512]);
    __syncthreads();
    h16x8 ah[4], al[4], bb[4];
    #pragma unroll
    for (int i=0;i<4;i++){
      ah[i] = *(const h16x8*)&AhS[(wr*64 + i*16 + lrow)*32 + quad*8];
      al[i] = *(const h16x8*)&AlS[(wr*64 + i*16 + lrow)*32 + quad*8];
    }
    #pragma unroll
    for (int j=0;j<4;j++) bb[j] = *(const h16x8*)&Bs[(wc*64 + j*16 + lrow)*32 + quad*8];
    #pragma unroll
    for (int i=0;i<4;i++)
      #pragma unroll
      for (int j=0;j<4;j++){
        acc[i][j] = mfma16(ah[i], bb[j], acc[i][j]);
        acc[i][j] = mfma16(al[i], bb[j], acc[i][j]);
      }
    __syncthreads();
  }
  #pragma unroll
  for (int i=0;i<4;i++)
    #pragma unroll
    for (int j=0;j<4;j++){
      int col = n0 + wc*64 + j*16 + lrow;
      #pragma unroll
      for (int r=0;r<4;r++){
        int row = m0 + wr*64 + i*16 + quad*4 + r;
        size_t idx = (size_t)row*N + col;
        float v = acc[i][j][r];
        if (EPI==1){
          v += ldin(res, idx, is32);
          C[idx] = v;
        } else {
          _Float16 hh = (_Float16)v;
          Chi[idx] = hh;
          Clo[idx] = (_Float16)(v - (float)hh);
        }
      }
    }
}

// ---------------- V^T prep: qkv hi/lo V-slice -> [bh][64 d][1024 keys] f16 hi/lo ----
__global__ __launch_bounds__(256) void k_vt(const _Float16* __restrict__ qh,
    const _Float16* __restrict__ ql, _Float16* __restrict__ vth, _Float16* __restrict__ vtl){
  __shared__ _Float16 th[64][72];
  __shared__ _Float16 tl[64][72];
  int bh = blockIdx.y;           // 0..63
  int b = bh>>4, h = bh&15;
  int key0 = blockIdx.x<<6;      // 16 tiles of 64 keys
  size_t tok0 = (size_t)b*S_LEN;
  int ty = threadIdx.x>>3, tx = threadIdx.x&7;  // ty 0..31, tx 0..7
  #pragma unroll
  for (int rr=0; rr<2; rr++){
    int r = rr*32 + ty;          // key within tile
    size_t gi = (tok0 + key0 + r)*(size_t)QKV_N + 2048 + h*64 + tx*8;
    h16x8 vh_ = *(const h16x8*)&qh[gi];
    h16x8 vl_ = *(const h16x8*)&ql[gi];
    #pragma unroll
    for (int i=0;i<8;i++){ th[r][tx*8+i] = vh_[i]; tl[r][tx*8+i] = vl_[i]; }
  }
  __syncthreads();
  size_t dbase = (size_t)bh*64*1024;
  #pragma unroll
  for (int rr=0; rr<2; rr++){
    int d = rr*32 + ty;
    h16x8 oh, ol;
    #pragma unroll
    for (int i=0;i<8;i++){ oh[i] = th[tx*8+i][d]; ol[i] = tl[tx*8+i][d]; }
    *(h16x8*)&vth[dbase + (size_t)d*1024 + key0 + tx*8] = oh;
    *(h16x8*)&vtl[dbase + (size_t)d*1024 + key0 + tx*8] = ol;
  }
}

// ---------------- flash attention v3: KVBLK=64, reg-prefetch staging, swizzled LDS --
// LDS pool 64KB: Khi[64k][64d] 8KB, Klo 8KB, Vth[64d][64k] 8KB, Vtl 8KB,
//                Phi[128r][64k] 16KB, Plo 16KB. Q staged through pool[0..16383] once.
__global__ __launch_bounds__(256, 2) void k_attn(const _Float16* __restrict__ qkvh,
    const _Float16* __restrict__ qkvl, const _Float16* __restrict__ vth_g,
    const _Float16* __restrict__ vtl_g, const void* __restrict__ mask,
    const int* __restrict__ mflag, _Float16* __restrict__ ohi, _Float16* __restrict__ olo,
    const int* __restrict__ df){
  const int is32 = *df;
  __shared__ __align__(16) _Float16 pool[32768];   // 64 KB
  _Float16* Khi = pool;            // [64 key][64 d], row-XOR swizzled
  _Float16* Klo = pool + 4096;
  _Float16* Vth = pool + 8192;     // [64 d][64 key], row-XOR swizzled
  _Float16* Vtl = pool + 12288;
  _Float16* Phi = pool + 16384;    // [128 row][64 key], row-XOR swizzled
  _Float16* Plo = pool + 24576;
  int qt = blockIdx.x, bh = blockIdx.y;
  int b = bh>>4, h = bh&15;
  int tid = threadIdx.x, lane = tid&63, wvx = tid>>6, quad = lane>>4, lrow = lane&15;
  size_t tok0 = (size_t)b*S_LEN;
  int q0 = qt<<7;
  // ---- stage Q hi/lo (32KB) into pool, pull fragments into registers ----
  {
    int r = tid>>2, cg = (tid&3)*8;
    #pragma unroll
    for (int p=0;p<2;p++)
      #pragma unroll
      for (int g=0;g<2;g++){
        size_t src = (tok0 + q0 + g*64 + r)*(size_t)QKV_N + h*64 + p*32 + cg;
        gll16(&qkvh[src], &pool[p*4096 + g*2048 + wvx*512]);
        gll16(&qkvl[src], &pool[8192 + p*4096 + g*2048 + wvx*512]);
      }
  }
  __syncthreads();
  h16x8 qfh[2][2], qfl[2][2];
  #pragma unroll
  for (int p=0;p<2;p++)
    #pragma unroll
    for (int i=0;i<2;i++){
      qfh[p][i] = *(const h16x8*)&pool[(p*128 + wvx*32 + i*16 + lrow)*32 + quad*8];
      qfl[p][i] = *(const h16x8*)&pool[8192 + (p*128 + wvx*32 + i*16 + lrow)*32 + quad*8];
    }
  int useMask = *mflag;
  float mrun[2][4], lrun[2][4];
  f32x4 oacc[2][4] = {};
  #pragma unroll
  for (int i=0;i<2;i++)
    #pragma unroll
    for (int r=0;r<4;r++){ mrun[i][r] = -INFINITY; lrun[i][r] = 0.f; }
  size_t vbase = (size_t)bh*64*1024;
  // per-thread staging geometry: chunk it covers rows it*32+(tid>>3), 8 halfs at (tid&7)*8
  int krow = tid>>3;                    // 0..31
  int c8   = (tid&7)*8;
  int rsw  = ((tid>>3)&7)<<3;           // store-side row XOR swizzle
  int fsw  = (lrow&7)<<3;               // fragment-read row XOR swizzle
  size_t ksrc0 = (tok0 + krow)*(size_t)QKV_N + 1024 + h*64 + c8;
  size_t vsrc0 = vbase + (size_t)krow*1024 + c8;
  h16x8 kh_r[2], kl_r[2], vh_r[2], vl_r[2];
  // prefetch tile 0 into regs
  {
    size_t ks0 = ksrc0, ks1 = ksrc0 + (size_t)32*QKV_N;
    kh_r[0] = *(const h16x8*)&qkvh[ks0];  kl_r[0] = *(const h16x8*)&qkvl[ks0];
    kh_r[1] = *(const h16x8*)&qkvh[ks1];  kl_r[1] = *(const h16x8*)&qkvl[ks1];
    size_t vs0 = vsrc0, vs1 = vsrc0 + 32*1024;
    vh_r[0] = *(const h16x8*)&vth_g[vs0]; vl_r[0] = *(const h16x8*)&vtl_g[vs0];
    vh_r[1] = *(const h16x8*)&vth_g[vs1]; vl_r[1] = *(const h16x8*)&vtl_g[vs1];
  }
  __syncthreads();   // Q-frag reads done everywhere; pool reusable

  for (int kt=0; kt<16; kt++){
    int key0 = kt*64;
    // store staged K/V regs -> LDS (swizzled, conflict-free 16B stripes)
    {
      int o0 = (tid*8) ^ rsw, o1 = (2048 + tid*8) ^ rsw;
      *(h16x8*)&Khi[o0] = kh_r[0];  *(h16x8*)&Khi[o1] = kh_r[1];
      *(h16x8*)&Klo[o0] = kl_r[0];  *(h16x8*)&Klo[o1] = kl_r[1];
      *(h16x8*)&Vth[o0] = vh_r[0];  *(h16x8*)&Vth[o1] = vh_r[1];
      *(h16x8*)&Vtl[o0] = vl_r[0];  *(h16x8*)&Vtl[o1] = vl_r[1];
    }
    // prefetch tile kt+1 into regs (hides under the whole compute phase)
    if (kt < 15){
      size_t ks0 = ksrc0 + (size_t)(key0+64)*QKV_N, ks1 = ks0 + (size_t)32*QKV_N;
      kh_r[0] = *(const h16x8*)&qkvh[ks0];  kl_r[0] = *(const h16x8*)&qkvl[ks0];
      kh_r[1] = *(const h16x8*)&qkvh[ks1];  kl_r[1] = *(const h16x8*)&qkvl[ks1];
      size_t vs0 = vsrc0 + (key0+64), vs1 = vs0 + 32*1024;
      vh_r[0] = *(const h16x8*)&vth_g[vs0]; vl_r[0] = *(const h16x8*)&vtl_g[vs0];
      vh_r[1] = *(const h16x8*)&vth_g[vs1]; vl_r[1] = *(const h16x8*)&vtl_g[vs1];
    }
    __syncthreads();   // K/V tile visible
    // ---- QK^T ----
    f32x4 sacc[2][4] = {};
    __builtin_amdgcn_s_setprio(1);
    #pragma unroll
    for (int p=0;p<2;p++){
      h16x8 kh[4], kl[4];
      #pragma unroll
      for (int j=0;j<4;j++){
        int kidx = ((j*16+lrow)*64 + p*32 + quad*8) ^ fsw;
        kh[j] = *(const h16x8*)&Khi[kidx];
        kl[j] = *(const h16x8*)&Klo[kidx];
      }
      #pragma unroll
      for (int i=0;i<2;i++)
        #pragma unroll
        for (int j=0;j<4;j++){
          sacc[i][j] = mfma16(qfh[p][i], kh[j], sacc[i][j]);
          sacc[i][j] = mfma16(qfh[p][i], kl[j], sacc[i][j]);
          sacc[i][j] = mfma16(qfl[p][i], kh[j], sacc[i][j]);
        }
    }
    __builtin_amdgcn_s_setprio(0);
    // ---- online softmax over 64 keys ----
    #pragma unroll
    for (int i=0;i<2;i++){
      #pragma unroll
      for (int r=0;r<4;r++){
        int qrow = q0 + wvx*32 + i*16 + quad*4 + r;
        float s[4];
        #pragma unroll
        for (int j=0;j<4;j++){
          float sv = sacc[i][j][r] * 0.125f;
          if (useMask) sv += ldin(mask, (size_t)qrow*S_LEN + key0 + j*16 + lrow, is32);
          s[j] = sv;
        }
        float mx = fmaxf(fmaxf(s[0],s[1]), fmaxf(s[2],s[3]));
        #pragma unroll
        for (int mm=1; mm<=8; mm<<=1) mx = fmaxf(mx, __shfl_xor(mx, mm, 64));
        float mnew = fmaxf(mrun[i][r], mx);
        float alpha = __expf(mrun[i][r] - mnew);
        float ps = 0.f;
        #pragma unroll
        for (int j=0;j<4;j++){
          float p = __expf(s[j] - mnew);
          s[j] = p;
          ps += p;
        }
        #pragma unroll
        for (int mm=1; mm<=8; mm<<=1) ps += __shfl_xor(ps, mm, 64);
        lrun[i][r] = lrun[i][r]*alpha + ps;
        mrun[i][r] = mnew;
        #pragma unroll
        for (int jd=0;jd<4;jd++) oacc[i][jd][r] *= alpha;
        int prow = wvx*32 + i*16 + quad*4 + r;
        int pswz = (prow&7)<<3;
        #pragma unroll
        for (int j=0;j<4;j++){
          int pidx = (prow*64 + j*16 + lrow) ^ pswz;
          float pv = s[j];
          _Float16 ph = (_Float16)pv;
          Phi[pidx] = ph;
          Plo[pidx] = (_Float16)(pv - (float)ph);
        }
      }
    }
    __syncthreads();   // P visible; K reads done
    // ---- PV ----
    {
      h16x8 pf[2][2], pl[2][2];
      #pragma unroll
      for (int i=0;i<2;i++)
        #pragma unroll
        for (int ks=0;ks<2;ks++){
          int pidx = ((wvx*32 + i*16 + lrow)*64 + ks*32 + quad*8) ^ fsw;
          pf[i][ks] = *(const h16x8*)&Phi[pidx];
          pl[i][ks] = *(const h16x8*)&Plo[pidx];
        }
      __builtin_amdgcn_s_setprio(1);
      #pragma unroll
      for (int ks=0;ks<2;ks++){
        h16x8 vh[4], vl[4];
        #pragma unroll
        for (int jd=0;jd<4;jd++){
          int vidx = ((jd*16+lrow)*64 + ks*32 + quad*8) ^ fsw;
          vh[jd] = *(const h16x8*)&Vth[vidx];
          vl[jd] = *(const h16x8*)&Vtl[vidx];
        }
        #pragma unroll
        for (int i=0;i<2;i++)
          #pragma unroll
          for (int jd=0;jd<4;jd++){
            oacc[i][jd] = mfma16(pf[i][ks], vh[jd], oacc[i][jd]);
            oacc[i][jd] = mfma16(pf[i][ks], vl[jd], oacc[i][jd]);
            oacc[i][jd] = mfma16(pl[i][ks], vh[jd], oacc[i][jd]);
          }
      }
      __builtin_amdgcn_s_setprio(0);
    }
    __syncthreads();   // V/P reads done; next iter may overwrite
  }
  #pragma unroll
  for (int i=0;i<2;i++)
    #pragma unroll
    for (int j=0;j<4;j++)
      #pragma unroll
      for (int r=0;r<4;r++){
        int row = q0 + wvx*32 + i*16 + quad*4 + r;
        int col = h*64 + j*16 + lrow;
        size_t idx = (tok0 + row)*H_DIM + col;
        float v = oacc[i][j][r] / lrun[i][r];
        _Float16 hh = (_Float16)v;
        ohi[idx] = hh;
        olo[idx] = (_Float16)(v - (float)hh);
      }
}

// ---------------- RMSNorm #2 + router (fp32 logits, top-2) ----------------
__global__ __launch_bounds__(256) void k_rms2_router(const float* __restrict__ x1, const void* __restrict__ w,
    const void* __restrict__ rw, _Float16* __restrict__ h2,
    int* __restrict__ tok_e, float* __restrict__ tok_w, int* __restrict__ counts,
    const int* __restrict__ df){
  const int is32 = *df;
  int t = blockIdx.x, tid = threadIdx.x;
  f32x4 v = *(const f32x4*)&x1[(size_t)t*H_DIM + tid*4];
  float ss = v[0]*v[0]+v[1]*v[1]+v[2]*v[2]+v[3]*v[3];
  #pragma unroll
  for (int off=32; off>0; off>>=1) ss += __shfl_down(ss, off, 64);
  __shared__ float red[4];
  __shared__ float lgs[32];
  if ((tid&63)==0) red[tid>>6] = ss;
  __syncthreads();
  float rstd = rsqrt_acc((red[0]+red[1]+red[2]+red[3])*(1.0f/H_DIM) + 1e-6f);
  float hv[4];
  h16x4 hst;
  #pragma unroll
  for (int m=0;m<4;m++){ hv[m] = v[m]*rstd*ldin(w, tid*4+m, is32); hst[m] = (_Float16)hv[m]; }
  *(h16x4*)&h2[(size_t)t*H_DIM + tid*4] = hst;
  float part[8] = {0,0,0,0,0,0,0,0};
  #pragma unroll
  for (int m=0;m<4;m++){
    size_t c = (size_t)(tid*4 + m)*8;
    #pragma unroll
    for (int e=0;e<8;e++) part[e] += hv[m]*ldin(rw, c+e, is32);
  }
  #pragma unroll
  for (int e=0;e<8;e++){
    #pragma unroll
    for (int off=32; off>0; off>>=1) part[e] += __shfl_down(part[e], off, 64);
  }
  if ((tid&63)==0){
    #pragma unroll
    for (int e=0;e<8;e++) lgs[(tid>>6)*8 + e] = part[e];
  }
  __syncthreads();
  if (tid==0){
    float lg[8];
    #pragma unroll
    for (int e=0;e<8;e++) lg[e] = lgs[e] + lgs[8+e] + lgs[16+e] + lgs[24+e];
    int e0 = 0;
    #pragma unroll
    for (int e=1;e<8;e++) if (lg[e] > lg[e0]) e0 = e;
    int e1 = (e0==0) ? 1 : 0;
    #pragma unroll
    for (int e=0;e<8;e++) if (e != e0 && lg[e] > lg[e1]) e1 = e;
    float d = expf(lg[e1] - lg[e0]);
    float w0 = 1.0f/(1.0f + d);
    float w1 = d * w0;
    tok_e[t*2] = e0; tok_e[t*2+1] = e1;
    tok_w[t*2] = w0; tok_w[t*2+1] = w1;
    atomicAdd(&counts[e0], 1);
    atomicAdd(&counts[e1], 1);
  }
}

// ---------------- expert offsets (padded prefix) ----------------
__global__ void k_offsets(const int* __restrict__ counts, int* __restrict__ offs, int* __restrict__ fillpos){
  if (threadIdx.x == 0 && blockIdx.x == 0){
    int o = 0;
    for (int e=0;e<8;e++){
      offs[e] = o; fillpos[e] = o;
      o += (counts[e] + 127) & ~127;
    }
    offs[8] = o;
  }
}

// ---------------- fill compact token lists ----------------
__global__ __launch_bounds__(256) void k_fill(const int* __restrict__ tok_e, const float* __restrict__ tok_w,
    int* __restrict__ fillpos, int* __restrict__ list_ts, float* __restrict__ list_w){
  int t = blockIdx.x*256 + threadIdx.x;
  if (t >= T_TOK) return;
  #pragma unroll
  for (int s=0;s<2;s++){
    int e = tok_e[t*2+s];
    int p = atomicAdd(&fillpos[e], 1);
    list_ts[p] = t*2 + s;
    list_w[p] = tok_w[t*2+s];
  }
}

// ======== HOT PATH: pre-transposed f16 weights + global_load_lds staging ========

// gate+up GEMM, B^T [e][n=4096][k=1024] f16; tile 128m x (64 gate + 64 up), BK=32
__global__ __launch_bounds__(256) void k_gemm_gu_t(const _Float16* __restrict__ h2,
    const _Float16* __restrict__ gwt, _Float16* __restrict__ act, const int* __restrict__ list_ts,
    const int* __restrict__ counts, const int* __restrict__ offs){
  int m0 = blockIdx.y<<7;
  if (m0 >= offs[8]) return;
  int e = 0;
  while (m0 >= offs[e+1]) e++;
  int base = offs[e], cnt = counts[e];
  if (m0 >= base + cnt) return;
  __shared__ __align__(16) _Float16 As[128*32], Bg[64*32], Bu[64*32];
  __shared__ int rowtok[128];
  int tid = threadIdx.x;
  if (tid < 128) rowtok[tid] = list_ts[min(m0 + tid, base + cnt - 1)] >> 1;
  __syncthreads();
  int lane = tid&63, wvx = tid>>6, wr = wvx>>1, wc = wvx&1, quad = lane>>4, lrow = lane&15;
  int n0 = blockIdx.x<<6;
  const _Float16* Bge = gwt + (size_t)e*4096*1024 + (size_t)n0*1024;
  const _Float16* Bue = gwt + (size_t)e*4096*1024 + (size_t)(2048+n0)*1024;
  // hoist gathered A row bases (k0-independent)
  const _Float16* arow0 = &h2[(size_t)rowtok[tid>>2]*H_DIM + (tid&3)*8];
  const _Float16* arow1 = &h2[(size_t)rowtok[(256+tid)>>2]*H_DIM + (tid&3)*8];
  int bR = tid>>2, bG = tid&3;
  f32x4 ag[4][2] = {}, au[4][2] = {};
  for (int k0=0; k0<1024; k0+=32){
    gll16(arow0 + k0, &As[(size_t)(wvx*64)*8]);
    gll16(arow1 + k0, &As[(size_t)(256 + wvx*64)*8]);
    gll16(&Bge[(size_t)bR*1024 + k0 + bG*8], &Bg[(size_t)(wvx*64)*8]);
    gll16(&Bue[(size_t)bR*1024 + k0 + bG*8], &Bu[(size_t)(wvx*64)*8]);
    __syncthreads();
    h16x8 a[4], bg[2], bu[2];
    #pragma unroll
    for (int i=0;i<4;i++) a[i] = *(const h16x8*)&As[(wr*64 + i*16 + lrow)*32 + quad*8];
    #pragma unroll
    for (int j=0;j<2;j++){
      bg[j] = *(const h16x8*)&Bg[(wc*32 + j*16 + lrow)*32 + quad*8];
      bu[j] = *(const h16x8*)&Bu[(wc*32 + j*16 + lrow)*32 + quad*8];
    }
    #pragma unroll
    for (int i=0;i<4;i++)
      #pragma unroll
      for (int j=0;j<2;j++){
        ag[i][j] = mfma16(a[i], bg[j], ag[i][j]);
        au[i][j] = mfma16(a[i], bu[j], au[i][j]);
      }
    __syncthreads();
  }
  #pragma unroll
  for (int i=0;i<4;i++)
    #pragma unroll
    for (int j=0;j<2;j++)
      #pragma unroll
      for (int r=0;r<4;r++){
        int row = m0 + wr*64 + i*16 + quad*4 + r;
        int col = n0 + wc*32 + j*16 + lrow;
        float g = ag[i][j][r], u = au[i][j][r];
        float sv = g / (1.0f + __expf(-g));
        act[(size_t)row*INTER_DIM + col] = (_Float16)(sv * u);
      }
}

// down GEMM, B^T [e][n=1024][k=2048] f16; tile 128x128, BK=32; scatter epilogue
__global__ __launch_bounds__(256) void k_gemm_down_t(const _Float16* __restrict__ act,
    const _Float16* __restrict__ dwt, _Float16* __restrict__ slotbuf, const int* __restrict__ list_ts,
    const float* __restrict__ list_w, const int* __restrict__ counts, const int* __restrict__ offs){
  int m0 = blockIdx.y<<7;
  if (m0 >= offs[8]) return;
  int e = 0;
  while (m0 >= offs[e+1]) e++;
  int base = offs[e], cnt = counts[e];
  if (m0 >= base + cnt) return;
  __shared__ __align__(16) _Float16 As[128*32], Bs[128*32];
  int tid = threadIdx.x, lane = tid&63, wvx = tid>>6;
  int wr = wvx>>1, wc = wvx&1, quad = lane>>4, lrow = lane&15;
  int n0 = blockIdx.x<<7;
  const _Float16* Be = dwt + (size_t)e*1024*2048 + (size_t)n0*2048;
  f32x4 acc[4][4] = {};
  for (int k0=0; k0<2048; k0+=32){
    #pragma unroll
    for (int it=0; it<2; it++){
      int c2 = it*256 + tid;
      int r = c2>>2, g = c2&3;
      gll16(&act[(size_t)(m0+r)*INTER_DIM + k0 + g*8], &As[(size_t)(it*256 + wvx*64)*8]);
      gll16(&Be[(size_t)r*2048 + k0 + g*8], &Bs[(size_t)(it*256 + wvx*64)*8]);
    }
    __syncthreads();
    h16x8 a[4], b[4];
    #pragma unroll
    for (int i=0;i<4;i++) a[i] = *(const h16x8*)&As[(wr*64 + i*16 + lrow)*32 + quad*8];
    #pragma unroll
    for (int j=0;j<4;j++) b[j] = *(const h16x8*)&Bs[(wc*64 + j*16 + lrow)*32 + quad*8];
    #pragma unroll
    for (int i=0;i<4;i++)
      #pragma unroll
      for (int j=0;j<4;j++)
        acc[i][j] = mfma16(a[i], b[j], acc[i][j]);
    __syncthreads();
  }
  #pragma unroll
  for (int i=0;i<4;i++)
    #pragma unroll
    for (int r=0;r<4;r++){
      int m = m0 + wr*64 + i*16 + quad*4 + r;
      if (m < base + cnt){
        int ts = list_ts[m];
        float wgt = list_w[m];
        #pragma unroll
        for (int j=0;j<4;j++){
          int col = n0 + wc*64 + j*16 + lrow;
          slotbuf[(size_t)ts*H_DIM + col] = (_Float16)(wgt * acc[i][j][r]);
        }
      }
    }
}

// ======== LEGACY PATH (ws too small for weight transposes) ========

__global__ __launch_bounds__(256) void k_gemm_gu(const _Float16* __restrict__ h2, const void* __restrict__ guw,
    _Float16* __restrict__ act, const int* __restrict__ list_ts,
    const int* __restrict__ counts, const int* __restrict__ offs, const int* __restrict__ df){
  const int is32 = *df;
  int m0 = blockIdx.y<<7;
  if (m0 >= offs[8]) return;
  int e = 0;
  while (m0 >= offs[e+1]) e++;
  int base = offs[e], cnt = counts[e];
  if (m0 >= base + cnt) return;
  __shared__ __align__(16) _Float16 As[128*32], Bg[64*40], Bu[64*40];
  __shared__ int rowtok[128];
  int tid = threadIdx.x;
  if (tid < 128){
    int mc = min(m0 + tid, base + cnt - 1);
    rowtok[tid] = list_ts[mc] >> 1;
  }
  __syncthreads();
  int lane = tid&63, wvx = tid>>6, wr = wvx>>1, wc = wvx&1, quad = lane>>4, lrow = lane&15;
  int n0 = blockIdx.x<<6;
  size_t ebase = (size_t)e*H_DIM*4096;
  f32x4 ag[4][2] = {}, au[4][2] = {};
  for (int k0=0; k0<1024; k0+=32){
    #pragma unroll
    for (int it=0; it<2; it++){
      int ch = it*256 + tid;
      int r = ch>>2, c = ch&3;
      *(i32x4*)&As[ch*8] = *(const i32x4*)&h2[(size_t)rowtok[r]*H_DIM + k0 + c*8];
    }
    {
      int k = tid>>3, g = tid&7;
      size_t rowb = ebase + (size_t)(k0+k)*4096;
      int ks = kslot_sw(k, g);
      _Float16 tg[8], tu[8];
      if (is32){
        const float* gf = (const float*)guw;
        f32x4 a0 = *(const f32x4*)&gf[rowb + n0 + g*8];
        f32x4 a1 = *(const f32x4*)&gf[rowb + n0 + g*8 + 4];
        f32x4 b0 = *(const f32x4*)&gf[rowb + 2048 + n0 + g*8];
        f32x4 b1 = *(const f32x4*)&gf[rowb + 2048 + n0 + g*8 + 4];
        #pragma unroll
        for (int i=0;i<4;i++){ tg[i]=(_Float16)a0[i]; tg[4+i]=(_Float16)a1[i];
                               tu[i]=(_Float16)b0[i]; tu[4+i]=(_Float16)b1[i]; }
      } else {
        const u16* gb = (const u16*)guw;
        u16x4 a0 = *(const u16x4*)&gb[rowb + n0 + g*8];
        u16x4 a1 = *(const u16x4*)&gb[rowb + n0 + g*8 + 4];
        u16x4 b0 = *(const u16x4*)&gb[rowb + 2048 + n0 + g*8];
        u16x4 b1 = *(const u16x4*)&gb[rowb + 2048 + n0 + g*8 + 4];
        #pragma unroll
        for (int i=0;i<4;i++){ tg[i]=(_Float16)bf2f(a0[i]); tg[4+i]=(_Float16)bf2f(a1[i]);
                               tu[i]=(_Float16)bf2f(b0[i]); tu[4+i]=(_Float16)bf2f(b1[i]); }
      }
      #pragma unroll
      for (int i=0;i<8;i++){
        int n = g*8 + i;
        Bg[n*40 + ks] = tg[i];
        Bu[n*40 + ks] = tu[i];
      }
    }
    __syncthreads();
    h16x8 a[4], bg[2], bu[2];
    #pragma unroll
    for (int i=0;i<4;i++) a[i] = *(const h16x8*)&As[(wr*64 + i*16 + lrow)*32 + quad*8];
    #pragma unroll
    for (int j=0;j<2;j++){
      int n = wc*32 + j*16 + lrow;
      int oct = (quad ^ ((n>>3)&3))*8;
      bg[j] = *(const h16x8*)&Bg[n*40 + oct];
      bu[j] = *(const h16x8*)&Bu[n*40 + oct];
    }
    #pragma unroll
    for (int i=0;i<4;i++)
      #pragma unroll
      for (int j=0;j<2;j++){
        ag[i][j] = mfma16(a[i], bg[j], ag[i][j]);
        au[i][j] = mfma16(a[i], bu[j], au[i][j]);
      }
    __syncthreads();
  }
  #pragma unroll
  for (int i=0;i<4;i++)
    #pragma unroll
    for (int j=0;j<2;j++)
      #pragma unroll
      for (int r=0;r<4;r++){
        int row = m0 + wr*64 + i*16 + quad*4 + r;
        int col = n0 + wc*32 + j*16 + lrow;
        float g = ag[i][j][r], u = au[i][j][r];
        float sv = g / (1.0f + __expf(-g));
        act[(size_t)row*INTER_DIM + col] = (_Float16)(sv * u);
      }
}

__global__ __launch_bounds__(256) void k_gemm_down(const _Float16* __restrict__ act, const void* __restrict__ dw,
    _Float16* __restrict__ slotbuf, const int* __restrict__ list_ts, const float* __restrict__ list_w,
    const int* __restrict__ counts, const int* __restrict__ offs, const int* __restrict__ df){
  const int is32 = *df;
  int m0 = blockIdx.y<<7;
  if (m0 >= offs[8]) return;
  int e = 0;
  while (m0 >= offs[e+1]) e++;
  int base = offs[e], cnt = counts[e];
  if (m0 >= base + cnt) return;
  __shared__ __align__(16) _Float16 As[128*32], Bs[128*40];
  int tid = threadIdx.x, lane = tid&63, wvx = tid>>6;
  int wr = wvx>>1, wc = wvx&1, quad = lane>>4, lrow = lane&15;
  int n0 = blockIdx.x<<7;
  size_t ebase = (size_t)e*INTER_DIM*H_DIM;
  f32x4 acc[4][4] = {};
  for (int k0=0; k0<2048; k0+=32){
    #pragma unroll
    for (int it=0; it<2; it++){
      int ch = it*256 + tid;
      int r = ch>>2, c = ch&3;
      *(i32x4*)&As[ch*8] = *(const i32x4*)&act[(size_t)(m0+r)*INTER_DIM + k0 + c*8];
    }
    {
      int k = tid>>3, g = tid&7;
      size_t rowb = ebase + (size_t)(k0+k)*H_DIM;
      int ks = kslot_sw(k, g);
      #pragma unroll
      for (int p=0;p<2;p++){
        _Float16 tb[8];
        if (is32){
          const float* bf = (const float*)dw;
          f32x4 a0 = *(const f32x4*)&bf[rowb + n0 + p*64 + g*8];
          f32x4 a1 = *(const f32x4*)&bf[rowb + n0 + p*64 + g*8 + 4];
          #pragma unroll
          for (int i=0;i<4;i++){ tb[i]=(_Float16)a0[i]; tb[4+i]=(_Float16)a1[i]; }
        } else {
          const u16* bb = (const u16*)dw;
          u16x4 a0 = *(const u16x4*)&bb[rowb + n0 + p*64 + g*8];
          u16x4 a1 = *(const u16x4*)&bb[rowb + n0 + p*64 + g*8 + 4];
          #pragma unroll
          for (int i=0;i<4;i++){ tb[i]=(_Float16)bf2f(a0[i]); tb[4+i]=(_Float16)bf2f(a1[i]); }
        }
        #pragma unroll
        for (int i=0;i<8;i++){
          int n = p*64 + g*8 + i;
          Bs[n*40 + ks] = tb[i];
        }
      }
    }
    __syncthreads();
    h16x8 a[4], b[4];
    #pragma unroll
    for (int i=0;i<4;i++) a[i] = *(const h16x8*)&As[(wr*64 + i*16 + lrow)*32 + quad*8];
    #pragma unroll
    for (int j=0;j<4;j++){
      int n = wc*64 + j*16 + lrow;
      b[j] = *(const h16x8*)&Bs[n*40 + ((quad ^ ((n>>3)&3))*8)];
    }
    #pragma unroll
    for (int i=0;i<4;i++)
      #pragma unroll
      for (int j=0;j<4;j++)
        acc[i][j] = mfma16(a[i], b[j], acc[i][j]);
    __syncthreads();
  }
  #pragma unroll
  for (int i=0;i<4;i++)
    #pragma unroll
    for (int r=0;r<4;r++){
      int m = m0 + wr*64 + i*16 + quad*4 + r;
      if (m < base + cnt){
        int ts = list_ts[m];
        float wgt = list_w[m];
        #pragma unroll
        for (int j=0;j<4;j++){
          int col = n0 + wc*64 + j*16 + lrow;
          slotbuf[(size_t)ts*H_DIM + col] = (_Float16)(wgt * acc[i][j][r]);
        }
      }
    }
}

// ---------------- final residual add -> dual-dtype out ----------------
__global__ __launch_bounds__(256) void k_final(const float* __restrict__ x1, const _Float16* __restrict__ slot,
                                               void* __restrict__ outv, const int* __restrict__ df){
  const int is32 = *df;
  int i4 = (blockIdx.x*256 + threadIdx.x)*4;
  int t = i4 >> 10, c = i4 & 1023;
  f32x4 a = *(const f32x4*)&x1[i4];
  h16x4 s0 = *(const h16x4*)&slot[(size_t)(t*2)*H_DIM + c];
  h16x4 s1 = *(const h16x4*)&slot[(size_t)(t*2+1)*H_DIM + c];
  if (is32){
    f32x4 o;
    #pragma unroll
    for (int m=0;m<4;m++) o[m] = a[m] + (float)s0[m] + (float)s1[m];
    *(f32x4*)&((float*)outv)[i4] = o;
  } else {
    u16x4 o;
    #pragma unroll
    for (int m=0;m<4;m++) o[m] = f2bf(a[m] + (float)s0[m] + (float)s1[m]);
    *(u16x4*)&((u16*)outv)[i4] = o;
  }
}

extern "C" void kernel_launch(void* const* d_in, const int* in_sizes, int n_in,
                              void* d_out, int out_size, void* d_ws, size_t ws_size,
                              hipStream_t stream){
  (void)in_sizes; (void)n_in; (void)out_size;
  const void* x    = d_in[0];
  const void* mask = d_in[1];
  const void* ln1  = d_in[2];
  const void* ln2  = d_in[3];
  const void* qkvw = d_in[4];
  const void* ow   = d_in[5];
  const void* rw   = d_in[6];
  const void* guw  = d_in[7];
  const void* dww  = d_in[8];

  char* ws = (char*)d_ws;
  size_t off = 0;
  auto alloc = [&](size_t b)->void*{ void* p = ws + off; off = (off + b + 255) & ~(size_t)255; return p; };
  int* meta            = (int*)alloc(32*sizeof(int));
  _Float16* qkv_wt     = (_Float16*)alloc((size_t)3072*1024*2);
  _Float16* o_wt       = (_Float16*)alloc((size_t)1024*1024*2);
  _Float16* hpair      = (_Float16*)alloc((size_t)2*4096*1024*2);  // h hi/lo; later aout hi/lo; later slotbuf
  _Float16* qkvpair    = (_Float16*)alloc((size_t)2*4096*3072*2);  // qkv hi/lo; later h2+act
  float* x1            = (float*)alloc((size_t)4096*1024*4);       // V^T hi/lo during attn; then x1
  int* list_ts         = (int*)alloc(MAXROWS*4);
  float* list_w        = (float*)alloc(MAXROWS*4);
  int* tok_e           = (int*)alloc((size_t)4096*2*4);
  float* tok_w         = (float*)alloc((size_t)4096*2*4);
  size_t base_end = off;                                           // ~92 MB
  _Float16* gu_wt      = (_Float16*)alloc((size_t)8*4096*1024*2);  // 67 MB
  _Float16* down_wt    = (_Float16*)alloc((size_t)8*1024*2048*2);  // 34 MB
  const int big = (ws_size >= off) ? 1 : 0;                        // need ~193 MB for hot path
  (void)base_end;

  int* counts = meta;
  int* offs   = meta + 8;
  int* fillpos= meta + 17;
  int* flag   = meta + 25;
  int* dflag  = meta + 26;

  _Float16* h_hi   = hpair;
  _Float16* h_lo   = hpair + (size_t)4096*1024;
  _Float16* qkv_hi = qkvpair;
  _Float16* qkv_lo = qkvpair + (size_t)4096*3072;
  _Float16* vth    = (_Float16*)x1;                     // 8 MB
  _Float16* vtl    = vth + (size_t)64*64*1024;          // 8 MB
  _Float16* ahi    = hpair;                             // aout hi (h dead)
  _Float16* alo    = hpair + (size_t)4096*1024;         // aout lo
  _Float16* h2     = qkvpair;                           // qkv dead after attn
  _Float16* act    = qkvpair + (size_t)4096*1024;
  _Float16* slotbuf= hpair;                             // aout dead after o-proj

  hipMemsetAsync(meta, 0, 32*sizeof(int), stream);
  k_detect<<<dim3(1), dim3(64), 0, stream>>>((const uint32_t*)x, dflag);
  k_trans2<<<dim3(48, 16, 1), 256, 0, stream>>>(qkvw, qkv_wt, 1024, 3072, dflag);
  k_trans2<<<dim3(16, 16, 1), 256, 0, stream>>>(ow, o_wt, 1024, 1024, dflag);
  if (big){
    k_trans2<<<dim3(64, 16, 8), 256, 0, stream>>>(guw, gu_wt, 1024, 4096, dflag);
    k_trans2<<<dim3(16, 32, 8), 256, 0, stream>>>(dww, down_wt, 2048, 1024, dflag);
  }
  k_maskchk<<<dim3(1024), 256, 0, stream>>>(mask, flag, dflag);
  k_rms1<<<dim3(4096), 256, 0, stream>>>(x, ln1, h_hi, h_lo, dflag);
  k_gemm_hl<0><<<dim3(24, 32), 256, 0, stream>>>(h_hi, h_lo, qkv_wt, nullptr, qkv_hi, qkv_lo,
                                                 nullptr, 3072, 1024, dflag);
  k_vt<<<dim3(16, 64), 256, 0, stream>>>(qkv_hi, qkv_lo, vth, vtl);
  k_attn<<<dim3(8, 64), 256, 0, stream>>>(qkv_hi, qkv_lo, vth, vtl, mask, flag, ahi, alo, dflag);
  k_gemm_hl<1><<<dim3(8, 32), 256, 0, stream>>>(ahi, alo, o_wt, x1, nullptr, nullptr,
                                                x, 1024, 1024, dflag);
  k_rms2_router<<<dim3(4096), 256, 0, stream>>>(x1, ln2, rw, h2, tok_e, tok_w, counts, dflag);
  k_offsets<<<dim3(1), dim3(64), 0, stream>>>(counts, offs, fillpos);
  k_fill<<<dim3(16), 256, 0, stream>>>(tok_e, tok_w, fillpos, list_ts, list_w);
  if (big){
    k_gemm_gu_t<<<dim3(32, 72), 256, 0, stream>>>(h2, gu_wt, act, list_ts, counts, offs);
    k_gemm_down_t<<<dim3(8, 72), 256, 0, stream>>>(act, down_wt, slotbuf, list_ts, list_w, counts, offs);
  } else {
    k_gemm_gu<<<dim3(32, 72), 256, 0, stream>>>(h2, guw, act, list_ts, counts, offs, dflag);
    k_gemm_down<<<dim3(8, 72), 256, 0, stream>>>(act, dww, slotbuf, list_ts, list_w, counts, offs, dflag);
  }
  k_final<<<dim3(4096), 256, 0, stream>>>(x1, slotbuf, d_out, dflag);
}

// Round 3
// 845.524 us; speedup vs baseline: 1.0881x; 1.0045x over previous
//
#include <hip/hip_runtime.h>
#include <cstdint>
#include <cmath>

// Problem constants (B=4, S=1024)
#define T_TOK 4096
#define H_DIM 1024
#define QKV_N 3072
#define S_LEN 1024
#define INTER_DIM 2048
#define MAXROWS 9216   // 2*T + 8*127 padding, rounded

typedef unsigned short u16;
using f32x4 = __attribute__((ext_vector_type(4))) float;
using h16x8 = __attribute__((ext_vector_type(8))) _Float16;
using h16x4 = __attribute__((ext_vector_type(4))) _Float16;
using i32x4 = __attribute__((ext_vector_type(4))) int;
using u16x4 = __attribute__((ext_vector_type(4))) u16;
using u16x8 = __attribute__((ext_vector_type(8))) u16;

__device__ __forceinline__ float bf2f(u16 u){ return __uint_as_float(((uint32_t)u)<<16); }
__device__ __forceinline__ u16 f2bf(float f){
  uint32_t x = __float_as_uint(f);
  uint32_t r = x + 0x7FFFu + ((x>>16)&1u);
  return (u16)(r>>16);
}
__device__ __forceinline__ f32x4 mfma16(h16x8 a, h16x8 b, f32x4 c){
  return __builtin_amdgcn_mfma_f32_16x16x32_f16(a,b,c,0,0,0);
}
__device__ __forceinline__ float rsqrt_acc(float v){
  float r = rsqrtf(v);
  r = r*(1.5f - 0.5f*v*r*r);
  r = r*(1.5f - 0.5f*v*r*r);
  return r;
}
// dual-dtype scalar input read
__device__ __forceinline__ float ldin(const void* p, size_t i, int is32){
  return is32 ? ((const float*)p)[i] : bf2f(((const u16*)p)[i]);
}
// swizzled k-slot for stride-40 B tiles (legacy path)
__device__ __forceinline__ int kslot_sw(int k, int noct){
  return (k&7) | (((k>>3) ^ (noct&3))<<3);
}
// async global->LDS, 16B per lane; lds base must be wave-uniform, lanes land at base+lane*16
__device__ __forceinline__ void gll16(const void* g, void* l){
  __builtin_amdgcn_global_load_lds(
      (const __attribute__((address_space(1))) void*)g,
      (__attribute__((address_space(3))) void*)l, 16, 0, 0);
}

// ---------------- dtype detection: fp32 exponent fields of N(0,1) data ----------------
__global__ void k_detect(const uint32_t* __restrict__ x, int* __restrict__ dflag){
  uint32_t u = x[threadIdx.x];
  int e = (u>>23)&0xFF;
  int ok = (e>=103 && e<=150);            // |f| in [2^-24, 2^23]
  unsigned long long m = __ballot(ok);
  if (threadIdx.x==0) *dflag = (__popcll(m) >= 48) ? 1 : 0;
}

// ---------------- vectorized transpose + cast to f16: src [R][C] -> dst [C][R] ------
// 64x64 tiles; conflict-free LDS (stride 65); 16B global loads/stores
__global__ __launch_bounds__(256) void k_trans2(const void* __restrict__ src,
    _Float16* __restrict__ dst, int R, int C, const int* __restrict__ df){
  const int is32 = *df;
  __shared__ _Float16 t[64][65];
  size_t bo = (size_t)blockIdx.z * R * C;
  int c0 = blockIdx.x<<6, r0 = blockIdx.y<<6;
  int ty = threadIdx.x>>3, tx = threadIdx.x&7;   // ty 0..31, tx 0..7
  #pragma unroll
  for (int rr=0; rr<2; rr++){
    int r = rr*32 + ty;
    size_t gi = bo + (size_t)(r0+r)*C + c0 + tx*8;
    _Float16 v[8];
    if (is32){
      f32x4 a0 = *(const f32x4*)&((const float*)src)[gi];
      f32x4 a1 = *(const f32x4*)&((const float*)src)[gi+4];
      #pragma unroll
      for (int i=0;i<4;i++){ v[i]=(_Float16)a0[i]; v[4+i]=(_Float16)a1[i]; }
    } else {
      u16x8 a = *(const u16x8*)&((const u16*)src)[gi];
      #pragma unroll
      for (int i=0;i<8;i++) v[i]=(_Float16)bf2f(a[i]);
    }
    #pragma unroll
    for (int i=0;i<8;i++) t[r][tx*8+i] = v[i];
  }
  __syncthreads();
  #pragma unroll
  for (int rr=0; rr<2; rr++){
    int n = rr*32 + ty;
    h16x8 v;
    #pragma unroll
    for (int i=0;i<8;i++) v[i] = t[tx*8+i][n];
    *(h16x8*)&dst[bo + (size_t)(c0+n)*R + r0 + tx*8] = v;
  }
}

// ---------------- mask all-zero check ----------------
__global__ __launch_bounds__(256) void k_maskchk(const void* __restrict__ m, int* __restrict__ flag,
                                                 const int* __restrict__ df){
  const int is32 = *df;
  int i = (blockIdx.x*256 + threadIdx.x)*4;
  int nz = 0;
  if (is32){
    f32x4 v = *(const f32x4*)&((const float*)m)[i];
    nz = (v[0]!=0.f)||(v[1]!=0.f)||(v[2]!=0.f)||(v[3]!=0.f);
  } else {
    u16x4 v = *(const u16x4*)&((const u16*)m)[i];
    nz = ((v[0]|v[1]|v[2]|v[3]) & 0x7FFF) != 0;
  }
  if (nz) atomicOr(flag, 1);
}

// ---------------- RMSNorm #1: x -> pre-split f16 hi/lo h ----------------
__global__ __launch_bounds__(256) void k_rms1(const void* __restrict__ x, const void* __restrict__ w,
                                              _Float16* __restrict__ hhi, _Float16* __restrict__ hlo,
                                              const int* __restrict__ df){
  const int is32 = *df;
  int t = blockIdx.x, tid = threadIdx.x;
  size_t base = (size_t)t*H_DIM + tid*4;
  float f[4];
  #pragma unroll
  for (int m=0;m<4;m++) f[m] = ldin(x, base+m, is32);
  float ss = f[0]*f[0] + f[1]*f[1] + f[2]*f[2] + f[3]*f[3];
  #pragma unroll
  for (int off=32; off>0; off>>=1) ss += __shfl_down(ss, off, 64);
  __shared__ float red[4];
  if ((tid & 63) == 0) red[tid>>6] = ss;
  __syncthreads();
  float rstd = rsqrt_acc((red[0]+red[1]+red[2]+red[3]) * (1.0f/H_DIM) + 1e-6f);
  h16x4 oh, ol;
  #pragma unroll
  for (int m=0;m<4;m++){
    float v = f[m]*rstd*ldin(w, tid*4+m, is32);
    _Float16 hh = (_Float16)v;
    oh[m] = hh;
    ol[m] = (_Float16)(v - (float)hh);
  }
  *(h16x4*)&hhi[base] = oh;
  *(h16x4*)&hlo[base] = ol;
}

// ---------------- high-precision GEMM: pre-split f16 hi/lo A, f16 B^T --------------
// BK=64, both-sides XOR swizzle (pre-swizzled gll16 source chunk + swizzled ds_read).
// EPI==0: write C as f16 hi/lo pair. EPI==1: fp32 C with residual add.
template<int EPI>
__global__ __launch_bounds__(256) void k_gemm_hl(const _Float16* __restrict__ Ah,
    const _Float16* __restrict__ Al, const _Float16* __restrict__ Bt,
    float* __restrict__ C, _Float16* __restrict__ Chi, _Float16* __restrict__ Clo,
    const void* __restrict__ res, int N, int K, const int* __restrict__ df){
  const int is32 = (EPI==1) ? *df : 0;
  __shared__ __align__(16) _Float16 AhS[128*64];
  __shared__ __align__(16) _Float16 AlS[128*64];
  __shared__ __align__(16) _Float16 Bs[128*64];
  int tid = threadIdx.x, lane = tid&63, wvx = tid>>6;
  int wr = wvx>>1, wc = wvx&1, quad = lane>>4, lrow = lane&15;
  int m0 = blockIdx.y<<7, n0 = blockIdx.x<<7;
  // staging geometry: thread covers row srow(+32*ro), swizzled chunk csw
  int srow = tid>>3;
  int csw  = (tid&7) ^ (srow&7);
  int fsw  = lrow&7;
  const _Float16* pah = &Ah[(size_t)(m0+srow)*K + csw*8];
  const _Float16* pal = &Al[(size_t)(m0+srow)*K + csw*8];
  const _Float16* pbt = &Bt[(size_t)(n0+srow)*K + csw*8];
  f32x4 acc[4][4] = {};
  for (int k0=0; k0<K; k0+=64){
    #pragma unroll
    for (int ro=0; ro<4; ro++){
      size_t rs = (size_t)(ro*32)*K + k0;
      gll16(pah + rs, &AhS[ro*2048 + wvx*512]);
      gll16(pal + rs, &AlS[ro*2048 + wvx*512]);
      gll16(pbt + rs, &Bs [ro*2048 + wvx*512]);
    }
    __syncthreads();
    #pragma unroll
    for (int ks=0; ks<2; ks++){
      int co = ((ks*4 + quad) ^ fsw)*8;
      h16x8 ah[4], al[4], bb[4];
      #pragma unroll
      for (int i=0;i<4;i++){
        int ra = (wr*64 + i*16 + lrow)*64;
        ah[i] = *(const h16x8*)&AhS[ra + co];
        al[i] = *(const h16x8*)&AlS[ra + co];
      }
      #pragma unroll
      for (int j=0;j<4;j++) bb[j] = *(const h16x8*)&Bs[(wc*64 + j*16 + lrow)*64 + co];
      #pragma unroll
      for (int i=0;i<4;i++)
        #pragma unroll
        for (int j=0;j<4;j++){
          acc[i][j] = mfma16(ah[i], bb[j], acc[i][j]);
          acc[i][j] = mfma16(al[i], bb[j], acc[i][j]);
        }
    }
    __syncthreads();
  }
  #pragma unroll
  for (int i=0;i<4;i++)
    #pragma unroll
    for (int j=0;j<4;j++){
      int col = n0 + wc*64 + j*16 + lrow;
      #pragma unroll
      for (int r=0;r<4;r++){
        int row = m0 + wr*64 + i*16 + quad*4 + r;
        size_t idx = (size_t)row*N + col;
        float v = acc[i][j][r];
        if (EPI==1){
          v += ldin(res, idx, is32);
          C[idx] = v;
        } else {
          _Float16 hh = (_Float16)v;
          Chi[idx] = hh;
          Clo[idx] = (_Float16)(v - (float)hh);
        }
      }
    }
}

// ---------------- V^T prep: qkv hi/lo V-slice -> [bh][64 d][1024 keys] f16 hi/lo ----
__global__ __launch_bounds__(256) void k_vt(const _Float16* __restrict__ qh,
    const _Float16* __restrict__ ql, _Float16* __restrict__ vth, _Float16* __restrict__ vtl){
  __shared__ _Float16 th[64][72];
  __shared__ _Float16 tl[64][72];
  int bh = blockIdx.y;           // 0..63
  int b = bh>>4, h = bh&15;
  int key0 = blockIdx.x<<6;      // 16 tiles of 64 keys
  size_t tok0 = (size_t)b*S_LEN;
  int ty = threadIdx.x>>3, tx = threadIdx.x&7;  // ty 0..31, tx 0..7
  #pragma unroll
  for (int rr=0; rr<2; rr++){
    int r = rr*32 + ty;          // key within tile
    size_t gi = (tok0 + key0 + r)*(size_t)QKV_N + 2048 + h*64 + tx*8;
    h16x8 vh_ = *(const h16x8*)&qh[gi];
    h16x8 vl_ = *(const h16x8*)&ql[gi];
    #pragma unroll
    for (int i=0;i<8;i++){ th[r][tx*8+i] = vh_[i]; tl[r][tx*8+i] = vl_[i]; }
  }
  __syncthreads();
  size_t dbase = (size_t)bh*64*1024;
  #pragma unroll
  for (int rr=0; rr<2; rr++){
    int d = rr*32 + ty;
    h16x8 oh, ol;
    #pragma unroll
    for (int i=0;i<8;i++){ oh[i] = th[tx*8+i][d]; ol[i] = tl[tx*8+i][d]; }
    *(h16x8*)&vth[dbase + (size_t)d*1024 + key0 + tx*8] = oh;
    *(h16x8*)&vtl[dbase + (size_t)d*1024 + key0 + tx*8] = ol;
  }
}

// ---------------- flash attention v3: KVBLK=64, reg-prefetch staging, swizzled LDS --
// LDS pool 64KB: Khi[64k][64d] 8KB, Klo 8KB, Vth[64d][64k] 8KB, Vtl 8KB,
//                Phi[128r][64k] 16KB, Plo 16KB. Q staged through pool[0..16383] once.
__global__ __launch_bounds__(256, 2) void k_attn(const _Float16* __restrict__ qkvh,
    const _Float16* __restrict__ qkvl, const _Float16* __restrict__ vth_g,
    const _Float16* __restrict__ vtl_g, const void* __restrict__ mask,
    const int* __restrict__ mflag, _Float16* __restrict__ ohi, _Float16* __restrict__ olo,
    const int* __restrict__ df){
  const int is32 = *df;
  __shared__ __align__(16) _Float16 pool[32768];   // 64 KB
  _Float16* Khi = pool;            // [64 key][64 d], row-XOR swizzled
  _Float16* Klo = pool + 4096;
  _Float16* Vth = pool + 8192;     // [64 d][64 key], row-XOR swizzled
  _Float16* Vtl = pool + 12288;
  _Float16* Phi = pool + 16384;    // [128 row][64 key], row-XOR swizzled
  _Float16* Plo = pool + 24576;
  int qt = blockIdx.x, bh = blockIdx.y;
  int b = bh>>4, h = bh&15;
  int tid = threadIdx.x, lane = tid&63, wvx = tid>>6, quad = lane>>4, lrow = lane&15;
  size_t tok0 = (size_t)b*S_LEN;
  int q0 = qt<<7;
  // ---- stage Q hi/lo (32KB) into pool, pull fragments into registers ----
  {
    int r = tid>>2, cg = (tid&3)*8;
    #pragma unroll
    for (int p=0;p<2;p++)
      #pragma unroll
      for (int g=0;g<2;g++){
        size_t src = (tok0 + q0 + g*64 + r)*(size_t)QKV_N + h*64 + p*32 + cg;
        gll16(&qkvh[src], &pool[p*4096 + g*2048 + wvx*512]);
        gll16(&qkvl[src], &pool[8192 + p*4096 + g*2048 + wvx*512]);
      }
  }
  __syncthreads();
  h16x8 qfh[2][2], qfl[2][2];
  #pragma unroll
  for (int p=0;p<2;p++)
    #pragma unroll
    for (int i=0;i<2;i++){
      qfh[p][i] = *(const h16x8*)&pool[(p*128 + wvx*32 + i*16 + lrow)*32 + quad*8];
      qfl[p][i] = *(const h16x8*)&pool[8192 + (p*128 + wvx*32 + i*16 + lrow)*32 + quad*8];
    }
  int useMask = *mflag;
  float mrun[2][4], lrun[2][4];
  f32x4 oacc[2][4] = {};
  #pragma unroll
  for (int i=0;i<2;i++)
    #pragma unroll
    for (int r=0;r<4;r++){ mrun[i][r] = -INFINITY; lrun[i][r] = 0.f; }
  size_t vbase = (size_t)bh*64*1024;
  // per-thread staging geometry: chunk it covers rows it*32+(tid>>3), 8 halfs at (tid&7)*8
  int krow = tid>>3;                    // 0..31
  int c8   = (tid&7)*8;
  int rsw  = ((tid>>3)&7)<<3;           // store-side row XOR swizzle
  int fsw  = (lrow&7)<<3;               // fragment-read row XOR swizzle
  size_t ksrc0 = (tok0 + krow)*(size_t)QKV_N + 1024 + h*64 + c8;
  size_t vsrc0 = vbase + (size_t)krow*1024 + c8;
  h16x8 kh_r[2], kl_r[2], vh_r[2], vl_r[2];
  // prefetch tile 0 into regs
  {
    size_t ks0 = ksrc0, ks1 = ksrc0 + (size_t)32*QKV_N;
    kh_r[0] = *(const h16x8*)&qkvh[ks0];  kl_r[0] = *(const h16x8*)&qkvl[ks0];
    kh_r[1] = *(const h16x8*)&qkvh[ks1];  kl_r[1] = *(const h16x8*)&qkvl[ks1];
    size_t vs0 = vsrc0, vs1 = vsrc0 + 32*1024;
    vh_r[0] = *(const h16x8*)&vth_g[vs0]; vl_r[0] = *(const h16x8*)&vtl_g[vs0];
    vh_r[1] = *(const h16x8*)&vth_g[vs1]; vl_r[1] = *(const h16x8*)&vtl_g[vs1];
  }
  __syncthreads();   // Q-frag reads done everywhere; pool reusable

  for (int kt=0; kt<16; kt++){
    int key0 = kt*64;
    // store staged K/V regs -> LDS (swizzled, conflict-free 16B stripes)
    {
      int o0 = (tid*8) ^ rsw, o1 = (2048 + tid*8) ^ rsw;
      *(h16x8*)&Khi[o0] = kh_r[0];  *(h16x8*)&Khi[o1] = kh_r[1];
      *(h16x8*)&Klo[o0] = kl_r[0];  *(h16x8*)&Klo[o1] = kl_r[1];
      *(h16x8*)&Vth[o0] = vh_r[0];  *(h16x8*)&Vth[o1] = vh_r[1];
      *(h16x8*)&Vtl[o0] = vl_r[0];  *(h16x8*)&Vtl[o1] = vl_r[1];
    }
    // prefetch tile kt+1 into regs (hides under the whole compute phase)
    if (kt < 15){
      size_t ks0 = ksrc0 + (size_t)(key0+64)*QKV_N, ks1 = ks0 + (size_t)32*QKV_N;
      kh_r[0] = *(const h16x8*)&qkvh[ks0];  kl_r[0] = *(const h16x8*)&qkvl[ks0];
      kh_r[1] = *(const h16x8*)&qkvh[ks1];  kl_r[1] = *(const h16x8*)&qkvl[ks1];
      size_t vs0 = vsrc0 + (key0+64), vs1 = vs0 + 32*1024;
      vh_r[0] = *(const h16x8*)&vth_g[vs0]; vl_r[0] = *(const h16x8*)&vtl_g[vs0];
      vh_r[1] = *(const h16x8*)&vth_g[vs1]; vl_r[1] = *(const h16x8*)&vtl_g[vs1];
    }
    __syncthreads();   // K/V tile visible
    // ---- QK^T ----
    f32x4 sacc[2][4] = {};
    __builtin_amdgcn_s_setprio(1);
    #pragma unroll
    for (int p=0;p<2;p++){
      h16x8 kh[4], kl[4];
      #pragma unroll
      for (int j=0;j<4;j++){
        int kidx = ((j*16+lrow)*64 + p*32 + quad*8) ^ fsw;
        kh[j] = *(const h16x8*)&Khi[kidx];
        kl[j] = *(const h16x8*)&Klo[kidx];
      }
      #pragma unroll
      for (int i=0;i<2;i++)
        #pragma unroll
        for (int j=0;j<4;j++){
          sacc[i][j] = mfma16(qfh[p][i], kh[j], sacc[i][j]);
          sacc[i][j] = mfma16(qfh[p][i], kl[j], sacc[i][j]);
          sacc[i][j] = mfma16(qfl[p][i], kh[j], sacc[i][j]);
        }
    }
    __builtin_amdgcn_s_setprio(0);
    // ---- online softmax over 64 keys ----
    #pragma unroll
    for (int i=0;i<2;i++){
      #pragma unroll
      for (int r=0;r<4;r++){
        int qrow = q0 + wvx*32 + i*16 + quad*4 + r;
        float s[4];
        #pragma unroll
        for (int j=0;j<4;j++){
          float sv = sacc[i][j][r] * 0.125f;
          if (useMask) sv += ldin(mask, (size_t)qrow*S_LEN + key0 + j*16 + lrow, is32);
          s[j] = sv;
        }
        float mx = fmaxf(fmaxf(s[0],s[1]), fmaxf(s[2],s[3]));
        #pragma unroll
        for (int mm=1; mm<=8; mm<<=1) mx = fmaxf(mx, __shfl_xor(mx, mm, 64));
        float mnew = fmaxf(mrun[i][r], mx);
        float alpha = __expf(mrun[i][r] - mnew);
        float ps = 0.f;
        #pragma unroll
        for (int j=0;j<4;j++){
          float p = __expf(s[j] - mnew);
          s[j] = p;
          ps += p;
        }
        #pragma unroll
        for (int mm=1; mm<=8; mm<<=1) ps += __shfl_xor(ps, mm, 64);
        lrun[i][r] = lrun[i][r]*alpha + ps;
        mrun[i][r] = mnew;
        #pragma unroll
        for (int jd=0;jd<4;jd++) oacc[i][jd][r] *= alpha;
        int prow = wvx*32 + i*16 + quad*4 + r;
        int pswz = (prow&7)<<3;
        #pragma unroll
        for (int j=0;j<4;j++){
          int pidx = (prow*64 + j*16 + lrow) ^ pswz;
          float pv = s[j];
          _Float16 ph = (_Float16)pv;
          Phi[pidx] = ph;
          Plo[pidx] = (_Float16)(pv - (float)ph);
        }
      }
    }
    __syncthreads();   // P visible; K reads done
    // ---- PV ----
    {
      h16x8 pf[2][2], pl[2][2];
      #pragma unroll
      for (int i=0;i<2;i++)
        #pragma unroll
        for (int ks=0;ks<2;ks++){
          int pidx = ((wvx*32 + i*16 + lrow)*64 + ks*32 + quad*8) ^ fsw;
          pf[i][ks] = *(const h16x8*)&Phi[pidx];
          pl[i][ks] = *(const h16x8*)&Plo[pidx];
        }
      __builtin_amdgcn_s_setprio(1);
      #pragma unroll
      for (int ks=0;ks<2;ks++){
        h16x8 vh[4], vl[4];
        #pragma unroll
        for (int jd=0;jd<4;jd++){
          int vidx = ((jd*16+lrow)*64 + ks*32 + quad*8) ^ fsw;
          vh[jd] = *(const h16x8*)&Vth[vidx];
          vl[jd] = *(const h16x8*)&Vtl[vidx];
        }
        #pragma unroll
        for (int i=0;i<2;i++)
          #pragma unroll
          for (int jd=0;jd<4;jd++){
            oacc[i][jd] = mfma16(pf[i][ks], vh[jd], oacc[i][jd]);
            oacc[i][jd] = mfma16(pf[i][ks], vl[jd], oacc[i][jd]);
            oacc[i][jd] = mfma16(pl[i][ks], vh[jd], oacc[i][jd]);
          }
      }
      __builtin_amdgcn_s_setprio(0);
    }
    __syncthreads();   // V/P reads done; next iter may overwrite
  }
  #pragma unroll
  for (int i=0;i<2;i++)
    #pragma unroll
    for (int j=0;j<4;j++)
      #pragma unroll
      for (int r=0;r<4;r++){
        int row = q0 + wvx*32 + i*16 + quad*4 + r;
        int col = h*64 + j*16 + lrow;
        size_t idx = (tok0 + row)*H_DIM + col;
        float v = oacc[i][j][r] / lrun[i][r];
        _Float16 hh = (_Float16)v;
        ohi[idx] = hh;
        olo[idx] = (_Float16)(v - (float)hh);
      }
}

// ---------------- RMSNorm #2 + router (fp32 logits, top-2) ----------------
__global__ __launch_bounds__(256) void k_rms2_router(const float* __restrict__ x1, const void* __restrict__ w,
    const void* __restrict__ rw, _Float16* __restrict__ h2,
    int* __restrict__ tok_e, float* __restrict__ tok_w, int* __restrict__ counts,
    const int* __restrict__ df){
  const int is32 = *df;
  int t = blockIdx.x, tid = threadIdx.x;
  f32x4 v = *(const f32x4*)&x1[(size_t)t*H_DIM + tid*4];
  float ss = v[0]*v[0]+v[1]*v[1]+v[2]*v[2]+v[3]*v[3];
  #pragma unroll
  for (int off=32; off>0; off>>=1) ss += __shfl_down(ss, off, 64);
  __shared__ float red[4];
  __shared__ float lgs[32];
  if ((tid&63)==0) red[tid>>6] = ss;
  __syncthreads();
  float rstd = rsqrt_acc((red[0]+red[1]+red[2]+red[3])*(1.0f/H_DIM) + 1e-6f);
  float hv[4];
  h16x4 hst;
  #pragma unroll
  for (int m=0;m<4;m++){ hv[m] = v[m]*rstd*ldin(w, tid*4+m, is32); hst[m] = (_Float16)hv[m]; }
  *(h16x4*)&h2[(size_t)t*H_DIM + tid*4] = hst;
  float part[8] = {0,0,0,0,0,0,0,0};
  #pragma unroll
  for (int m=0;m<4;m++){
    size_t c = (size_t)(tid*4 + m)*8;
    #pragma unroll
    for (int e=0;e<8;e++) part[e] += hv[m]*ldin(rw, c+e, is32);
  }
  #pragma unroll
  for (int e=0;e<8;e++){
    #pragma unroll
    for (int off=32; off>0; off>>=1) part[e] += __shfl_down(part[e], off, 64);
  }
  if ((tid&63)==0){
    #pragma unroll
    for (int e=0;e<8;e++) lgs[(tid>>6)*8 + e] = part[e];
  }
  __syncthreads();
  if (tid==0){
    float lg[8];
    #pragma unroll
    for (int e=0;e<8;e++) lg[e] = lgs[e] + lgs[8+e] + lgs[16+e] + lgs[24+e];
    int e0 = 0;
    #pragma unroll
    for (int e=1;e<8;e++) if (lg[e] > lg[e0]) e0 = e;
    int e1 = (e0==0) ? 1 : 0;
    #pragma unroll
    for (int e=0;e<8;e++) if (e != e0 && lg[e] > lg[e1]) e1 = e;
    float d = expf(lg[e1] - lg[e0]);
    float w0 = 1.0f/(1.0f + d);
    float w1 = d * w0;
    tok_e[t*2] = e0; tok_e[t*2+1] = e1;
    tok_w[t*2] = w0; tok_w[t*2+1] = w1;
    atomicAdd(&counts[e0], 1);
    atomicAdd(&counts[e1], 1);
  }
}

// ---------------- expert offsets (padded prefix) ----------------
__global__ void k_offsets(const int* __restrict__ counts, int* __restrict__ offs, int* __restrict__ fillpos){
  if (threadIdx.x == 0 && blockIdx.x == 0){
    int o = 0;
    for (int e=0;e<8;e++){
      offs[e] = o; fillpos[e] = o;
      o += (counts[e] + 127) & ~127;
    }
    offs[8] = o;
  }
}

// ---------------- fill compact token lists ----------------
__global__ __launch_bounds__(256) void k_fill(const int* __restrict__ tok_e, const float* __restrict__ tok_w,
    int* __restrict__ fillpos, int* __restrict__ list_ts, float* __restrict__ list_w){
  int t = blockIdx.x*256 + threadIdx.x;
  if (t >= T_TOK) return;
  #pragma unroll
  for (int s=0;s<2;s++){
    int e = tok_e[t*2+s];
    int p = atomicAdd(&fillpos[e], 1);
    list_ts[p] = t*2 + s;
    list_w[p] = tok_w[t*2+s];
  }
}

// ======== HOT PATH: pre-transposed f16 weights + global_load_lds staging ========

// gate+up GEMM, B^T [e][n=4096][k=1024] f16; tile 128m x (64 gate + 64 up), BK=64,
// both-sides XOR swizzle
__global__ __launch_bounds__(256) void k_gemm_gu_t(const _Float16* __restrict__ h2,
    const _Float16* __restrict__ gwt, _Float16* __restrict__ act, const int* __restrict__ list_ts,
    const int* __restrict__ counts, const int* __restrict__ offs){
  int m0 = blockIdx.y<<7;
  if (m0 >= offs[8]) return;
  int e = 0;
  while (m0 >= offs[e+1]) e++;
  int base = offs[e], cnt = counts[e];
  if (m0 >= base + cnt) return;
  __shared__ __align__(16) _Float16 As[128*64], Bg[64*64], Bu[64*64];
  __shared__ int rowtok[128];
  int tid = threadIdx.x;
  if (tid < 128) rowtok[tid] = list_ts[min(m0 + tid, base + cnt - 1)] >> 1;
  __syncthreads();
  int lane = tid&63, wvx = tid>>6, wr = wvx>>1, wc = wvx&1, quad = lane>>4, lrow = lane&15;
  int n0 = blockIdx.x<<6;
  const _Float16* Bge = gwt + (size_t)e*4096*1024 + (size_t)n0*1024;
  const _Float16* Bue = gwt + (size_t)e*4096*1024 + (size_t)(2048+n0)*1024;
  int srow = tid>>3;
  int csw  = (tid&7) ^ (srow&7);
  int fsw  = lrow&7;
  // hoisted k0-independent row bases (gathered A rows, contiguous B rows)
  const _Float16* ar0 = &h2[(size_t)rowtok[srow    ]*H_DIM + csw*8];
  const _Float16* ar1 = &h2[(size_t)rowtok[32+srow ]*H_DIM + csw*8];
  const _Float16* ar2 = &h2[(size_t)rowtok[64+srow ]*H_DIM + csw*8];
  const _Float16* ar3 = &h2[(size_t)rowtok[96+srow ]*H_DIM + csw*8];
  const _Float16* bg0 = Bge + (size_t)srow*1024 + csw*8;
  const _Float16* bg1 = Bge + (size_t)(32+srow)*1024 + csw*8;
  const _Float16* bu0 = Bue + (size_t)srow*1024 + csw*8;
  const _Float16* bu1 = Bue + (size_t)(32+srow)*1024 + csw*8;
  f32x4 ag[4][2] = {}, au[4][2] = {};
  for (int k0=0; k0<1024; k0+=64){
    gll16(ar0 + k0, &As[       wvx*512]);
    gll16(ar1 + k0, &As[2048 + wvx*512]);
    gll16(ar2 + k0, &As[4096 + wvx*512]);
    gll16(ar3 + k0, &As[6144 + wvx*512]);
    gll16(bg0 + k0, &Bg[       wvx*512]);
    gll16(bg1 + k0, &Bg[2048 + wvx*512]);
    gll16(bu0 + k0, &Bu[       wvx*512]);
    gll16(bu1 + k0, &Bu[2048 + wvx*512]);
    __syncthreads();
    #pragma unroll
    for (int ks=0; ks<2; ks++){
      int co = ((ks*4 + quad) ^ fsw)*8;
      h16x8 a[4], bgf[2], buf_[2];
      #pragma unroll
      for (int i=0;i<4;i++) a[i] = *(const h16x8*)&As[(wr*64 + i*16 + lrow)*64 + co];
      #pragma unroll
      for (int j=0;j<2;j++){
        bgf[j]  = *(const h16x8*)&Bg[(wc*32 + j*16 + lrow)*64 + co];
        buf_[j] = *(const h16x8*)&Bu[(wc*32 + j*16 + lrow)*64 + co];
      }
      #pragma unroll
      for (int i=0;i<4;i++)
        #pragma unroll
        for (int j=0;j<2;j++){
          ag[i][j] = mfma16(a[i], bgf[j],  ag[i][j]);
          au[i][j] = mfma16(a[i], buf_[j], au[i][j]);
        }
    }
    __syncthreads();
  }
  #pragma unroll
  for (int i=0;i<4;i++)
    #pragma unroll
    for (int j=0;j<2;j++)
      #pragma unroll
      for (int r=0;r<4;r++){
        int row = m0 + wr*64 + i*16 + quad*4 + r;
        int col = n0 + wc*32 + j*16 + lrow;
        float g = ag[i][j][r], u = au[i][j][r];
        float sv = g / (1.0f + __expf(-g));
        act[(size_t)row*INTER_DIM + col] = (_Float16)(sv * u);
      }
}

// down GEMM, B^T [e][n=1024][k=2048] f16; tile 128x128, BK=64, both-sides swizzle;
// scatter epilogue
__global__ __launch_bounds__(256) void k_gemm_down_t(const _Float16* __restrict__ act,
    const _Float16* __restrict__ dwt, _Float16* __restrict__ slotbuf, const int* __restrict__ list_ts,
    const float* __restrict__ list_w, const int* __restrict__ counts, const int* __restrict__ offs){
  int m0 = blockIdx.y<<7;
  if (m0 >= offs[8]) return;
  int e = 0;
  while (m0 >= offs[e+1]) e++;
  int base = offs[e], cnt = counts[e];
  if (m0 >= base + cnt) return;
  __shared__ __align__(16) _Float16 As[128*64], Bs[128*64];
  int tid = threadIdx.x, lane = tid&63, wvx = tid>>6;
  int wr = wvx>>1, wc = wvx&1, quad = lane>>4, lrow = lane&15;
  int n0 = blockIdx.x<<7;
  const _Float16* Be = dwt + (size_t)e*1024*2048 + (size_t)n0*2048;
  int srow = tid>>3;
  int csw  = (tid&7) ^ (srow&7);
  int fsw  = lrow&7;
  const _Float16* pa = &act[(size_t)(m0+srow)*INTER_DIM + csw*8];
  const _Float16* pb = Be + (size_t)srow*2048 + csw*8;
  f32x4 acc[4][4] = {};
  for (int k0=0; k0<2048; k0+=64){
    #pragma unroll
    for (int ro=0; ro<4; ro++){
      size_t rs = (size_t)(ro*32)*2048 + k0;
      gll16(pa + rs, &As[ro*2048 + wvx*512]);
      gll16(pb + rs, &Bs[ro*2048 + wvx*512]);
    }
    __syncthreads();
    #pragma unroll
    for (int ks=0; ks<2; ks++){
      int co = ((ks*4 + quad) ^ fsw)*8;
      h16x8 a[4], b[4];
      #pragma unroll
      for (int i=0;i<4;i++) a[i] = *(const h16x8*)&As[(wr*64 + i*16 + lrow)*64 + co];
      #pragma unroll
      for (int j=0;j<4;j++) b[j] = *(const h16x8*)&Bs[(wc*64 + j*16 + lrow)*64 + co];
      #pragma unroll
      for (int i=0;i<4;i++)
        #pragma unroll
        for (int j=0;j<4;j++)
          acc[i][j] = mfma16(a[i], b[j], acc[i][j]);
    }
    __syncthreads();
  }
  #pragma unroll
  for (int i=0;i<4;i++)
    #pragma unroll
    for (int r=0;r<4;r++){
      int m = m0 + wr*64 + i*16 + quad*4 + r;
      if (m < base + cnt){
        int ts = list_ts[m];
        float wgt = list_w[m];
        #pragma unroll
        for (int j=0;j<4;j++){
          int col = n0 + wc*64 + j*16 + lrow;
          slotbuf[(size_t)ts*H_DIM + col] = (_Float16)(wgt * acc[i][j][r]);
        }
      }
    }
}

// ======== LEGACY PATH (ws too small for weight transposes) ========

__global__ __launch_bounds__(256) void k_gemm_gu(const _Float16* __restrict__ h2, const void* __restrict__ guw,
    _Float16* __restrict__ act, const int* __restrict__ list_ts,
    const int* __restrict__ counts, const int* __restrict__ offs, const int* __restrict__ df){
  const int is32 = *df;
  int m0 = blockIdx.y<<7;
  if (m0 >= offs[8]) return;
  int e = 0;
  while (m0 >= offs[e+1]) e++;
  int base = offs[e], cnt = counts[e];
  if (m0 >= base + cnt) return;
  __shared__ __align__(16) _Float16 As[128*32], Bg[64*40], Bu[64*40];
  __shared__ int rowtok[128];
  int tid = threadIdx.x;
  if (tid < 128){
    int mc = min(m0 + tid, base + cnt - 1);
    rowtok[tid] = list_ts[mc] >> 1;
  }
  __syncthreads();
  int lane = tid&63, wvx = tid>>6, wr = wvx>>1, wc = wvx&1, quad = lane>>4, lrow = lane&15;
  int n0 = blockIdx.x<<6;
  size_t ebase = (size_t)e*H_DIM*4096;
  f32x4 ag[4][2] = {}, au[4][2] = {};
  for (int k0=0; k0<1024; k0+=32){
    #pragma unroll
    for (int it=0; it<2; it++){
      int ch = it*256 + tid;
      int r = ch>>2, c = ch&3;
      *(i32x4*)&As[ch*8] = *(const i32x4*)&h2[(size_t)rowtok[r]*H_DIM + k0 + c*8];
    }
    {
      int k = tid>>3, g = tid&7;
      size_t rowb = ebase + (size_t)(k0+k)*4096;
      int ks = kslot_sw(k, g);
      _Float16 tg[8], tu[8];
      if (is32){
        const float* gf = (const float*)guw;
        f32x4 a0 = *(const f32x4*)&gf[rowb + n0 + g*8];
        f32x4 a1 = *(const f32x4*)&gf[rowb + n0 + g*8 + 4];
        f32x4 b0 = *(const f32x4*)&gf[rowb + 2048 + n0 + g*8];
        f32x4 b1 = *(const f32x4*)&gf[rowb + 2048 + n0 + g*8 + 4];
        #pragma unroll
        for (int i=0;i<4;i++){ tg[i]=(_Float16)a0[i]; tg[4+i]=(_Float16)a1[i];
                               tu[i]=(_Float16)b0[i]; tu[4+i]=(_Float16)b1[i]; }
      } else {
        const u16* gb = (const u16*)guw;
        u16x4 a0 = *(const u16x4*)&gb[rowb + n0 + g*8];
        u16x4 a1 = *(const u16x4*)&gb[rowb + n0 + g*8 + 4];
        u16x4 b0 = *(const u16x4*)&gb[rowb + 2048 + n0 + g*8];
        u16x4 b1 = *(const u16x4*)&gb[rowb + 2048 + n0 + g*8 + 4];
        #pragma unroll
        for (int i=0;i<4;i++){ tg[i]=(_Float16)bf2f(a0[i]); tg[4+i]=(_Float16)bf2f(a1[i]);
                               tu[i]=(_Float16)bf2f(b0[i]); tu[4+i]=(_Float16)bf2f(b1[i]); }
      }
      #pragma unroll
      for (int i=0;i<8;i++){
        int n = g*8 + i;
        Bg[n*40 + ks] = tg[i];
        Bu[n*40 + ks] = tu[i];
      }
    }
    __syncthreads();
    h16x8 a[4], bg[2], bu[2];
    #pragma unroll
    for (int i=0;i<4;i++) a[i] = *(const h16x8*)&As[(wr*64 + i*16 + lrow)*32 + quad*8];
    #pragma unroll
    for (int j=0;j<2;j++){
      int n = wc*32 + j*16 + lrow;
      int oct = (quad ^ ((n>>3)&3))*8;
      bg[j] = *(const h16x8*)&Bg[n*40 + oct];
      bu[j] = *(const h16x8*)&Bu[n*40 + oct];
    }
    #pragma unroll
    for (int i=0;i<4;i++)
      #pragma unroll
      for (int j=0;j<2;j++){
        ag[i][j] = mfma16(a[i], bg[j], ag[i][j]);
        au[i][j] = mfma16(a[i], bu[j], au[i][j]);
      }
    __syncthreads();
  }
  #pragma unroll
  for (int i=0;i<4;i++)
    #pragma unroll
    for (int j=0;j<2;j++)
      #pragma unroll
      for (int r=0;r<4;r++){
        int row = m0 + wr*64 + i*16 + quad*4 + r;
        int col = n0 + wc*32 + j*16 + lrow;
        float g = ag[i][j][r], u = au[i][j][r];
        float sv = g / (1.0f + __expf(-g));
        act[(size_t)row*INTER_DIM + col] = (_Float16)(sv * u);
      }
}

__global__ __launch_bounds__(256) void k_gemm_down(const _Float16* __restrict__ act, const void* __restrict__ dw,
    _Float16* __restrict__ slotbuf, const int* __restrict__ list_ts, const float* __restrict__ list_w,
    const int* __restrict__ counts, const int* __restrict__ offs, const int* __restrict__ df){
  const int is32 = *df;
  int m0 = blockIdx.y<<7;
  if (m0 >= offs[8]) return;
  int e = 0;
  while (m0 >= offs[e+1]) e++;
  int base = offs[e], cnt = counts[e];
  if (m0 >= base + cnt) return;
  __shared__ __align__(16) _Float16 As[128*32], Bs[128*40];
  int tid = threadIdx.x, lane = tid&63, wvx = tid>>6;
  int wr = wvx>>1, wc = wvx&1, quad = lane>>4, lrow = lane&15;
  int n0 = blockIdx.x<<7;
  size_t ebase = (size_t)e*INTER_DIM*H_DIM;
  f32x4 acc[4][4] = {};
  for (int k0=0; k0<2048; k0+=32){
    #pragma unroll
    for (int it=0; it<2; it++){
      int ch = it*256 + tid;
      int r = ch>>2, c = ch&3;
      *(i32x4*)&As[ch*8] = *(const i32x4*)&act[(size_t)(m0+r)*INTER_DIM + k0 + c*8];
    }
    {
      int k = tid>>3, g = tid&7;
      size_t rowb = ebase + (size_t)(k0+k)*H_DIM;
      int ks = kslot_sw(k, g);
      #pragma unroll
      for (int p=0;p<2;p++){
        _Float16 tb[8];
        if (is32){
          const float* bf = (const float*)dw;
          f32x4 a0 = *(const f32x4*)&bf[rowb + n0 + p*64 + g*8];
          f32x4 a1 = *(const f32x4*)&bf[rowb + n0 + p*64 + g*8 + 4];
          #pragma unroll
          for (int i=0;i<4;i++){ tb[i]=(_Float16)a0[i]; tb[4+i]=(_Float16)a1[i]; }
        } else {
          const u16* bb = (const u16*)dw;
          u16x4 a0 = *(const u16x4*)&bb[rowb + n0 + p*64 + g*8];
          u16x4 a1 = *(const u16x4*)&bb[rowb + n0 + p*64 + g*8 + 4];
          #pragma unroll
          for (int i=0;i<4;i++){ tb[i]=(_Float16)bf2f(a0[i]); tb[4+i]=(_Float16)bf2f(a1[i]); }
        }
        #pragma unroll
        for (int i=0;i<8;i++){
          int n = p*64 + g*8 + i;
          Bs[n*40 + ks] = tb[i];
        }
      }
    }
    __syncthreads();
    h16x8 a[4], b[4];
    #pragma unroll
    for (int i=0;i<4;i++) a[i] = *(const h16x8*)&As[(wr*64 + i*16 + lrow)*32 + quad*8];
    #pragma unroll
    for (int j=0;j<4;j++){
      int n = wc*64 + j*16 + lrow;
      b[j] = *(const h16x8*)&Bs[n*40 + ((quad ^ ((n>>3)&3))*8)];
    }
    #pragma unroll
    for (int i=0;i<4;i++)
      #pragma unroll
      for (int j=0;j<4;j++)
        acc[i][j] = mfma16(a[i], b[j], acc[i][j]);
    __syncthreads();
  }
  #pragma unroll
  for (int i=0;i<4;i++)
    #pragma unroll
    for (int r=0;r<4;r++){
      int m = m0 + wr*64 + i*16 + quad*4 + r;
      if (m < base + cnt){
        int ts = list_ts[m];
        float wgt = list_w[m];
        #pragma unroll
        for (int j=0;j<4;j++){
          int col = n0 + wc*64 + j*16 + lrow;
          slotbuf[(size_t)ts*H_DIM + col] = (_Float16)(wgt * acc[i][j][r]);
        }
      }
    }
}

// ---------------- final residual add -> dual-dtype out ----------------
__global__ __launch_bounds__(256) void k_final(const float* __restrict__ x1, const _Float16* __restrict__ slot,
                                               void* __restrict__ outv, const int* __restrict__ df){
  const int is32 = *df;
  int i4 = (blockIdx.x*256 + threadIdx.x)*4;
  int t = i4 >> 10, c = i4 & 1023;
  f32x4 a = *(const f32x4*)&x1[i4];
  h16x4 s0 = *(const h16x4*)&slot[(size_t)(t*2)*H_DIM + c];
  h16x4 s1 = *(const h16x4*)&slot[(size_t)(t*2+1)*H_DIM + c];
  if (is32){
    f32x4 o;
    #pragma unroll
    for (int m=0;m<4;m++) o[m] = a[m] + (float)s0[m] + (float)s1[m];
    *(f32x4*)&((float*)outv)[i4] = o;
  } else {
    u16x4 o;
    #pragma unroll
    for (int m=0;m<4;m++) o[m] = f2bf(a[m] + (float)s0[m] + (float)s1[m]);
    *(u16x4*)&((u16*)outv)[i4] = o;
  }
}

extern "C" void kernel_launch(void* const* d_in, const int* in_sizes, int n_in,
                              void* d_out, int out_size, void* d_ws, size_t ws_size,
                              hipStream_t stream){
  (void)in_sizes; (void)n_in; (void)out_size;
  const void* x    = d_in[0];
  const void* mask = d_in[1];
  const void* ln1  = d_in[2];
  const void* ln2  = d_in[3];
  const void* qkvw = d_in[4];
  const void* ow   = d_in[5];
  const void* rw   = d_in[6];
  const void* guw  = d_in[7];
  const void* dww  = d_in[8];

  char* ws = (char*)d_ws;
  size_t off = 0;
  auto alloc = [&](size_t b)->void*{ void* p = ws + off; off = (off + b + 255) & ~(size_t)255; return p; };
  int* meta            = (int*)alloc(32*sizeof(int));
  _Float16* qkv_wt     = (_Float16*)alloc((size_t)3072*1024*2);
  _Float16* o_wt       = (_Float16*)alloc((size_t)1024*1024*2);
  _Float16* hpair      = (_Float16*)alloc((size_t)2*4096*1024*2);  // h hi/lo; later aout hi/lo; later slotbuf
  _Float16* qkvpair    = (_Float16*)alloc((size_t)2*4096*3072*2);  // qkv hi/lo; later h2+act
  float* x1            = (float*)alloc((size_t)4096*1024*4);       // V^T hi/lo during attn; then x1
  int* list_ts         = (int*)alloc(MAXROWS*4);
  float* list_w        = (float*)alloc(MAXROWS*4);
  int* tok_e           = (int*)alloc((size_t)4096*2*4);
  float* tok_w         = (float*)alloc((size_t)4096*2*4);
  size_t base_end = off;                                           // ~92 MB
  _Float16* gu_wt      = (_Float16*)alloc((size_t)8*4096*1024*2);  // 67 MB
  _Float16* down_wt    = (_Float16*)alloc((size_t)8*1024*2048*2);  // 34 MB
  const int big = (ws_size >= off) ? 1 : 0;                        // need ~193 MB for hot path
  (void)base_end;

  int* counts = meta;
  int* offs   = meta + 8;
  int* fillpos= meta + 17;
  int* flag   = meta + 25;
  int* dflag  = meta + 26;

  _Float16* h_hi   = hpair;
  _Float16* h_lo   = hpair + (size_t)4096*1024;
  _Float16* qkv_hi = qkvpair;
  _Float16* qkv_lo = qkvpair + (size_t)4096*3072;
  _Float16* vth    = (_Float16*)x1;                     // 8 MB
  _Float16* vtl    = vth + (size_t)64*64*1024;          // 8 MB
  _Float16* ahi    = hpair;                             // aout hi (h dead)
  _Float16* alo    = hpair + (size_t)4096*1024;         // aout lo
  _Float16* h2     = qkvpair;                           // qkv dead after attn
  _Float16* act    = qkvpair + (size_t)4096*1024;
  _Float16* slotbuf= hpair;                             // aout dead after o-proj

  hipMemsetAsync(meta, 0, 32*sizeof(int), stream);
  k_detect<<<dim3(1), dim3(64), 0, stream>>>((const uint32_t*)x, dflag);
  k_trans2<<<dim3(48, 16, 1), 256, 0, stream>>>(qkvw, qkv_wt, 1024, 3072, dflag);
  k_trans2<<<dim3(16, 16, 1), 256, 0, stream>>>(ow, o_wt, 1024, 1024, dflag);
  if (big){
    k_trans2<<<dim3(64, 16, 8), 256, 0, stream>>>(guw, gu_wt, 1024, 4096, dflag);
    k_trans2<<<dim3(16, 32, 8), 256, 0, stream>>>(dww, down_wt, 2048, 1024, dflag);
  }
  k_maskchk<<<dim3(1024), 256, 0, stream>>>(mask, flag, dflag);
  k_rms1<<<dim3(4096), 256, 0, stream>>>(x, ln1, h_hi, h_lo, dflag);
  k_gemm_hl<0><<<dim3(24, 32), 256, 0, stream>>>(h_hi, h_lo, qkv_wt, nullptr, qkv_hi, qkv_lo,
                                                 nullptr, 3072, 1024, dflag);
  k_vt<<<dim3(16, 64), 256, 0, stream>>>(qkv_hi, qkv_lo, vth, vtl);
  k_attn<<<dim3(8, 64), 256, 0, stream>>>(qkv_hi, qkv_lo, vth, vtl, mask, flag, ahi, alo, dflag);
  k_gemm_hl<1><<<dim3(8, 32), 256, 0, stream>>>(ahi, alo, o_wt, x1, nullptr, nullptr,
                                                x, 1024, 1024, dflag);
  k_rms2_router<<<dim3(4096), 256, 0, stream>>>(x1, ln2, rw, h2, tok_e, tok_w, counts, dflag);
  k_offsets<<<dim3(1), dim3(64), 0, stream>>>(counts, offs, fillpos);
  k_fill<<<dim3(16), 256, 0, stream>>>(tok_e, tok_w, fillpos, list_ts, list_w);
  if (big){
    k_gemm_gu_t<<<dim3(32, 72), 256, 0, stream>>>(h2, gu_wt, act, list_ts, counts, offs);
    k_gemm_down_t<<<dim3(8, 72), 256, 0, stream>>>(act, down_wt, slotbuf, list_ts, list_w, counts, offs);
  } else {
    k_gemm_gu<<<dim3(32, 72), 256, 0, stream>>>(h2, guw, act, list_ts, counts, offs, dflag);
    k_gemm_down<<<dim3(8, 72), 256, 0, stream>>>(act, dww, slotbuf, list_ts, list_w, counts, offs, dflag);
  }
  k_final<<<dim3(4096), 256, 0, stream>>>(x1, slotbuf, d_out, dflag);
}

// Round 4
// 834.467 us; speedup vs baseline: 1.1025x; 1.0133x over previous
//
#include <hip/hip_runtime.h>
#include <cstdint>
#include <cmath>

// Problem constants (B=4, S=1024)
#define T_TOK 4096
#define H_DIM 1024
#define QKV_N 3072
#define S_LEN 1024
#define INTER_DIM 2048
#define MAXROWS 9216   // 2*T + 8*127 padding, rounded

typedef unsigned short u16;
using f32x4 = __attribute__((ext_vector_type(4))) float;
using h16x8 = __attribute__((ext_vector_type(8))) _Float16;
using h16x4 = __attribute__((ext_vector_type(4))) _Float16;
using i32x4 = __attribute__((ext_vector_type(4))) int;
using u16x4 = __attribute__((ext_vector_type(4))) u16;
using u16x8 = __attribute__((ext_vector_type(8))) u16;

__device__ __forceinline__ float bf2f(u16 u){ return __uint_as_float(((uint32_t)u)<<16); }
__device__ __forceinline__ u16 f2bf(float f){
  uint32_t x = __float_as_uint(f);
  uint32_t r = x + 0x7FFFu + ((x>>16)&1u);
  return (u16)(r>>16);
}
__device__ __forceinline__ f32x4 mfma16(h16x8 a, h16x8 b, f32x4 c){
  return __builtin_amdgcn_mfma_f32_16x16x32_f16(a,b,c,0,0,0);
}
__device__ __forceinline__ float rsqrt_acc(float v){
  float r = rsqrtf(v);
  r = r*(1.5f - 0.5f*v*r*r);
  r = r*(1.5f - 0.5f*v*r*r);
  return r;
}
// dual-dtype scalar input read
__device__ __forceinline__ float ldin(const void* p, size_t i, int is32){
  return is32 ? ((const float*)p)[i] : bf2f(((const u16*)p)[i]);
}
// swizzled k-slot for stride-40 B tiles (legacy path)
__device__ __forceinline__ int kslot_sw(int k, int noct){
  return (k&7) | (((k>>3) ^ (noct&3))<<3);
}
// async global->LDS, 16B per lane; lds base must be wave-uniform, lanes land at base+lane*16
__device__ __forceinline__ void gll16(const void* g, void* l){
  __builtin_amdgcn_global_load_lds(
      (const __attribute__((address_space(1))) void*)g,
      (__attribute__((address_space(3))) void*)l, 16, 0, 0);
}

// ---------------- dtype detection: fp32 exponent fields of N(0,1) data ----------------
__global__ void k_detect(const uint32_t* __restrict__ x, int* __restrict__ dflag){
  uint32_t u = x[threadIdx.x];
  int e = (u>>23)&0xFF;
  int ok = (e>=103 && e<=150);            // |f| in [2^-24, 2^23]
  unsigned long long m = __ballot(ok);
  if (threadIdx.x==0) *dflag = (__popcll(m) >= 48) ? 1 : 0;
}

// ---------------- vectorized transpose + cast to f16: src [R][C] -> dst [C][R] ------
// 64x64 tiles; conflict-free LDS (stride 65); 16B global loads/stores
__global__ __launch_bounds__(256) void k_trans2(const void* __restrict__ src,
    _Float16* __restrict__ dst, int R, int C, const int* __restrict__ df){
  const int is32 = *df;
  __shared__ _Float16 t[64][65];
  size_t bo = (size_t)blockIdx.z * R * C;
  int c0 = blockIdx.x<<6, r0 = blockIdx.y<<6;
  int ty = threadIdx.x>>3, tx = threadIdx.x&7;   // ty 0..31, tx 0..7
  #pragma unroll
  for (int rr=0; rr<2; rr++){
    int r = rr*32 + ty;
    size_t gi = bo + (size_t)(r0+r)*C + c0 + tx*8;
    _Float16 v[8];
    if (is32){
      f32x4 a0 = *(const f32x4*)&((const float*)src)[gi];
      f32x4 a1 = *(const f32x4*)&((const float*)src)[gi+4];
      #pragma unroll
      for (int i=0;i<4;i++){ v[i]=(_Float16)a0[i]; v[4+i]=(_Float16)a1[i]; }
    } else {
      u16x8 a = *(const u16x8*)&((const u16*)src)[gi];
      #pragma unroll
      for (int i=0;i<8;i++) v[i]=(_Float16)bf2f(a[i]);
    }
    #pragma unroll
    for (int i=0;i<8;i++) t[r][tx*8+i] = v[i];
  }
  __syncthreads();
  #pragma unroll
  for (int rr=0; rr<2; rr++){
    int n = rr*32 + ty;
    h16x8 v;
    #pragma unroll
    for (int i=0;i<8;i++) v[i] = t[tx*8+i][n];
    *(h16x8*)&dst[bo + (size_t)(c0+n)*R + r0 + tx*8] = v;
  }
}

// ---------------- mask all-zero check ----------------
__global__ __launch_bounds__(256) void k_maskchk(const void* __restrict__ m, int* __restrict__ flag,
                                                 const int* __restrict__ df){
  const int is32 = *df;
  int i = (blockIdx.x*256 + threadIdx.x)*4;
  int nz = 0;
  if (is32){
    f32x4 v = *(const f32x4*)&((const float*)m)[i];
    nz = (v[0]!=0.f)||(v[1]!=0.f)||(v[2]!=0.f)||(v[3]!=0.f);
  } else {
    u16x4 v = *(const u16x4*)&((const u16*)m)[i];
    nz = ((v[0]|v[1]|v[2]|v[3]) & 0x7FFF) != 0;
  }
  if (nz) atomicOr(flag, 1);
}

// ---------------- RMSNorm #1: x -> pre-split f16 hi/lo h ----------------
__global__ __launch_bounds__(256) void k_rms1(const void* __restrict__ x, const void* __restrict__ w,
                                              _Float16* __restrict__ hhi, _Float16* __restrict__ hlo,
                                              const int* __restrict__ df){
  const int is32 = *df;
  int t = blockIdx.x, tid = threadIdx.x;
  size_t base = (size_t)t*H_DIM + tid*4;
  float f[4];
  #pragma unroll
  for (int m=0;m<4;m++) f[m] = ldin(x, base+m, is32);
  float ss = f[0]*f[0] + f[1]*f[1] + f[2]*f[2] + f[3]*f[3];
  #pragma unroll
  for (int off=32; off>0; off>>=1) ss += __shfl_down(ss, off, 64);
  __shared__ float red[4];
  if ((tid & 63) == 0) red[tid>>6] = ss;
  __syncthreads();
  float rstd = rsqrt_acc((red[0]+red[1]+red[2]+red[3]) * (1.0f/H_DIM) + 1e-6f);
  h16x4 oh, ol;
  #pragma unroll
  for (int m=0;m<4;m++){
    float v = f[m]*rstd*ldin(w, tid*4+m, is32);
    _Float16 hh = (_Float16)v;
    oh[m] = hh;
    ol[m] = (_Float16)(v - (float)hh);
  }
  *(h16x4*)&hhi[base] = oh;
  *(h16x4*)&hlo[base] = ol;
}

// ---------------- high-precision GEMM: pre-split f16 hi/lo A, f16 B^T --------------
// BK=32, double-buffered LDS, prefetch-before-compute pipeline (one barrier/K-step),
// 2-bit both-sides chunk swizzle (chunk ^= row&3) -> 2-way (free) LDS reads.
// EPI==0: write C as f16 hi/lo pair. EPI==1: fp32 C with residual add.
template<int EPI>
__global__ __launch_bounds__(256) void k_gemm_hl(const _Float16* __restrict__ Ah,
    const _Float16* __restrict__ Al, const _Float16* __restrict__ Bt,
    float* __restrict__ C, _Float16* __restrict__ Chi, _Float16* __restrict__ Clo,
    const void* __restrict__ res, int N, int K, const int* __restrict__ df){
  const int is32 = (EPI==1) ? *df : 0;
  __shared__ __align__(16) _Float16 AhS[2][128*32];
  __shared__ __align__(16) _Float16 AlS[2][128*32];
  __shared__ __align__(16) _Float16 Bs[2][128*32];
  int tid = threadIdx.x, lane = tid&63, wvx = tid>>6;
  int wr = wvx>>1, wc = wvx&1, quad = lane>>4, lrow = lane&15;
  int m0 = blockIdx.y<<7, n0 = blockIdx.x<<7;
  // staging geometry: thread covers row srow (+64 for second half), swizzled chunk csw
  int srow = tid>>2;                  // 0..63
  int csw  = (tid&3) ^ (srow&3);
  const _Float16* a0h = &Ah[(size_t)(m0+srow)*K + csw*8];
  const _Float16* a1h = &Ah[(size_t)(m0+64+srow)*K + csw*8];
  const _Float16* a0l = &Al[(size_t)(m0+srow)*K + csw*8];
  const _Float16* a1l = &Al[(size_t)(m0+64+srow)*K + csw*8];
  const _Float16* b0  = &Bt[(size_t)(n0+srow)*K + csw*8];
  const _Float16* b1  = &Bt[(size_t)(n0+64+srow)*K + csw*8];
  auto stage = [&](int bb, int k0){
    gll16(a0h + k0, &AhS[bb][wvx*512]);
    gll16(a1h + k0, &AhS[bb][2048 + wvx*512]);
    gll16(a0l + k0, &AlS[bb][wvx*512]);
    gll16(a1l + k0, &AlS[bb][2048 + wvx*512]);
    gll16(b0  + k0, &Bs[bb][wvx*512]);
    gll16(b1  + k0, &Bs[bb][2048 + wvx*512]);
  };
  f32x4 acc[4][4] = {};
  stage(0, 0);
  __syncthreads();
  int cur = 0;
  int co = (quad ^ (lrow&3))*8;
  for (int k0=0; k0<K; k0+=32){
    if (k0 + 32 < K) stage(cur^1, k0+32);
    h16x8 ah[4], al[4], bb[4];
    #pragma unroll
    for (int i=0;i<4;i++){
      int ra = (wr*64 + i*16 + lrow)*32;
      ah[i] = *(const h16x8*)&AhS[cur][ra + co];
      al[i] = *(const h16x8*)&AlS[cur][ra + co];
    }
    #pragma unroll
    for (int j=0;j<4;j++) bb[j] = *(const h16x8*)&Bs[cur][(wc*64 + j*16 + lrow)*32 + co];
    #pragma unroll
    for (int i=0;i<4;i++)
      #pragma unroll
      for (int j=0;j<4;j++){
        acc[i][j] = mfma16(ah[i], bb[j], acc[i][j]);
        acc[i][j] = mfma16(al[i], bb[j], acc[i][j]);
      }
    __syncthreads();   // drains this iter's prefetch (had full compute to land); P/C swap
    cur ^= 1;
  }
  #pragma unroll
  for (int i=0;i<4;i++)
    #pragma unroll
    for (int j=0;j<4;j++){
      int col = n0 + wc*64 + j*16 + lrow;
      #pragma unroll
      for (int r=0;r<4;r++){
        int row = m0 + wr*64 + i*16 + quad*4 + r;
        size_t idx = (size_t)row*N + col;
        float v = acc[i][j][r];
        if (EPI==1){
          v += ldin(res, idx, is32);
          C[idx] = v;
        } else {
          _Float16 hh = (_Float16)v;
          Chi[idx] = hh;
          Clo[idx] = (_Float16)(v - (float)hh);
        }
      }
    }
}

// ---------------- V^T prep: qkv hi/lo V-slice -> [bh][64 d][1024 keys] f16 hi/lo ----
__global__ __launch_bounds__(256) void k_vt(const _Float16* __restrict__ qh,
    const _Float16* __restrict__ ql, _Float16* __restrict__ vth, _Float16* __restrict__ vtl){
  __shared__ _Float16 th[64][72];
  __shared__ _Float16 tl[64][72];
  int bh = blockIdx.y;           // 0..63
  int b = bh>>4, h = bh&15;
  int key0 = blockIdx.x<<6;      // 16 tiles of 64 keys
  size_t tok0 = (size_t)b*S_LEN;
  int ty = threadIdx.x>>3, tx = threadIdx.x&7;  // ty 0..31, tx 0..7
  #pragma unroll
  for (int rr=0; rr<2; rr++){
    int r = rr*32 + ty;          // key within tile
    size_t gi = (tok0 + key0 + r)*(size_t)QKV_N + 2048 + h*64 + tx*8;
    h16x8 vh_ = *(const h16x8*)&qh[gi];
    h16x8 vl_ = *(const h16x8*)&ql[gi];
    #pragma unroll
    for (int i=0;i<8;i++){ th[r][tx*8+i] = vh_[i]; tl[r][tx*8+i] = vl_[i]; }
  }
  __syncthreads();
  size_t dbase = (size_t)bh*64*1024;
  #pragma unroll
  for (int rr=0; rr<2; rr++){
    int d = rr*32 + ty;
    h16x8 oh, ol;
    #pragma unroll
    for (int i=0;i<8;i++){ oh[i] = th[tx*8+i][d]; ol[i] = tl[tx*8+i][d]; }
    *(h16x8*)&vth[dbase + (size_t)d*1024 + key0 + tx*8] = oh;
    *(h16x8*)&vtl[dbase + (size_t)d*1024 + key0 + tx*8] = ol;
  }
}

// ---------------- flash attention v3: KVBLK=64, reg-prefetch staging, swizzled LDS --
// LDS pool 64KB: Khi[64k][64d] 8KB, Klo 8KB, Vth[64d][64k] 8KB, Vtl 8KB,
//                Phi[128r][64k] 16KB, Plo 16KB. Q staged through pool[0..16383] once.
__global__ __launch_bounds__(256, 2) void k_attn(const _Float16* __restrict__ qkvh,
    const _Float16* __restrict__ qkvl, const _Float16* __restrict__ vth_g,
    const _Float16* __restrict__ vtl_g, const void* __restrict__ mask,
    const int* __restrict__ mflag, _Float16* __restrict__ ohi, _Float16* __restrict__ olo,
    const int* __restrict__ df){
  const int is32 = *df;
  __shared__ __align__(16) _Float16 pool[32768];   // 64 KB
  _Float16* Khi = pool;            // [64 key][64 d], row-XOR swizzled
  _Float16* Klo = pool + 4096;
  _Float16* Vth = pool + 8192;     // [64 d][64 key], row-XOR swizzled
  _Float16* Vtl = pool + 12288;
  _Float16* Phi = pool + 16384;    // [128 row][64 key], row-XOR swizzled
  _Float16* Plo = pool + 24576;
  int qt = blockIdx.x, bh = blockIdx.y;
  int b = bh>>4, h = bh&15;
  int tid = threadIdx.x, lane = tid&63, wvx = tid>>6, quad = lane>>4, lrow = lane&15;
  size_t tok0 = (size_t)b*S_LEN;
  int q0 = qt<<7;
  // ---- stage Q hi/lo (32KB) into pool, pull fragments into registers ----
  {
    int r = tid>>2, cg = (tid&3)*8;
    #pragma unroll
    for (int p=0;p<2;p++)
      #pragma unroll
      for (int g=0;g<2;g++){
        size_t src = (tok0 + q0 + g*64 + r)*(size_t)QKV_N + h*64 + p*32 + cg;
        gll16(&qkvh[src], &pool[p*4096 + g*2048 + wvx*512]);
        gll16(&qkvl[src], &pool[8192 + p*4096 + g*2048 + wvx*512]);
      }
  }
  __syncthreads();
  h16x8 qfh[2][2], qfl[2][2];
  #pragma unroll
  for (int p=0;p<2;p++)
    #pragma unroll
    for (int i=0;i<2;i++){
      qfh[p][i] = *(const h16x8*)&pool[(p*128 + wvx*32 + i*16 + lrow)*32 + quad*8];
      qfl[p][i] = *(const h16x8*)&pool[8192 + (p*128 + wvx*32 + i*16 + lrow)*32 + quad*8];
    }
  int useMask = *mflag;
  float mrun[2][4], lrun[2][4];
  f32x4 oacc[2][4] = {};
  #pragma unroll
  for (int i=0;i<2;i++)
    #pragma unroll
    for (int r=0;r<4;r++){ mrun[i][r] = -INFINITY; lrun[i][r] = 0.f; }
  size_t vbase = (size_t)bh*64*1024;
  // per-thread staging geometry: chunk it covers rows it*32+(tid>>3), 8 halfs at (tid&7)*8
  int krow = tid>>3;                    // 0..31
  int c8   = (tid&7)*8;
  int rsw  = ((tid>>3)&7)<<3;           // store-side row XOR swizzle
  int fsw  = (lrow&7)<<3;               // fragment-read row XOR swizzle
  size_t ksrc0 = (tok0 + krow)*(size_t)QKV_N + 1024 + h*64 + c8;
  size_t vsrc0 = vbase + (size_t)krow*1024 + c8;
  h16x8 kh_r[2], kl_r[2], vh_r[2], vl_r[2];
  // prefetch tile 0 into regs
  {
    size_t ks0 = ksrc0, ks1 = ksrc0 + (size_t)32*QKV_N;
    kh_r[0] = *(const h16x8*)&qkvh[ks0];  kl_r[0] = *(const h16x8*)&qkvl[ks0];
    kh_r[1] = *(const h16x8*)&qkvh[ks1];  kl_r[1] = *(const h16x8*)&qkvl[ks1];
    size_t vs0 = vsrc0, vs1 = vsrc0 + 32*1024;
    vh_r[0] = *(const h16x8*)&vth_g[vs0]; vl_r[0] = *(const h16x8*)&vtl_g[vs0];
    vh_r[1] = *(const h16x8*)&vth_g[vs1]; vl_r[1] = *(const h16x8*)&vtl_g[vs1];
  }
  __syncthreads();   // Q-frag reads done everywhere; pool reusable

  for (int kt=0; kt<16; kt++){
    int key0 = kt*64;
    // store staged K/V regs -> LDS (swizzled, conflict-free 16B stripes)
    {
      int o0 = (tid*8) ^ rsw, o1 = (2048 + tid*8) ^ rsw;
      *(h16x8*)&Khi[o0] = kh_r[0];  *(h16x8*)&Khi[o1] = kh_r[1];
      *(h16x8*)&Klo[o0] = kl_r[0];  *(h16x8*)&Klo[o1] = kl_r[1];
      *(h16x8*)&Vth[o0] = vh_r[0];  *(h16x8*)&Vth[o1] = vh_r[1];
      *(h16x8*)&Vtl[o0] = vl_r[0];  *(h16x8*)&Vtl[o1] = vl_r[1];
    }
    // prefetch tile kt+1 into regs (hides under the whole compute phase)
    if (kt < 15){
      size_t ks0 = ksrc0 + (size_t)(key0+64)*QKV_N, ks1 = ks0 + (size_t)32*QKV_N;
      kh_r[0] = *(const h16x8*)&qkvh[ks0];  kl_r[0] = *(const h16x8*)&qkvl[ks0];
      kh_r[1] = *(const h16x8*)&qkvh[ks1];  kl_r[1] = *(const h16x8*)&qkvl[ks1];
      size_t vs0 = vsrc0 + (key0+64), vs1 = vs0 + 32*1024;
      vh_r[0] = *(const h16x8*)&vth_g[vs0]; vl_r[0] = *(const h16x8*)&vtl_g[vs0];
      vh_r[1] = *(const h16x8*)&vth_g[vs1]; vl_r[1] = *(const h16x8*)&vtl_g[vs1];
    }
    __syncthreads();   // K/V tile visible
    // ---- QK^T ----
    f32x4 sacc[2][4] = {};
    __builtin_amdgcn_s_setprio(1);
    #pragma unroll
    for (int p=0;p<2;p++){
      h16x8 kh[4], kl[4];
      #pragma unroll
      for (int j=0;j<4;j++){
        int kidx = ((j*16+lrow)*64 + p*32 + quad*8) ^ fsw;
        kh[j] = *(const h16x8*)&Khi[kidx];
        kl[j] = *(const h16x8*)&Klo[kidx];
      }
      #pragma unroll
      for (int i=0;i<2;i++)
        #pragma unroll
        for (int j=0;j<4;j++){
          sacc[i][j] = mfma16(qfh[p][i], kh[j], sacc[i][j]);
          sacc[i][j] = mfma16(qfh[p][i], kl[j], sacc[i][j]);
          sacc[i][j] = mfma16(qfl[p][i], kh[j], sacc[i][j]);
        }
    }
    __builtin_amdgcn_s_setprio(0);
    // ---- online softmax over 64 keys ----
    #pragma unroll
    for (int i=0;i<2;i++){
      #pragma unroll
      for (int r=0;r<4;r++){
        int qrow = q0 + wvx*32 + i*16 + quad*4 + r;
        float s[4];
        #pragma unroll
        for (int j=0;j<4;j++){
          float sv = sacc[i][j][r] * 0.125f;
          if (useMask) sv += ldin(mask, (size_t)qrow*S_LEN + key0 + j*16 + lrow, is32);
          s[j] = sv;
        }
        float mx = fmaxf(fmaxf(s[0],s[1]), fmaxf(s[2],s[3]));
        #pragma unroll
        for (int mm=1; mm<=8; mm<<=1) mx = fmaxf(mx, __shfl_xor(mx, mm, 64));
        float mnew = fmaxf(mrun[i][r], mx);
        float alpha = __expf(mrun[i][r] - mnew);
        float ps = 0.f;
        #pragma unroll
        for (int j=0;j<4;j++){
          float p = __expf(s[j] - mnew);
          s[j] = p;
          ps += p;
        }
        #pragma unroll
        for (int mm=1; mm<=8; mm<<=1) ps += __shfl_xor(ps, mm, 64);
        lrun[i][r] = lrun[i][r]*alpha + ps;
        mrun[i][r] = mnew;
        #pragma unroll
        for (int jd=0;jd<4;jd++) oacc[i][jd][r] *= alpha;
        int prow = wvx*32 + i*16 + quad*4 + r;
        int pswz = (prow&7)<<3;
        #pragma unroll
        for (int j=0;j<4;j++){
          int pidx = (prow*64 + j*16 + lrow) ^ pswz;
          float pv = s[j];
          _Float16 ph = (_Float16)pv;
          Phi[pidx] = ph;
          Plo[pidx] = (_Float16)(pv - (float)ph);
        }
      }
    }
    __syncthreads();   // P visible; K reads done
    // ---- PV ----
    {
      h16x8 pf[2][2], pl[2][2];
      #pragma unroll
      for (int i=0;i<2;i++)
        #pragma unroll
        for (int ks=0;ks<2;ks++){
          int pidx = ((wvx*32 + i*16 + lrow)*64 + ks*32 + quad*8) ^ fsw;
          pf[i][ks] = *(const h16x8*)&Phi[pidx];
          pl[i][ks] = *(const h16x8*)&Plo[pidx];
        }
      __builtin_amdgcn_s_setprio(1);
      #pragma unroll
      for (int ks=0;ks<2;ks++){
        h16x8 vh[4], vl[4];
        #pragma unroll
        for (int jd=0;jd<4;jd++){
          int vidx = ((jd*16+lrow)*64 + ks*32 + quad*8) ^ fsw;
          vh[jd] = *(const h16x8*)&Vth[vidx];
          vl[jd] = *(const h16x8*)&Vtl[vidx];
        }
        #pragma unroll
        for (int i=0;i<2;i++)
          #pragma unroll
          for (int jd=0;jd<4;jd++){
            oacc[i][jd] = mfma16(pf[i][ks], vh[jd], oacc[i][jd]);
            oacc[i][jd] = mfma16(pf[i][ks], vl[jd], oacc[i][jd]);
            oacc[i][jd] = mfma16(pl[i][ks], vh[jd], oacc[i][jd]);
          }
      }
      __builtin_amdgcn_s_setprio(0);
    }
    __syncthreads();   // V/P reads done; next iter may overwrite
  }
  #pragma unroll
  for (int i=0;i<2;i++)
    #pragma unroll
    for (int j=0;j<4;j++)
      #pragma unroll
      for (int r=0;r<4;r++){
        int row = q0 + wvx*32 + i*16 + quad*4 + r;
        int col = h*64 + j*16 + lrow;
        size_t idx = (tok0 + row)*H_DIM + col;
        float v = oacc[i][j][r] / lrun[i][r];
        _Float16 hh = (_Float16)v;
        ohi[idx] = hh;
        olo[idx] = (_Float16)(v - (float)hh);
      }
}

// ---------------- RMSNorm #2 + router (fp32 logits, top-2) ----------------
__global__ __launch_bounds__(256) void k_rms2_router(const float* __restrict__ x1, const void* __restrict__ w,
    const void* __restrict__ rw, _Float16* __restrict__ h2,
    int* __restrict__ tok_e, float* __restrict__ tok_w, int* __restrict__ counts,
    const int* __restrict__ df){
  const int is32 = *df;
  int t = blockIdx.x, tid = threadIdx.x;
  f32x4 v = *(const f32x4*)&x1[(size_t)t*H_DIM + tid*4];
  float ss = v[0]*v[0]+v[1]*v[1]+v[2]*v[2]+v[3]*v[3];
  #pragma unroll
  for (int off=32; off>0; off>>=1) ss += __shfl_down(ss, off, 64);
  __shared__ float red[4];
  __shared__ float lgs[32];
  if ((tid&63)==0) red[tid>>6] = ss;
  __syncthreads();
  float rstd = rsqrt_acc((red[0]+red[1]+red[2]+red[3])*(1.0f/H_DIM) + 1e-6f);
  float hv[4];
  h16x4 hst;
  #pragma unroll
  for (int m=0;m<4;m++){ hv[m] = v[m]*rstd*ldin(w, tid*4+m, is32); hst[m] = (_Float16)hv[m]; }
  *(h16x4*)&h2[(size_t)t*H_DIM + tid*4] = hst;
  float part[8] = {0,0,0,0,0,0,0,0};
  #pragma unroll
  for (int m=0;m<4;m++){
    size_t c = (size_t)(tid*4 + m)*8;
    #pragma unroll
    for (int e=0;e<8;e++) part[e] += hv[m]*ldin(rw, c+e, is32);
  }
  #pragma unroll
  for (int e=0;e<8;e++){
    #pragma unroll
    for (int off=32; off>0; off>>=1) part[e] += __shfl_down(part[e], off, 64);
  }
  if ((tid&63)==0){
    #pragma unroll
    for (int e=0;e<8;e++) lgs[(tid>>6)*8 + e] = part[e];
  }
  __syncthreads();
  if (tid==0){
    float lg[8];
    #pragma unroll
    for (int e=0;e<8;e++) lg[e] = lgs[e] + lgs[8+e] + lgs[16+e] + lgs[24+e];
    int e0 = 0;
    #pragma unroll
    for (int e=1;e<8;e++) if (lg[e] > lg[e0]) e0 = e;
    int e1 = (e0==0) ? 1 : 0;
    #pragma unroll
    for (int e=0;e<8;e++) if (e != e0 && lg[e] > lg[e1]) e1 = e;
    float d = expf(lg[e1] - lg[e0]);
    float w0 = 1.0f/(1.0f + d);
    float w1 = d * w0;
    tok_e[t*2] = e0; tok_e[t*2+1] = e1;
    tok_w[t*2] = w0; tok_w[t*2+1] = w1;
    atomicAdd(&counts[e0], 1);
    atomicAdd(&counts[e1], 1);
  }
}

// ---------------- expert offsets (padded prefix) ----------------
__global__ void k_offsets(const int* __restrict__ counts, int* __restrict__ offs, int* __restrict__ fillpos){
  if (threadIdx.x == 0 && blockIdx.x == 0){
    int o = 0;
    for (int e=0;e<8;e++){
      offs[e] = o; fillpos[e] = o;
      o += (counts[e] + 127) & ~127;
    }
    offs[8] = o;
  }
}

// ---------------- fill compact token lists ----------------
__global__ __launch_bounds__(256) void k_fill(const int* __restrict__ tok_e, const float* __restrict__ tok_w,
    int* __restrict__ fillpos, int* __restrict__ list_ts, float* __restrict__ list_w){
  int t = blockIdx.x*256 + threadIdx.x;
  if (t >= T_TOK) return;
  #pragma unroll
  for (int s=0;s<2;s++){
    int e = tok_e[t*2+s];
    int p = atomicAdd(&fillpos[e], 1);
    list_ts[p] = t*2 + s;
    list_w[p] = tok_w[t*2+s];
  }
}

// ======== HOT PATH: pre-transposed f16 weights + global_load_lds staging ========

// gate+up GEMM, B^T [e][n=4096][k=1024] f16; tile 128m x (64 gate + 64 up), BK=32,
// double-buffered prefetch pipeline + 2-bit both-sides chunk swizzle
__global__ __launch_bounds__(256) void k_gemm_gu_t(const _Float16* __restrict__ h2,
    const _Float16* __restrict__ gwt, _Float16* __restrict__ act, const int* __restrict__ list_ts,
    const int* __restrict__ counts, const int* __restrict__ offs){
  int m0 = blockIdx.y<<7;
  if (m0 >= offs[8]) return;
  int e = 0;
  while (m0 >= offs[e+1]) e++;
  int base = offs[e], cnt = counts[e];
  if (m0 >= base + cnt) return;
  __shared__ __align__(16) _Float16 As[2][128*32], Bg[2][64*32], Bu[2][64*32];
  __shared__ int rowtok[128];
  int tid = threadIdx.x;
  if (tid < 128) rowtok[tid] = list_ts[min(m0 + tid, base + cnt - 1)] >> 1;
  __syncthreads();
  int lane = tid&63, wvx = tid>>6, wr = wvx>>1, wc = wvx&1, quad = lane>>4, lrow = lane&15;
  int n0 = blockIdx.x<<6;
  const _Float16* Bge = gwt + (size_t)e*4096*1024 + (size_t)n0*1024;
  const _Float16* Bue = gwt + (size_t)e*4096*1024 + (size_t)(2048+n0)*1024;
  int srow = tid>>2;                  // 0..63
  int csw  = (tid&3) ^ (srow&3);
  // hoisted k0-independent row bases (gathered A rows, contiguous B rows)
  const _Float16* ar0 = &h2[(size_t)rowtok[srow   ]*H_DIM + csw*8];
  const _Float16* ar1 = &h2[(size_t)rowtok[64+srow]*H_DIM + csw*8];
  const _Float16* bg0 = Bge + (size_t)srow*1024 + csw*8;
  const _Float16* bu0 = Bue + (size_t)srow*1024 + csw*8;
  auto stage = [&](int bb, int k0){
    gll16(ar0 + k0, &As[bb][wvx*512]);
    gll16(ar1 + k0, &As[bb][2048 + wvx*512]);
    gll16(bg0 + k0, &Bg[bb][wvx*512]);
    gll16(bu0 + k0, &Bu[bb][wvx*512]);
  };
  f32x4 ag[4][2] = {}, au[4][2] = {};
  stage(0, 0);
  __syncthreads();
  int cur = 0;
  int co = (quad ^ (lrow&3))*8;
  for (int k0=0; k0<1024; k0+=32){
    if (k0 < 992) stage(cur^1, k0+32);
    h16x8 a[4], bgf[2], buf_[2];
    #pragma unroll
    for (int i=0;i<4;i++) a[i] = *(const h16x8*)&As[cur][(wr*64 + i*16 + lrow)*32 + co];
    #pragma unroll
    for (int j=0;j<2;j++){
      bgf[j]  = *(const h16x8*)&Bg[cur][(wc*32 + j*16 + lrow)*32 + co];
      buf_[j] = *(const h16x8*)&Bu[cur][(wc*32 + j*16 + lrow)*32 + co];
    }
    #pragma unroll
    for (int i=0;i<4;i++)
      #pragma unroll
      for (int j=0;j<2;j++){
        ag[i][j] = mfma16(a[i], bgf[j],  ag[i][j]);
        au[i][j] = mfma16(a[i], buf_[j], au[i][j]);
      }
    __syncthreads();
    cur ^= 1;
  }
  #pragma unroll
  for (int i=0;i<4;i++)
    #pragma unroll
    for (int j=0;j<2;j++)
      #pragma unroll
      for (int r=0;r<4;r++){
        int row = m0 + wr*64 + i*16 + quad*4 + r;
        int col = n0 + wc*32 + j*16 + lrow;
        float g = ag[i][j][r], u = au[i][j][r];
        float sv = g / (1.0f + __expf(-g));
        act[(size_t)row*INTER_DIM + col] = (_Float16)(sv * u);
      }
}

// down GEMM, B^T [e][n=1024][k=2048] f16; tile 128x128, BK=32, double-buffered
// prefetch pipeline + 2-bit both-sides swizzle; scatter epilogue
__global__ __launch_bounds__(256) void k_gemm_down_t(const _Float16* __restrict__ act,
    const _Float16* __restrict__ dwt, _Float16* __restrict__ slotbuf, const int* __restrict__ list_ts,
    const float* __restrict__ list_w, const int* __restrict__ counts, const int* __restrict__ offs){
  int m0 = blockIdx.y<<7;
  if (m0 >= offs[8]) return;
  int e = 0;
  while (m0 >= offs[e+1]) e++;
  int base = offs[e], cnt = counts[e];
  if (m0 >= base + cnt) return;
  __shared__ __align__(16) _Float16 As[2][128*32], Bs[2][128*32];
  int tid = threadIdx.x, lane = tid&63, wvx = tid>>6;
  int wr = wvx>>1, wc = wvx&1, quad = lane>>4, lrow = lane&15;
  int n0 = blockIdx.x<<7;
  const _Float16* Be = dwt + (size_t)e*1024*2048 + (size_t)n0*2048;
  int srow = tid>>2;                  // 0..63
  int csw  = (tid&3) ^ (srow&3);
  const _Float16* pa0 = &act[(size_t)(m0+srow)*INTER_DIM + csw*8];
  const _Float16* pa1 = &act[(size_t)(m0+64+srow)*INTER_DIM + csw*8];
  const _Float16* pb0 = Be + (size_t)srow*2048 + csw*8;
  const _Float16* pb1 = Be + (size_t)(64+srow)*2048 + csw*8;
  auto stage = [&](int bb, int k0){
    gll16(pa0 + k0, &As[bb][wvx*512]);
    gll16(pa1 + k0, &As[bb][2048 + wvx*512]);
    gll16(pb0 + k0, &Bs[bb][wvx*512]);
    gll16(pb1 + k0, &Bs[bb][2048 + wvx*512]);
  };
  f32x4 acc[4][4] = {};
  stage(0, 0);
  __syncthreads();
  int cur = 0;
  int co = (quad ^ (lrow&3))*8;
  for (int k0=0; k0<2048; k0+=32){
    if (k0 < 2016) stage(cur^1, k0+32);
    h16x8 a[4], b[4];
    #pragma unroll
    for (int i=0;i<4;i++) a[i] = *(const h16x8*)&As[cur][(wr*64 + i*16 + lrow)*32 + co];
    #pragma unroll
    for (int j=0;j<4;j++) b[j] = *(const h16x8*)&Bs[cur][(wc*64 + j*16 + lrow)*32 + co];
    #pragma unroll
    for (int i=0;i<4;i++)
      #pragma unroll
      for (int j=0;j<4;j++)
        acc[i][j] = mfma16(a[i], b[j], acc[i][j]);
    __syncthreads();
    cur ^= 1;
  }
  #pragma unroll
  for (int i=0;i<4;i++)
    #pragma unroll
    for (int r=0;r<4;r++){
      int m = m0 + wr*64 + i*16 + quad*4 + r;
      if (m < base + cnt){
        int ts = list_ts[m];
        float wgt = list_w[m];
        #pragma unroll
        for (int j=0;j<4;j++){
          int col = n0 + wc*64 + j*16 + lrow;
          slotbuf[(size_t)ts*H_DIM + col] = (_Float16)(wgt * acc[i][j][r]);
        }
      }
    }
}

// ======== LEGACY PATH (ws too small for weight transposes) ========

__global__ __launch_bounds__(256) void k_gemm_gu(const _Float16* __restrict__ h2, const void* __restrict__ guw,
    _Float16* __restrict__ act, const int* __restrict__ list_ts,
    const int* __restrict__ counts, const int* __restrict__ offs, const int* __restrict__ df){
  const int is32 = *df;
  int m0 = blockIdx.y<<7;
  if (m0 >= offs[8]) return;
  int e = 0;
  while (m0 >= offs[e+1]) e++;
  int base = offs[e], cnt = counts[e];
  if (m0 >= base + cnt) return;
  __shared__ __align__(16) _Float16 As[128*32], Bg[64*40], Bu[64*40];
  __shared__ int rowtok[128];
  int tid = threadIdx.x;
  if (tid < 128){
    int mc = min(m0 + tid, base + cnt - 1);
    rowtok[tid] = list_ts[mc] >> 1;
  }
  __syncthreads();
  int lane = tid&63, wvx = tid>>6, wr = wvx>>1, wc = wvx&1, quad = lane>>4, lrow = lane&15;
  int n0 = blockIdx.x<<6;
  size_t ebase = (size_t)e*H_DIM*4096;
  f32x4 ag[4][2] = {}, au[4][2] = {};
  for (int k0=0; k0<1024; k0+=32){
    #pragma unroll
    for (int it=0; it<2; it++){
      int ch = it*256 + tid;
      int r = ch>>2, c = ch&3;
      *(i32x4*)&As[ch*8] = *(const i32x4*)&h2[(size_t)rowtok[r]*H_DIM + k0 + c*8];
    }
    {
      int k = tid>>3, g = tid&7;
      size_t rowb = ebase + (size_t)(k0+k)*4096;
      int ks = kslot_sw(k, g);
      _Float16 tg[8], tu[8];
      if (is32){
        const float* gf = (const float*)guw;
        f32x4 a0 = *(const f32x4*)&gf[rowb + n0 + g*8];
        f32x4 a1 = *(const f32x4*)&gf[rowb + n0 + g*8 + 4];
        f32x4 b0 = *(const f32x4*)&gf[rowb + 2048 + n0 + g*8];
        f32x4 b1 = *(const f32x4*)&gf[rowb + 2048 + n0 + g*8 + 4];
        #pragma unroll
        for (int i=0;i<4;i++){ tg[i]=(_Float16)a0[i]; tg[4+i]=(_Float16)a1[i];
                               tu[i]=(_Float16)b0[i]; tu[4+i]=(_Float16)b1[i]; }
      } else {
        const u16* gb = (const u16*)guw;
        u16x4 a0 = *(const u16x4*)&gb[rowb + n0 + g*8];
        u16x4 a1 = *(const u16x4*)&gb[rowb + n0 + g*8 + 4];
        u16x4 b0 = *(const u16x4*)&gb[rowb + 2048 + n0 + g*8];
        u16x4 b1 = *(const u16x4*)&gb[rowb + 2048 + n0 + g*8 + 4];
        #pragma unroll
        for (int i=0;i<4;i++){ tg[i]=(_Float16)bf2f(a0[i]); tg[4+i]=(_Float16)bf2f(a1[i]);
                               tu[i]=(_Float16)bf2f(b0[i]); tu[4+i]=(_Float16)bf2f(b1[i]); }
      }
      #pragma unroll
      for (int i=0;i<8;i++){
        int n = g*8 + i;
        Bg[n*40 + ks] = tg[i];
        Bu[n*40 + ks] = tu[i];
      }
    }
    __syncthreads();
    h16x8 a[4], bg[2], bu[2];
    #pragma unroll
    for (int i=0;i<4;i++) a[i] = *(const h16x8*)&As[(wr*64 + i*16 + lrow)*32 + quad*8];
    #pragma unroll
    for (int j=0;j<2;j++){
      int n = wc*32 + j*16 + lrow;
      int oct = (quad ^ ((n>>3)&3))*8;
      bg[j] = *(const h16x8*)&Bg[n*40 + oct];
      bu[j] = *(const h16x8*)&Bu[n*40 + oct];
    }
    #pragma unroll
    for (int i=0;i<4;i++)
      #pragma unroll
      for (int j=0;j<2;j++){
        ag[i][j] = mfma16(a[i], bg[j], ag[i][j]);
        au[i][j] = mfma16(a[i], bu[j], au[i][j]);
      }
    __syncthreads();
  }
  #pragma unroll
  for (int i=0;i<4;i++)
    #pragma unroll
    for (int j=0;j<2;j++)
      #pragma unroll
      for (int r=0;r<4;r++){
        int row = m0 + wr*64 + i*16 + quad*4 + r;
        int col = n0 + wc*32 + j*16 + lrow;
        float g = ag[i][j][r], u = au[i][j][r];
        float sv = g / (1.0f + __expf(-g));
        act[(size_t)row*INTER_DIM + col] = (_Float16)(sv * u);
      }
}

__global__ __launch_bounds__(256) void k_gemm_down(const _Float16* __restrict__ act, const void* __restrict__ dw,
    _Float16* __restrict__ slotbuf, const int* __restrict__ list_ts, const float* __restrict__ list_w,
    const int* __restrict__ counts, const int* __restrict__ offs, const int* __restrict__ df){
  const int is32 = *df;
  int m0 = blockIdx.y<<7;
  if (m0 >= offs[8]) return;
  int e = 0;
  while (m0 >= offs[e+1]) e++;
  int base = offs[e], cnt = counts[e];
  if (m0 >= base + cnt) return;
  __shared__ __align__(16) _Float16 As[128*32], Bs[128*40];
  int tid = threadIdx.x, lane = tid&63, wvx = tid>>6;
  int wr = wvx>>1, wc = wvx&1, quad = lane>>4, lrow = lane&15;
  int n0 = blockIdx.x<<7;
  size_t ebase = (size_t)e*INTER_DIM*H_DIM;
  f32x4 acc[4][4] = {};
  for (int k0=0; k0<2048; k0+=32){
    #pragma unroll
    for (int it=0; it<2; it++){
      int ch = it*256 + tid;
      int r = ch>>2, c = ch&3;
      *(i32x4*)&As[ch*8] = *(const i32x4*)&act[(size_t)(m0+r)*INTER_DIM + k0 + c*8];
    }
    {
      int k = tid>>3, g = tid&7;
      size_t rowb = ebase + (size_t)(k0+k)*H_DIM;
      int ks = kslot_sw(k, g);
      #pragma unroll
      for (int p=0;p<2;p++){
        _Float16 tb[8];
        if (is32){
          const float* bf = (const float*)dw;
          f32x4 a0 = *(const f32x4*)&bf[rowb + n0 + p*64 + g*8];
          f32x4 a1 = *(const f32x4*)&bf[rowb + n0 + p*64 + g*8 + 4];
          #pragma unroll
          for (int i=0;i<4;i++){ tb[i]=(_Float16)a0[i]; tb[4+i]=(_Float16)a1[i]; }
        } else {
          const u16* bb = (const u16*)dw;
          u16x4 a0 = *(const u16x4*)&bb[rowb + n0 + p*64 + g*8];
          u16x4 a1 = *(const u16x4*)&bb[rowb + n0 + p*64 + g*8 + 4];
          #pragma unroll
          for (int i=0;i<4;i++){ tb[i]=(_Float16)bf2f(a0[i]); tb[4+i]=(_Float16)bf2f(a1[i]); }
        }
        #pragma unroll
        for (int i=0;i<8;i++){
          int n = p*64 + g*8 + i;
          Bs[n*40 + ks] = tb[i];
        }
      }
    }
    __syncthreads();
    h16x8 a[4], b[4];
    #pragma unroll
    for (int i=0;i<4;i++) a[i] = *(const h16x8*)&As[(wr*64 + i*16 + lrow)*32 + quad*8];
    #pragma unroll
    for (int j=0;j<4;j++){
      int n = wc*64 + j*16 + lrow;
      b[j] = *(const h16x8*)&Bs[n*40 + ((quad ^ ((n>>3)&3))*8)];
    }
    #pragma unroll
    for (int i=0;i<4;i++)
      #pragma unroll
      for (int j=0;j<4;j++)
        acc[i][j] = mfma16(a[i], b[j], acc[i][j]);
    __syncthreads();
  }
  #pragma unroll
  for (int i=0;i<4;i++)
    #pragma unroll
    for (int r=0;r<4;r++){
      int m = m0 + wr*64 + i*16 + quad*4 + r;
      if (m < base + cnt){
        int ts = list_ts[m];
        float wgt = list_w[m];
        #pragma unroll
        for (int j=0;j<4;j++){
          int col = n0 + wc*64 + j*16 + lrow;
          slotbuf[(size_t)ts*H_DIM + col] = (_Float16)(wgt * acc[i][j][r]);
        }
      }
    }
}

// ---------------- final residual add -> dual-dtype out ----------------
__global__ __launch_bounds__(256) void k_final(const float* __restrict__ x1, const _Float16* __restrict__ slot,
                                               void* __restrict__ outv, const int* __restrict__ df){
  const int is32 = *df;
  int i4 = (blockIdx.x*256 + threadIdx.x)*4;
  int t = i4 >> 10, c = i4 & 1023;
  f32x4 a = *(const f32x4*)&x1[i4];
  h16x4 s0 = *(const h16x4*)&slot[(size_t)(t*2)*H_DIM + c];
  h16x4 s1 = *(const h16x4*)&slot[(size_t)(t*2+1)*H_DIM + c];
  if (is32){
    f32x4 o;
    #pragma unroll
    for (int m=0;m<4;m++) o[m] = a[m] + (float)s0[m] + (float)s1[m];
    *(f32x4*)&((float*)outv)[i4] = o;
  } else {
    u16x4 o;
    #pragma unroll
    for (int m=0;m<4;m++) o[m] = f2bf(a[m] + (float)s0[m] + (float)s1[m]);
    *(u16x4*)&((u16*)outv)[i4] = o;
  }
}

extern "C" void kernel_launch(void* const* d_in, const int* in_sizes, int n_in,
                              void* d_out, int out_size, void* d_ws, size_t ws_size,
                              hipStream_t stream){
  (void)in_sizes; (void)n_in; (void)out_size;
  const void* x    = d_in[0];
  const void* mask = d_in[1];
  const void* ln1  = d_in[2];
  const void* ln2  = d_in[3];
  const void* qkvw = d_in[4];
  const void* ow   = d_in[5];
  const void* rw   = d_in[6];
  const void* guw  = d_in[7];
  const void* dww  = d_in[8];

  char* ws = (char*)d_ws;
  size_t off = 0;
  auto alloc = [&](size_t b)->void*{ void* p = ws + off; off = (off + b + 255) & ~(size_t)255; return p; };
  int* meta            = (int*)alloc(32*sizeof(int));
  _Float16* qkv_wt     = (_Float16*)alloc((size_t)3072*1024*2);
  _Float16* o_wt       = (_Float16*)alloc((size_t)1024*1024*2);
  _Float16* hpair      = (_Float16*)alloc((size_t)2*4096*1024*2);  // h hi/lo; later aout hi/lo; later slotbuf
  _Float16* qkvpair    = (_Float16*)alloc((size_t)2*4096*3072*2);  // qkv hi/lo; later h2+act
  float* x1            = (float*)alloc((size_t)4096*1024*4);       // V^T hi/lo during attn; then x1
  int* list_ts         = (int*)alloc(MAXROWS*4);
  float* list_w        = (float*)alloc(MAXROWS*4);
  int* tok_e           = (int*)alloc((size_t)4096*2*4);
  float* tok_w         = (float*)alloc((size_t)4096*2*4);
  size_t base_end = off;                                           // ~92 MB
  _Float16* gu_wt      = (_Float16*)alloc((size_t)8*4096*1024*2);  // 67 MB
  _Float16* down_wt    = (_Float16*)alloc((size_t)8*1024*2048*2);  // 34 MB
  const int big = (ws_size >= off) ? 1 : 0;                        // need ~193 MB for hot path
  (void)base_end;

  int* counts = meta;
  int* offs   = meta + 8;
  int* fillpos= meta + 17;
  int* flag   = meta + 25;
  int* dflag  = meta + 26;

  _Float16* h_hi   = hpair;
  _Float16* h_lo   = hpair + (size_t)4096*1024;
  _Float16* qkv_hi = qkvpair;
  _Float16* qkv_lo = qkvpair + (size_t)4096*3072;
  _Float16* vth    = (_Float16*)x1;                     // 8 MB
  _Float16* vtl    = vth + (size_t)64*64*1024;          // 8 MB
  _Float16* ahi    = hpair;                             // aout hi (h dead)
  _Float16* alo    = hpair + (size_t)4096*1024;         // aout lo
  _Float16* h2     = qkvpair;                           // qkv dead after attn
  _Float16* act    = qkvpair + (size_t)4096*1024;
  _Float16* slotbuf= hpair;                             // aout dead after o-proj

  hipMemsetAsync(meta, 0, 32*sizeof(int), stream);
  k_detect<<<dim3(1), dim3(64), 0, stream>>>((const uint32_t*)x, dflag);
  k_trans2<<<dim3(48, 16, 1), 256, 0, stream>>>(qkvw, qkv_wt, 1024, 3072, dflag);
  k_trans2<<<dim3(16, 16, 1), 256, 0, stream>>>(ow, o_wt, 1024, 1024, dflag);
  if (big){
    k_trans2<<<dim3(64, 16, 8), 256, 0, stream>>>(guw, gu_wt, 1024, 4096, dflag);
    k_trans2<<<dim3(16, 32, 8), 256, 0, stream>>>(dww, down_wt, 2048, 1024, dflag);
  }
  k_maskchk<<<dim3(1024), 256, 0, stream>>>(mask, flag, dflag);
  k_rms1<<<dim3(4096), 256, 0, stream>>>(x, ln1, h_hi, h_lo, dflag);
  k_gemm_hl<0><<<dim3(24, 32), 256, 0, stream>>>(h_hi, h_lo, qkv_wt, nullptr, qkv_hi, qkv_lo,
                                                 nullptr, 3072, 1024, dflag);
  k_vt<<<dim3(16, 64), 256, 0, stream>>>(qkv_hi, qkv_lo, vth, vtl);
  k_attn<<<dim3(8, 64), 256, 0, stream>>>(qkv_hi, qkv_lo, vth, vtl, mask, flag, ahi, alo, dflag);
  k_gemm_hl<1><<<dim3(8, 32), 256, 0, stream>>>(ahi, alo, o_wt, x1, nullptr, nullptr,
                                                x, 1024, 1024, dflag);
  k_rms2_router<<<dim3(4096), 256, 0, stream>>>(x1, ln2, rw, h2, tok_e, tok_w, counts, dflag);
  k_offsets<<<dim3(1), dim3(64), 0, stream>>>(counts, offs, fillpos);
  k_fill<<<dim3(16), 256, 0, stream>>>(tok_e, tok_w, fillpos, list_ts, list_w);
  if (big){
    k_gemm_gu_t<<<dim3(32, 72), 256, 0, stream>>>(h2, gu_wt, act, list_ts, counts, offs);
    k_gemm_down_t<<<dim3(8, 72), 256, 0, stream>>>(act, down_wt, slotbuf, list_ts, list_w, counts, offs);
  } else {
    k_gemm_gu<<<dim3(32, 72), 256, 0, stream>>>(h2, guw, act, list_ts, counts, offs, dflag);
    k_gemm_down<<<dim3(8, 72), 256, 0, stream>>>(act, dww, slotbuf, list_ts, list_w, counts, offs, dflag);
  }
  k_final<<<dim3(4096), 256, 0, stream>>>(x1, slotbuf, d_out, dflag);
}

// Round 5
// 774.064 us; speedup vs baseline: 1.1885x; 1.0780x over previous
//
#include <hip/hip_runtime.h>
#include <cstdint>
#include <cmath>

// Problem constants (B=4, S=1024)
#define T_TOK 4096
#define H_DIM 1024
#define QKV_N 3072
#define S_LEN 1024
#define INTER_DIM 2048
#define MAXROWS 9216   // 2*T + 8*127 padding, rounded

typedef unsigned short u16;
using f32x4 = __attribute__((ext_vector_type(4))) float;
using h16x8 = __attribute__((ext_vector_type(8))) _Float16;
using h16x4 = __attribute__((ext_vector_type(4))) _Float16;
using i32x4 = __attribute__((ext_vector_type(4))) int;
using u16x4 = __attribute__((ext_vector_type(4))) u16;
using u16x8 = __attribute__((ext_vector_type(8))) u16;

__device__ __forceinline__ float bf2f(u16 u){ return __uint_as_float(((uint32_t)u)<<16); }
__device__ __forceinline__ u16 f2bf(float f){
  uint32_t x = __float_as_uint(f);
  uint32_t r = x + 0x7FFFu + ((x>>16)&1u);
  return (u16)(r>>16);
}
__device__ __forceinline__ f32x4 mfma16(h16x8 a, h16x8 b, f32x4 c){
  return __builtin_amdgcn_mfma_f32_16x16x32_f16(a,b,c,0,0,0);
}
__device__ __forceinline__ float rsqrt_acc(float v){
  float r = rsqrtf(v);
  r = r*(1.5f - 0.5f*v*r*r);
  r = r*(1.5f - 0.5f*v*r*r);
  return r;
}
// dual-dtype scalar input read
__device__ __forceinline__ float ldin(const void* p, size_t i, int is32){
  return is32 ? ((const float*)p)[i] : bf2f(((const u16*)p)[i]);
}
// swizzled k-slot for stride-40 B tiles (legacy path)
__device__ __forceinline__ int kslot_sw(int k, int noct){
  return (k&7) | (((k>>3) ^ (noct&3))<<3);
}
// async global->LDS, 16B per lane; lds base must be wave-uniform, lanes land at base+lane*16
__device__ __forceinline__ void gll16(const void* g, void* l){
  __builtin_amdgcn_global_load_lds(
      (const __attribute__((address_space(1))) void*)g,
      (__attribute__((address_space(3))) void*)l, 16, 0, 0);
}

// ---------------- dtype detection: fp32 exponent fields of N(0,1) data ----------------
__global__ void k_detect(const uint32_t* __restrict__ x, int* __restrict__ dflag){
  uint32_t u = x[threadIdx.x];
  int e = (u>>23)&0xFF;
  int ok = (e>=103 && e<=150);            // |f| in [2^-24, 2^23]
  unsigned long long m = __ballot(ok);
  if (threadIdx.x==0) *dflag = (__popcll(m) >= 48) ? 1 : 0;
}

// ---------------- vectorized transpose + cast to f16: src [R][C] -> dst [C][R] ------
// 64x64 tiles; conflict-free LDS (stride 65); 16B global loads/stores
__global__ __launch_bounds__(256) void k_trans2(const void* __restrict__ src,
    _Float16* __restrict__ dst, int R, int C, const int* __restrict__ df){
  const int is32 = *df;
  __shared__ _Float16 t[64][65];
  size_t bo = (size_t)blockIdx.z * R * C;
  int c0 = blockIdx.x<<6, r0 = blockIdx.y<<6;
  int ty = threadIdx.x>>3, tx = threadIdx.x&7;   // ty 0..31, tx 0..7
  #pragma unroll
  for (int rr=0; rr<2; rr++){
    int r = rr*32 + ty;
    size_t gi = bo + (size_t)(r0+r)*C + c0 + tx*8;
    _Float16 v[8];
    if (is32){
      f32x4 a0 = *(const f32x4*)&((const float*)src)[gi];
      f32x4 a1 = *(const f32x4*)&((const float*)src)[gi+4];
      #pragma unroll
      for (int i=0;i<4;i++){ v[i]=(_Float16)a0[i]; v[4+i]=(_Float16)a1[i]; }
    } else {
      u16x8 a = *(const u16x8*)&((const u16*)src)[gi];
      #pragma unroll
      for (int i=0;i<8;i++) v[i]=(_Float16)bf2f(a[i]);
    }
    #pragma unroll
    for (int i=0;i<8;i++) t[r][tx*8+i] = v[i];
  }
  __syncthreads();
  #pragma unroll
  for (int rr=0; rr<2; rr++){
    int n = rr*32 + ty;
    h16x8 v;
    #pragma unroll
    for (int i=0;i<8;i++) v[i] = t[tx*8+i][n];
    *(h16x8*)&dst[bo + (size_t)(c0+n)*R + r0 + tx*8] = v;
  }
}

// ---------------- mask all-zero check ----------------
__global__ __launch_bounds__(256) void k_maskchk(const void* __restrict__ m, int* __restrict__ flag,
                                                 const int* __restrict__ df){
  const int is32 = *df;
  int i = (blockIdx.x*256 + threadIdx.x)*4;
  int nz = 0;
  if (is32){
    f32x4 v = *(const f32x4*)&((const float*)m)[i];
    nz = (v[0]!=0.f)||(v[1]!=0.f)||(v[2]!=0.f)||(v[3]!=0.f);
  } else {
    u16x4 v = *(const u16x4*)&((const u16*)m)[i];
    nz = ((v[0]|v[1]|v[2]|v[3]) & 0x7FFF) != 0;
  }
  if (nz) atomicOr(flag, 1);
}

// ---------------- RMSNorm #1: x -> pre-split f16 hi/lo h ----------------
__global__ __launch_bounds__(256) void k_rms1(const void* __restrict__ x, const void* __restrict__ w,
                                              _Float16* __restrict__ hhi, _Float16* __restrict__ hlo,
                                              const int* __restrict__ df){
  const int is32 = *df;
  int t = blockIdx.x, tid = threadIdx.x;
  size_t base = (size_t)t*H_DIM + tid*4;
  float f[4];
  #pragma unroll
  for (int m=0;m<4;m++) f[m] = ldin(x, base+m, is32);
  float ss = f[0]*f[0] + f[1]*f[1] + f[2]*f[2] + f[3]*f[3];
  #pragma unroll
  for (int off=32; off>0; off>>=1) ss += __shfl_down(ss, off, 64);
  __shared__ float red[4];
  if ((tid & 63) == 0) red[tid>>6] = ss;
  __syncthreads();
  float rstd = rsqrt_acc((red[0]+red[1]+red[2]+red[3]) * (1.0f/H_DIM) + 1e-6f);
  h16x4 oh, ol;
  #pragma unroll
  for (int m=0;m<4;m++){
    float v = f[m]*rstd*ldin(w, tid*4+m, is32);
    _Float16 hh = (_Float16)v;
    oh[m] = hh;
    ol[m] = (_Float16)(v - (float)hh);
  }
  *(h16x4*)&hhi[base] = oh;
  *(h16x4*)&hlo[base] = ol;
}

// ---------------- high-precision GEMM: pre-split f16 hi/lo A, f16 B^T --------------
// BK=32, double-buffered LDS, prefetch-before-compute pipeline (one barrier/K-step),
// 2-bit both-sides chunk swizzle (chunk ^= row&3) -> 2-way (free) LDS reads.
// EPI==0: write C as f16 hi/lo pair. EPI==1: fp32 C with residual add.
template<int EPI>
__global__ __launch_bounds__(256) void k_gemm_hl(const _Float16* __restrict__ Ah,
    const _Float16* __restrict__ Al, const _Float16* __restrict__ Bt,
    float* __restrict__ C, _Float16* __restrict__ Chi, _Float16* __restrict__ Clo,
    const void* __restrict__ res, int N, int K, const int* __restrict__ df){
  const int is32 = (EPI==1) ? *df : 0;
  __shared__ __align__(16) _Float16 AhS[2][128*32];
  __shared__ __align__(16) _Float16 AlS[2][128*32];
  __shared__ __align__(16) _Float16 Bs[2][128*32];
  int tid = threadIdx.x, lane = tid&63, wvx = tid>>6;
  int wr = wvx>>1, wc = wvx&1, quad = lane>>4, lrow = lane&15;
  int m0 = blockIdx.y<<7, n0 = blockIdx.x<<7;
  // staging geometry: thread covers row srow (+64 for second half), swizzled chunk csw
  int srow = tid>>2;                  // 0..63
  int csw  = (tid&3) ^ (srow&3);
  const _Float16* a0h = &Ah[(size_t)(m0+srow)*K + csw*8];
  const _Float16* a1h = &Ah[(size_t)(m0+64+srow)*K + csw*8];
  const _Float16* a0l = &Al[(size_t)(m0+srow)*K + csw*8];
  const _Float16* a1l = &Al[(size_t)(m0+64+srow)*K + csw*8];
  const _Float16* b0  = &Bt[(size_t)(n0+srow)*K + csw*8];
  const _Float16* b1  = &Bt[(size_t)(n0+64+srow)*K + csw*8];
  auto stage = [&](int bb, int k0){
    gll16(a0h + k0, &AhS[bb][wvx*512]);
    gll16(a1h + k0, &AhS[bb][2048 + wvx*512]);
    gll16(a0l + k0, &AlS[bb][wvx*512]);
    gll16(a1l + k0, &AlS[bb][2048 + wvx*512]);
    gll16(b0  + k0, &Bs[bb][wvx*512]);
    gll16(b1  + k0, &Bs[bb][2048 + wvx*512]);
  };
  f32x4 acc[4][4] = {};
  stage(0, 0);
  __syncthreads();
  int cur = 0;
  int co = (quad ^ (lrow&3))*8;
  for (int k0=0; k0<K; k0+=32){
    if (k0 + 32 < K) stage(cur^1, k0+32);
    h16x8 ah[4], al[4], bb[4];
    #pragma unroll
    for (int i=0;i<4;i++){
      int ra = (wr*64 + i*16 + lrow)*32;
      ah[i] = *(const h16x8*)&AhS[cur][ra + co];
      al[i] = *(const h16x8*)&AlS[cur][ra + co];
    }
    #pragma unroll
    for (int j=0;j<4;j++) bb[j] = *(const h16x8*)&Bs[cur][(wc*64 + j*16 + lrow)*32 + co];
    #pragma unroll
    for (int i=0;i<4;i++)
      #pragma unroll
      for (int j=0;j<4;j++){
        acc[i][j] = mfma16(ah[i], bb[j], acc[i][j]);
        acc[i][j] = mfma16(al[i], bb[j], acc[i][j]);
      }
    __syncthreads();   // drains this iter's prefetch (had full compute to land); P/C swap
    cur ^= 1;
  }
  #pragma unroll
  for (int i=0;i<4;i++)
    #pragma unroll
    for (int j=0;j<4;j++){
      int col = n0 + wc*64 + j*16 + lrow;
      #pragma unroll
      for (int r=0;r<4;r++){
        int row = m0 + wr*64 + i*16 + quad*4 + r;
        size_t idx = (size_t)row*N + col;
        float v = acc[i][j][r];
        if (EPI==1){
          v += ldin(res, idx, is32);
          C[idx] = v;
        } else {
          _Float16 hh = (_Float16)v;
          Chi[idx] = hh;
          Clo[idx] = (_Float16)(v - (float)hh);
        }
      }
    }
}

// ---------------- V^T prep: qkv hi/lo V-slice -> [bh][64 d][1024 keys] f16 hi/lo ----
__global__ __launch_bounds__(256) void k_vt(const _Float16* __restrict__ qh,
    const _Float16* __restrict__ ql, _Float16* __restrict__ vth, _Float16* __restrict__ vtl){
  __shared__ _Float16 th[64][72];
  __shared__ _Float16 tl[64][72];
  int bh = blockIdx.y;           // 0..63
  int b = bh>>4, h = bh&15;
  int key0 = blockIdx.x<<6;      // 16 tiles of 64 keys
  size_t tok0 = (size_t)b*S_LEN;
  int ty = threadIdx.x>>3, tx = threadIdx.x&7;  // ty 0..31, tx 0..7
  #pragma unroll
  for (int rr=0; rr<2; rr++){
    int r = rr*32 + ty;          // key within tile
    size_t gi = (tok0 + key0 + r)*(size_t)QKV_N + 2048 + h*64 + tx*8;
    h16x8 vh_ = *(const h16x8*)&qh[gi];
    h16x8 vl_ = *(const h16x8*)&ql[gi];
    #pragma unroll
    for (int i=0;i<8;i++){ th[r][tx*8+i] = vh_[i]; tl[r][tx*8+i] = vl_[i]; }
  }
  __syncthreads();
  size_t dbase = (size_t)bh*64*1024;
  #pragma unroll
  for (int rr=0; rr<2; rr++){
    int d = rr*32 + ty;
    h16x8 oh, ol;
    #pragma unroll
    for (int i=0;i<8;i++){ oh[i] = th[tx*8+i][d]; ol[i] = tl[tx*8+i][d]; }
    *(h16x8*)&vth[dbase + (size_t)d*1024 + key0 + tx*8] = oh;
    *(h16x8*)&vtl[dbase + (size_t)d*1024 + key0 + tx*8] = ol;
  }
}

// ---------------- flash attention v3: KVBLK=64, reg-prefetch staging, swizzled LDS --
// LDS pool 64KB: Khi[64k][64d] 8KB, Klo 8KB, Vth[64d][64k] 8KB, Vtl 8KB,
//                Phi[128r][64k] 16KB, Plo 16KB. Q staged through pool[0..16383] once.
__global__ __launch_bounds__(256, 2) void k_attn(const _Float16* __restrict__ qkvh,
    const _Float16* __restrict__ qkvl, const _Float16* __restrict__ vth_g,
    const _Float16* __restrict__ vtl_g, const void* __restrict__ mask,
    const int* __restrict__ mflag, _Float16* __restrict__ ohi, _Float16* __restrict__ olo,
    const int* __restrict__ df){
  const int is32 = *df;
  __shared__ __align__(16) _Float16 pool[32768];   // 64 KB
  _Float16* Khi = pool;            // [64 key][64 d], row-XOR swizzled
  _Float16* Klo = pool + 4096;
  _Float16* Vth = pool + 8192;     // [64 d][64 key], row-XOR swizzled
  _Float16* Vtl = pool + 12288;
  _Float16* Phi = pool + 16384;    // [128 row][64 key], row-XOR swizzled
  _Float16* Plo = pool + 24576;
  int qt = blockIdx.x, bh = blockIdx.y;
  int b = bh>>4, h = bh&15;
  int tid = threadIdx.x, lane = tid&63, wvx = tid>>6, quad = lane>>4, lrow = lane&15;
  size_t tok0 = (size_t)b*S_LEN;
  int q0 = qt<<7;
  // ---- stage Q hi/lo (32KB) into pool, pull fragments into registers ----
  {
    int r = tid>>2, cg = (tid&3)*8;
    #pragma unroll
    for (int p=0;p<2;p++)
      #pragma unroll
      for (int g=0;g<2;g++){
        size_t src = (tok0 + q0 + g*64 + r)*(size_t)QKV_N + h*64 + p*32 + cg;
        gll16(&qkvh[src], &pool[p*4096 + g*2048 + wvx*512]);
        gll16(&qkvl[src], &pool[8192 + p*4096 + g*2048 + wvx*512]);
      }
  }
  __syncthreads();
  h16x8 qfh[2][2], qfl[2][2];
  #pragma unroll
  for (int p=0;p<2;p++)
    #pragma unroll
    for (int i=0;i<2;i++){
      qfh[p][i] = *(const h16x8*)&pool[(p*128 + wvx*32 + i*16 + lrow)*32 + quad*8];
      qfl[p][i] = *(const h16x8*)&pool[8192 + (p*128 + wvx*32 + i*16 + lrow)*32 + quad*8];
    }
  int useMask = *mflag;
  float mrun[2][4], lrun[2][4];
  f32x4 oacc[2][4] = {};
  #pragma unroll
  for (int i=0;i<2;i++)
    #pragma unroll
    for (int r=0;r<4;r++){ mrun[i][r] = -INFINITY; lrun[i][r] = 0.f; }
  size_t vbase = (size_t)bh*64*1024;
  // per-thread staging geometry: chunk it covers rows it*32+(tid>>3), 8 halfs at (tid&7)*8
  int krow = tid>>3;                    // 0..31
  int c8   = (tid&7)*8;
  int rsw  = ((tid>>3)&7)<<3;           // store-side row XOR swizzle
  int fsw  = (lrow&7)<<3;               // fragment-read row XOR swizzle
  size_t ksrc0 = (tok0 + krow)*(size_t)QKV_N + 1024 + h*64 + c8;
  size_t vsrc0 = vbase + (size_t)krow*1024 + c8;
  h16x8 kh_r[2], kl_r[2], vh_r[2], vl_r[2];
  // prefetch tile 0 into regs
  {
    size_t ks0 = ksrc0, ks1 = ksrc0 + (size_t)32*QKV_N;
    kh_r[0] = *(const h16x8*)&qkvh[ks0];  kl_r[0] = *(const h16x8*)&qkvl[ks0];
    kh_r[1] = *(const h16x8*)&qkvh[ks1];  kl_r[1] = *(const h16x8*)&qkvl[ks1];
    size_t vs0 = vsrc0, vs1 = vsrc0 + 32*1024;
    vh_r[0] = *(const h16x8*)&vth_g[vs0]; vl_r[0] = *(const h16x8*)&vtl_g[vs0];
    vh_r[1] = *(const h16x8*)&vth_g[vs1]; vl_r[1] = *(const h16x8*)&vtl_g[vs1];
  }
  __syncthreads();   // Q-frag reads done everywhere; pool reusable

  for (int kt=0; kt<16; kt++){
    int key0 = kt*64;
    // store staged K/V regs -> LDS (swizzled, conflict-free 16B stripes)
    {
      int o0 = (tid*8) ^ rsw, o1 = (2048 + tid*8) ^ rsw;
      *(h16x8*)&Khi[o0] = kh_r[0];  *(h16x8*)&Khi[o1] = kh_r[1];
      *(h16x8*)&Klo[o0] = kl_r[0];  *(h16x8*)&Klo[o1] = kl_r[1];
      *(h16x8*)&Vth[o0] = vh_r[0];  *(h16x8*)&Vth[o1] = vh_r[1];
      *(h16x8*)&Vtl[o0] = vl_r[0];  *(h16x8*)&Vtl[o1] = vl_r[1];
    }
    // prefetch tile kt+1 into regs (hides under the whole compute phase)
    if (kt < 15){
      size_t ks0 = ksrc0 + (size_t)(key0+64)*QKV_N, ks1 = ks0 + (size_t)32*QKV_N;
      kh_r[0] = *(const h16x8*)&qkvh[ks0];  kl_r[0] = *(const h16x8*)&qkvl[ks0];
      kh_r[1] = *(const h16x8*)&qkvh[ks1];  kl_r[1] = *(const h16x8*)&qkvl[ks1];
      size_t vs0 = vsrc0 + (key0+64), vs1 = vs0 + 32*1024;
      vh_r[0] = *(const h16x8*)&vth_g[vs0]; vl_r[0] = *(const h16x8*)&vtl_g[vs0];
      vh_r[1] = *(const h16x8*)&vth_g[vs1]; vl_r[1] = *(const h16x8*)&vtl_g[vs1];
    }
    __syncthreads();   // K/V tile visible
    // ---- QK^T ----
    f32x4 sacc[2][4] = {};
    __builtin_amdgcn_s_setprio(1);
    #pragma unroll
    for (int p=0;p<2;p++){
      h16x8 kh[4], kl[4];
      #pragma unroll
      for (int j=0;j<4;j++){
        int kidx = ((j*16+lrow)*64 + p*32 + quad*8) ^ fsw;
        kh[j] = *(const h16x8*)&Khi[kidx];
        kl[j] = *(const h16x8*)&Klo[kidx];
      }
      #pragma unroll
      for (int i=0;i<2;i++)
        #pragma unroll
        for (int j=0;j<4;j++){
          sacc[i][j] = mfma16(qfh[p][i], kh[j], sacc[i][j]);
          sacc[i][j] = mfma16(qfh[p][i], kl[j], sacc[i][j]);
          sacc[i][j] = mfma16(qfl[p][i], kh[j], sacc[i][j]);
        }
    }
    __builtin_amdgcn_s_setprio(0);
    // ---- online softmax over 64 keys ----
    #pragma unroll
    for (int i=0;i<2;i++){
      #pragma unroll
      for (int r=0;r<4;r++){
        int qrow = q0 + wvx*32 + i*16 + quad*4 + r;
        float s[4];
        #pragma unroll
        for (int j=0;j<4;j++){
          float sv = sacc[i][j][r] * 0.125f;
          if (useMask) sv += ldin(mask, (size_t)qrow*S_LEN + key0 + j*16 + lrow, is32);
          s[j] = sv;
        }
        float mx = fmaxf(fmaxf(s[0],s[1]), fmaxf(s[2],s[3]));
        #pragma unroll
        for (int mm=1; mm<=8; mm<<=1) mx = fmaxf(mx, __shfl_xor(mx, mm, 64));
        float mnew = fmaxf(mrun[i][r], mx);
        float alpha = __expf(mrun[i][r] - mnew);
        float ps = 0.f;
        #pragma unroll
        for (int j=0;j<4;j++){
          float p = __expf(s[j] - mnew);
          s[j] = p;
          ps += p;
        }
        #pragma unroll
        for (int mm=1; mm<=8; mm<<=1) ps += __shfl_xor(ps, mm, 64);
        lrun[i][r] = lrun[i][r]*alpha + ps;
        mrun[i][r] = mnew;
        #pragma unroll
        for (int jd=0;jd<4;jd++) oacc[i][jd][r] *= alpha;
        int prow = wvx*32 + i*16 + quad*4 + r;
        int pswz = (prow&7)<<3;
        #pragma unroll
        for (int j=0;j<4;j++){
          int pidx = (prow*64 + j*16 + lrow) ^ pswz;
          float pv = s[j];
          _Float16 ph = (_Float16)pv;
          Phi[pidx] = ph;
          Plo[pidx] = (_Float16)(pv - (float)ph);
        }
      }
    }
    __syncthreads();   // P visible; K reads done
    // ---- PV ----
    {
      h16x8 pf[2][2], pl[2][2];
      #pragma unroll
      for (int i=0;i<2;i++)
        #pragma unroll
        for (int ks=0;ks<2;ks++){
          int pidx = ((wvx*32 + i*16 + lrow)*64 + ks*32 + quad*8) ^ fsw;
          pf[i][ks] = *(const h16x8*)&Phi[pidx];
          pl[i][ks] = *(const h16x8*)&Plo[pidx];
        }
      __builtin_amdgcn_s_setprio(1);
      #pragma unroll
      for (int ks=0;ks<2;ks++){
        h16x8 vh[4], vl[4];
        #pragma unroll
        for (int jd=0;jd<4;jd++){
          int vidx = ((jd*16+lrow)*64 + ks*32 + quad*8) ^ fsw;
          vh[jd] = *(const h16x8*)&Vth[vidx];
          vl[jd] = *(const h16x8*)&Vtl[vidx];
        }
        #pragma unroll
        for (int i=0;i<2;i++)
          #pragma unroll
          for (int jd=0;jd<4;jd++){
            oacc[i][jd] = mfma16(pf[i][ks], vh[jd], oacc[i][jd]);
            oacc[i][jd] = mfma16(pf[i][ks], vl[jd], oacc[i][jd]);
            oacc[i][jd] = mfma16(pl[i][ks], vh[jd], oacc[i][jd]);
          }
      }
      __builtin_amdgcn_s_setprio(0);
    }
    __syncthreads();   // V/P reads done; next iter may overwrite
  }
  #pragma unroll
  for (int i=0;i<2;i++)
    #pragma unroll
    for (int j=0;j<4;j++)
      #pragma unroll
      for (int r=0;r<4;r++){
        int row = q0 + wvx*32 + i*16 + quad*4 + r;
        int col = h*64 + j*16 + lrow;
        size_t idx = (tok0 + row)*H_DIM + col;
        float v = oacc[i][j][r] / lrun[i][r];
        _Float16 hh = (_Float16)v;
        ohi[idx] = hh;
        olo[idx] = (_Float16)(v - (float)hh);
      }
}

// ---------------- RMSNorm #2 + router (fp32 logits, top-2; NO global atomics) ------
__global__ __launch_bounds__(256) void k_rms2_router(const float* __restrict__ x1, const void* __restrict__ w,
    const void* __restrict__ rw, _Float16* __restrict__ h2,
    int* __restrict__ tok_e, float* __restrict__ tok_w,
    const int* __restrict__ df){
  const int is32 = *df;
  int t = blockIdx.x, tid = threadIdx.x;
  f32x4 v = *(const f32x4*)&x1[(size_t)t*H_DIM + tid*4];
  float ss = v[0]*v[0]+v[1]*v[1]+v[2]*v[2]+v[3]*v[3];
  #pragma unroll
  for (int off=32; off>0; off>>=1) ss += __shfl_down(ss, off, 64);
  __shared__ float red[4];
  __shared__ float lgs[32];
  if ((tid&63)==0) red[tid>>6] = ss;
  __syncthreads();
  float rstd = rsqrt_acc((red[0]+red[1]+red[2]+red[3])*(1.0f/H_DIM) + 1e-6f);
  float hv[4];
  h16x4 hst;
  #pragma unroll
  for (int m=0;m<4;m++){ hv[m] = v[m]*rstd*ldin(w, tid*4+m, is32); hst[m] = (_Float16)hv[m]; }
  *(h16x4*)&h2[(size_t)t*H_DIM + tid*4] = hst;
  float part[8] = {0,0,0,0,0,0,0,0};
  #pragma unroll
  for (int m=0;m<4;m++){
    size_t c = (size_t)(tid*4 + m)*8;
    #pragma unroll
    for (int e=0;e<8;e++) part[e] += hv[m]*ldin(rw, c+e, is32);
  }
  #pragma unroll
  for (int e=0;e<8;e++){
    #pragma unroll
    for (int off=32; off>0; off>>=1) part[e] += __shfl_down(part[e], off, 64);
  }
  if ((tid&63)==0){
    #pragma unroll
    for (int e=0;e<8;e++) lgs[(tid>>6)*8 + e] = part[e];
  }
  __syncthreads();
  if (tid==0){
    float lg[8];
    #pragma unroll
    for (int e=0;e<8;e++) lg[e] = lgs[e] + lgs[8+e] + lgs[16+e] + lgs[24+e];
    int e0 = 0;
    #pragma unroll
    for (int e=1;e<8;e++) if (lg[e] > lg[e0]) e0 = e;
    int e1 = (e0==0) ? 1 : 0;
    #pragma unroll
    for (int e=0;e<8;e++) if (e != e0 && lg[e] > lg[e1]) e1 = e;
    float d = expf(lg[e1] - lg[e0]);
    float w0 = 1.0f/(1.0f + d);
    float w1 = d * w0;
    tok_e[t*2] = e0; tok_e[t*2+1] = e1;
    tok_w[t*2] = w0; tok_w[t*2+1] = w1;
  }
}

// ---------------- single-block routing: counts + offsets + compact lists -----------
// 1024 threads x 8 slots each; register counting + shfl reduce (no global atomics);
// scatter via LDS atomics (8 counters on 8 distinct banks).
__global__ __launch_bounds__(1024) void k_route(const int* __restrict__ tok_e,
    const float* __restrict__ tok_w, int* __restrict__ counts, int* __restrict__ offs,
    int* __restrict__ list_ts, float* __restrict__ list_w){
  __shared__ int scnt[8];
  __shared__ int sfill[8];
  int tid = threadIdx.x;
  if (tid < 8) scnt[tid] = 0;
  __syncthreads();
  int te0,te1,te2,te3,te4,te5,te6,te7;
  float tw0,tw1,tw2,tw3,tw4,tw5,tw6,tw7;
  i32x4 ea = *(const i32x4*)&tok_e[tid*8];
  i32x4 eb = *(const i32x4*)&tok_e[tid*8+4];
  f32x4 wa = *(const f32x4*)&tok_w[tid*8];
  f32x4 wb = *(const f32x4*)&tok_w[tid*8+4];
  te0=ea[0]; te1=ea[1]; te2=ea[2]; te3=ea[3];
  te4=eb[0]; te5=eb[1]; te6=eb[2]; te7=eb[3];
  tw0=wa[0]; tw1=wa[1]; tw2=wa[2]; tw3=wa[3];
  tw4=wb[0]; tw5=wb[1]; tw6=wb[2]; tw7=wb[3];
  #pragma unroll
  for (int q=0;q<8;q++){
    int v = (te0==q)+(te1==q)+(te2==q)+(te3==q)+(te4==q)+(te5==q)+(te6==q)+(te7==q);
    #pragma unroll
    for (int off=32; off>0; off>>=1) v += __shfl_down(v, off, 64);
    if ((tid&63)==0 && v) atomicAdd(&scnt[q], v);   // 16 waves x 8 LDS atomics
  }
  __syncthreads();
  if (tid==0){
    int o = 0;
    #pragma unroll
    for (int e=0;e<8;e++){
      counts[e] = scnt[e];
      offs[e] = o;
      sfill[e] = o;
      o += (scnt[e] + 127) & ~127;
    }
    offs[8] = o;
  }
  __syncthreads();
  int p;
  p = atomicAdd(&sfill[te0],1); list_ts[p]=tid*8+0; list_w[p]=tw0;
  p = atomicAdd(&sfill[te1],1); list_ts[p]=tid*8+1; list_w[p]=tw1;
  p = atomicAdd(&sfill[te2],1); list_ts[p]=tid*8+2; list_w[p]=tw2;
  p = atomicAdd(&sfill[te3],1); list_ts[p]=tid*8+3; list_w[p]=tw3;
  p = atomicAdd(&sfill[te4],1); list_ts[p]=tid*8+4; list_w[p]=tw4;
  p = atomicAdd(&sfill[te5],1); list_ts[p]=tid*8+5; list_w[p]=tw5;
  p = atomicAdd(&sfill[te6],1); list_ts[p]=tid*8+6; list_w[p]=tw6;
  p = atomicAdd(&sfill[te7],1); list_ts[p]=tid*8+7; list_w[p]=tw7;
}

// ======== HOT PATH: pre-transposed f16 weights + global_load_lds staging ========

// gate+up GEMM, B^T [e][n=4096][k=1024] f16; tile 128m x (64 gate + 64 up), BK=32,
// double-buffered prefetch pipeline + 2-bit both-sides chunk swizzle
__global__ __launch_bounds__(256) void k_gemm_gu_t(const _Float16* __restrict__ h2,
    const _Float16* __restrict__ gwt, _Float16* __restrict__ act, const int* __restrict__ list_ts,
    const int* __restrict__ counts, const int* __restrict__ offs){
  int m0 = blockIdx.y<<7;
  if (m0 >= offs[8]) return;
  int e = 0;
  while (m0 >= offs[e+1]) e++;
  int base = offs[e], cnt = counts[e];
  if (m0 >= base + cnt) return;
  __shared__ __align__(16) _Float16 As[2][128*32], Bg[2][64*32], Bu[2][64*32];
  __shared__ int rowtok[128];
  int tid = threadIdx.x;
  if (tid < 128) rowtok[tid] = list_ts[min(m0 + tid, base + cnt - 1)] >> 1;
  __syncthreads();
  int lane = tid&63, wvx = tid>>6, wr = wvx>>1, wc = wvx&1, quad = lane>>4, lrow = lane&15;
  int n0 = blockIdx.x<<6;
  const _Float16* Bge = gwt + (size_t)e*4096*1024 + (size_t)n0*1024;
  const _Float16* Bue = gwt + (size_t)e*4096*1024 + (size_t)(2048+n0)*1024;
  int srow = tid>>2;                  // 0..63
  int csw  = (tid&3) ^ (srow&3);
  // hoisted k0-independent row bases (gathered A rows, contiguous B rows)
  const _Float16* ar0 = &h2[(size_t)rowtok[srow   ]*H_DIM + csw*8];
  const _Float16* ar1 = &h2[(size_t)rowtok[64+srow]*H_DIM + csw*8];
  const _Float16* bg0 = Bge + (size_t)srow*1024 + csw*8;
  const _Float16* bu0 = Bue + (size_t)srow*1024 + csw*8;
  auto stage = [&](int bb, int k0){
    gll16(ar0 + k0, &As[bb][wvx*512]);
    gll16(ar1 + k0, &As[bb][2048 + wvx*512]);
    gll16(bg0 + k0, &Bg[bb][wvx*512]);
    gll16(bu0 + k0, &Bu[bb][wvx*512]);
  };
  f32x4 ag[4][2] = {}, au[4][2] = {};
  stage(0, 0);
  __syncthreads();
  int cur = 0;
  int co = (quad ^ (lrow&3))*8;
  for (int k0=0; k0<1024; k0+=32){
    if (k0 < 992) stage(cur^1, k0+32);
    h16x8 a[4], bgf[2], buf_[2];
    #pragma unroll
    for (int i=0;i<4;i++) a[i] = *(const h16x8*)&As[cur][(wr*64 + i*16 + lrow)*32 + co];
    #pragma unroll
    for (int j=0;j<2;j++){
      bgf[j]  = *(const h16x8*)&Bg[cur][(wc*32 + j*16 + lrow)*32 + co];
      buf_[j] = *(const h16x8*)&Bu[cur][(wc*32 + j*16 + lrow)*32 + co];
    }
    #pragma unroll
    for (int i=0;i<4;i++)
      #pragma unroll
      for (int j=0;j<2;j++){
        ag[i][j] = mfma16(a[i], bgf[j],  ag[i][j]);
        au[i][j] = mfma16(a[i], buf_[j], au[i][j]);
      }
    __syncthreads();
    cur ^= 1;
  }
  #pragma unroll
  for (int i=0;i<4;i++)
    #pragma unroll
    for (int j=0;j<2;j++)
      #pragma unroll
      for (int r=0;r<4;r++){
        int row = m0 + wr*64 + i*16 + quad*4 + r;
        int col = n0 + wc*32 + j*16 + lrow;
        float g = ag[i][j][r], u = au[i][j][r];
        float sv = g / (1.0f + __expf(-g));
        act[(size_t)row*INTER_DIM + col] = (_Float16)(sv * u);
      }
}

// down GEMM, B^T [e][n=1024][k=2048] f16; tile 128x128, BK=32, double-buffered
// prefetch pipeline + 2-bit both-sides swizzle; scatter epilogue
__global__ __launch_bounds__(256) void k_gemm_down_t(const _Float16* __restrict__ act,
    const _Float16* __restrict__ dwt, _Float16* __restrict__ slotbuf, const int* __restrict__ list_ts,
    const float* __restrict__ list_w, const int* __restrict__ counts, const int* __restrict__ offs){
  int m0 = blockIdx.y<<7;
  if (m0 >= offs[8]) return;
  int e = 0;
  while (m0 >= offs[e+1]) e++;
  int base = offs[e], cnt = counts[e];
  if (m0 >= base + cnt) return;
  __shared__ __align__(16) _Float16 As[2][128*32], Bs[2][128*32];
  int tid = threadIdx.x, lane = tid&63, wvx = tid>>6;
  int wr = wvx>>1, wc = wvx&1, quad = lane>>4, lrow = lane&15;
  int n0 = blockIdx.x<<7;
  const _Float16* Be = dwt + (size_t)e*1024*2048 + (size_t)n0*2048;
  int srow = tid>>2;                  // 0..63
  int csw  = (tid&3) ^ (srow&3);
  const _Float16* pa0 = &act[(size_t)(m0+srow)*INTER_DIM + csw*8];
  const _Float16* pa1 = &act[(size_t)(m0+64+srow)*INTER_DIM + csw*8];
  const _Float16* pb0 = Be + (size_t)srow*2048 + csw*8;
  const _Float16* pb1 = Be + (size_t)(64+srow)*2048 + csw*8;
  auto stage = [&](int bb, int k0){
    gll16(pa0 + k0, &As[bb][wvx*512]);
    gll16(pa1 + k0, &As[bb][2048 + wvx*512]);
    gll16(pb0 + k0, &Bs[bb][wvx*512]);
    gll16(pb1 + k0, &Bs[bb][2048 + wvx*512]);
  };
  f32x4 acc[4][4] = {};
  stage(0, 0);
  __syncthreads();
  int cur = 0;
  int co = (quad ^ (lrow&3))*8;
  for (int k0=0; k0<2048; k0+=32){
    if (k0 < 2016) stage(cur^1, k0+32);
    h16x8 a[4], b[4];
    #pragma unroll
    for (int i=0;i<4;i++) a[i] = *(const h16x8*)&As[cur][(wr*64 + i*16 + lrow)*32 + co];
    #pragma unroll
    for (int j=0;j<4;j++) b[j] = *(const h16x8*)&Bs[cur][(wc*64 + j*16 + lrow)*32 + co];
    #pragma unroll
    for (int i=0;i<4;i++)
      #pragma unroll
      for (int j=0;j<4;j++)
        acc[i][j] = mfma16(a[i], b[j], acc[i][j]);
    __syncthreads();
    cur ^= 1;
  }
  #pragma unroll
  for (int i=0;i<4;i++)
    #pragma unroll
    for (int r=0;r<4;r++){
      int m = m0 + wr*64 + i*16 + quad*4 + r;
      if (m < base + cnt){
        int ts = list_ts[m];
        float wgt = list_w[m];
        #pragma unroll
        for (int j=0;j<4;j++){
          int col = n0 + wc*64 + j*16 + lrow;
          slotbuf[(size_t)ts*H_DIM + col] = (_Float16)(wgt * acc[i][j][r]);
        }
      }
    }
}

// ======== LEGACY PATH (ws too small for weight transposes) ========

__global__ __launch_bounds__(256) void k_gemm_gu(const _Float16* __restrict__ h2, const void* __restrict__ guw,
    _Float16* __restrict__ act, const int* __restrict__ list_ts,
    const int* __restrict__ counts, const int* __restrict__ offs, const int* __restrict__ df){
  const int is32 = *df;
  int m0 = blockIdx.y<<7;
  if (m0 >= offs[8]) return;
  int e = 0;
  while (m0 >= offs[e+1]) e++;
  int base = offs[e], cnt = counts[e];
  if (m0 >= base + cnt) return;
  __shared__ __align__(16) _Float16 As[128*32], Bg[64*40], Bu[64*40];
  __shared__ int rowtok[128];
  int tid = threadIdx.x;
  if (tid < 128){
    int mc = min(m0 + tid, base + cnt - 1);
    rowtok[tid] = list_ts[mc] >> 1;
  }
  __syncthreads();
  int lane = tid&63, wvx = tid>>6, wr = wvx>>1, wc = wvx&1, quad = lane>>4, lrow = lane&15;
  int n0 = blockIdx.x<<6;
  size_t ebase = (size_t)e*H_DIM*4096;
  f32x4 ag[4][2] = {}, au[4][2] = {};
  for (int k0=0; k0<1024; k0+=32){
    #pragma unroll
    for (int it=0; it<2; it++){
      int ch = it*256 + tid;
      int r = ch>>2, c = ch&3;
      *(i32x4*)&As[ch*8] = *(const i32x4*)&h2[(size_t)rowtok[r]*H_DIM + k0 + c*8];
    }
    {
      int k = tid>>3, g = tid&7;
      size_t rowb = ebase + (size_t)(k0+k)*4096;
      int ks = kslot_sw(k, g);
      _Float16 tg[8], tu[8];
      if (is32){
        const float* gf = (const float*)guw;
        f32x4 a0 = *(const f32x4*)&gf[rowb + n0 + g*8];
        f32x4 a1 = *(const f32x4*)&gf[rowb + n0 + g*8 + 4];
        f32x4 b0 = *(const f32x4*)&gf[rowb + 2048 + n0 + g*8];
        f32x4 b1 = *(const f32x4*)&gf[rowb + 2048 + n0 + g*8 + 4];
        #pragma unroll
        for (int i=0;i<4;i++){ tg[i]=(_Float16)a0[i]; tg[4+i]=(_Float16)a1[i];
                               tu[i]=(_Float16)b0[i]; tu[4+i]=(_Float16)b1[i]; }
      } else {
        const u16* gb = (const u16*)guw;
        u16x4 a0 = *(const u16x4*)&gb[rowb + n0 + g*8];
        u16x4 a1 = *(const u16x4*)&gb[rowb + n0 + g*8 + 4];
        u16x4 b0 = *(const u16x4*)&gb[rowb + 2048 + n0 + g*8];
        u16x4 b1 = *(const u16x4*)&gb[rowb + 2048 + n0 + g*8 + 4];
        #pragma unroll
        for (int i=0;i<4;i++){ tg[i]=(_Float16)bf2f(a0[i]); tg[4+i]=(_Float16)bf2f(a1[i]);
                               tu[i]=(_Float16)bf2f(b0[i]); tu[4+i]=(_Float16)bf2f(b1[i]); }
      }
      #pragma unroll
      for (int i=0;i<8;i++){
        int n = g*8 + i;
        Bg[n*40 + ks] = tg[i];
        Bu[n*40 + ks] = tu[i];
      }
    }
    __syncthreads();
    h16x8 a[4], bg[2], bu[2];
    #pragma unroll
    for (int i=0;i<4;i++) a[i] = *(const h16x8*)&As[(wr*64 + i*16 + lrow)*32 + quad*8];
    #pragma unroll
    for (int j=0;j<2;j++){
      int n = wc*32 + j*16 + lrow;
      int oct = (quad ^ ((n>>3)&3))*8;
      bg[j] = *(const h16x8*)&Bg[n*40 + oct];
      bu[j] = *(const h16x8*)&Bu[n*40 + oct];
    }
    #pragma unroll
    for (int i=0;i<4;i++)
      #pragma unroll
      for (int j=0;j<2;j++){
        ag[i][j] = mfma16(a[i], bg[j], ag[i][j]);
        au[i][j] = mfma16(a[i], bu[j], au[i][j]);
      }
    __syncthreads();
  }
  #pragma unroll
  for (int i=0;i<4;i++)
    #pragma unroll
    for (int j=0;j<2;j++)
      #pragma unroll
      for (int r=0;r<4;r++){
        int row = m0 + wr*64 + i*16 + quad*4 + r;
        int col = n0 + wc*32 + j*16 + lrow;
        float g = ag[i][j][r], u = au[i][j][r];
        float sv = g / (1.0f + __expf(-g));
        act[(size_t)row*INTER_DIM + col] = (_Float16)(sv * u);
      }
}

__global__ __launch_bounds__(256) void k_gemm_down(const _Float16* __restrict__ act, const void* __restrict__ dw,
    _Float16* __restrict__ slotbuf, const int* __restrict__ list_ts, const float* __restrict__ list_w,
    const int* __restrict__ counts, const int* __restrict__ offs, const int* __restrict__ df){
  const int is32 = *df;
  int m0 = blockIdx.y<<7;
  if (m0 >= offs[8]) return;
  int e = 0;
  while (m0 >= offs[e+1]) e++;
  int base = offs[e], cnt = counts[e];
  if (m0 >= base + cnt) return;
  __shared__ __align__(16) _Float16 As[128*32], Bs[128*40];
  int tid = threadIdx.x, lane = tid&63, wvx = tid>>6;
  int wr = wvx>>1, wc = wvx&1, quad = lane>>4, lrow = lane&15;
  int n0 = blockIdx.x<<7;
  size_t ebase = (size_t)e*INTER_DIM*H_DIM;
  f32x4 acc[4][4] = {};
  for (int k0=0; k0<2048; k0+=32){
    #pragma unroll
    for (int it=0; it<2; it++){
      int ch = it*256 + tid;
      int r = ch>>2, c = ch&3;
      *(i32x4*)&As[ch*8] = *(const i32x4*)&act[(size_t)(m0+r)*INTER_DIM + k0 + c*8];
    }
    {
      int k = tid>>3, g = tid&7;
      size_t rowb = ebase + (size_t)(k0+k)*H_DIM;
      int ks = kslot_sw(k, g);
      #pragma unroll
      for (int p=0;p<2;p++){
        _Float16 tb[8];
        if (is32){
          const float* bf = (const float*)dw;
          f32x4 a0 = *(const f32x4*)&bf[rowb + n0 + p*64 + g*8];
          f32x4 a1 = *(const f32x4*)&bf[rowb + n0 + p*64 + g*8 + 4];
          #pragma unroll
          for (int i=0;i<4;i++){ tb[i]=(_Float16)a0[i]; tb[4+i]=(_Float16)a1[i]; }
        } else {
          const u16* bb = (const u16*)dw;
          u16x4 a0 = *(const u16x4*)&bb[rowb + n0 + p*64 + g*8];
          u16x4 a1 = *(const u16x4*)&bb[rowb + n0 + p*64 + g*8 + 4];
          #pragma unroll
          for (int i=0;i<4;i++){ tb[i]=(_Float16)bf2f(a0[i]); tb[4+i]=(_Float16)bf2f(a1[i]); }
        }
        #pragma unroll
        for (int i=0;i<8;i++){
          int n = p*64 + g*8 + i;
          Bs[n*40 + ks] = tb[i];
        }
      }
    }
    __syncthreads();
    h16x8 a[4], b[4];
    #pragma unroll
    for (int i=0;i<4;i++) a[i] = *(const h16x8*)&As[(wr*64 + i*16 + lrow)*32 + quad*8];
    #pragma unroll
    for (int j=0;j<4;j++){
      int n = wc*64 + j*16 + lrow;
      b[j] = *(const h16x8*)&Bs[n*40 + ((quad ^ ((n>>3)&3))*8)];
    }
    #pragma unroll
    for (int i=0;i<4;i++)
      #pragma unroll
      for (int j=0;j<4;j++)
        acc[i][j] = mfma16(a[i], b[j], acc[i][j]);
    __syncthreads();
  }
  #pragma unroll
  for (int i=0;i<4;i++)
    #pragma unroll
    for (int r=0;r<4;r++){
      int m = m0 + wr*64 + i*16 + quad*4 + r;
      if (m < base + cnt){
        int ts = list_ts[m];
        float wgt = list_w[m];
        #pragma unroll
        for (int j=0;j<4;j++){
          int col = n0 + wc*64 + j*16 + lrow;
          slotbuf[(size_t)ts*H_DIM + col] = (_Float16)(wgt * acc[i][j][r]);
        }
      }
    }
}

// ---------------- final residual add -> dual-dtype out ----------------
__global__ __launch_bounds__(256) void k_final(const float* __restrict__ x1, const _Float16* __restrict__ slot,
                                               void* __restrict__ outv, const int* __restrict__ df){
  const int is32 = *df;
  int i4 = (blockIdx.x*256 + threadIdx.x)*4;
  int t = i4 >> 10, c = i4 & 1023;
  f32x4 a = *(const f32x4*)&x1[i4];
  h16x4 s0 = *(const h16x4*)&slot[(size_t)(t*2)*H_DIM + c];
  h16x4 s1 = *(const h16x4*)&slot[(size_t)(t*2+1)*H_DIM + c];
  if (is32){
    f32x4 o;
    #pragma unroll
    for (int m=0;m<4;m++) o[m] = a[m] + (float)s0[m] + (float)s1[m];
    *(f32x4*)&((float*)outv)[i4] = o;
  } else {
    u16x4 o;
    #pragma unroll
    for (int m=0;m<4;m++) o[m] = f2bf(a[m] + (float)s0[m] + (float)s1[m]);
    *(u16x4*)&((u16*)outv)[i4] = o;
  }
}

extern "C" void kernel_launch(void* const* d_in, const int* in_sizes, int n_in,
                              void* d_out, int out_size, void* d_ws, size_t ws_size,
                              hipStream_t stream){
  (void)in_sizes; (void)n_in; (void)out_size;
  const void* x    = d_in[0];
  const void* mask = d_in[1];
  const void* ln1  = d_in[2];
  const void* ln2  = d_in[3];
  const void* qkvw = d_in[4];
  const void* ow   = d_in[5];
  const void* rw   = d_in[6];
  const void* guw  = d_in[7];
  const void* dww  = d_in[8];

  char* ws = (char*)d_ws;
  size_t off = 0;
  auto alloc = [&](size_t b)->void*{ void* p = ws + off; off = (off + b + 255) & ~(size_t)255; return p; };
  int* meta            = (int*)alloc(32*sizeof(int));
  _Float16* qkv_wt     = (_Float16*)alloc((size_t)3072*1024*2);
  _Float16* o_wt       = (_Float16*)alloc((size_t)1024*1024*2);
  _Float16* hpair      = (_Float16*)alloc((size_t)2*4096*1024*2);  // h hi/lo; later aout hi/lo; later slotbuf
  _Float16* qkvpair    = (_Float16*)alloc((size_t)2*4096*3072*2);  // qkv hi/lo; later h2+act
  float* x1            = (float*)alloc((size_t)4096*1024*4);       // V^T hi/lo during attn; then x1
  int* list_ts         = (int*)alloc(MAXROWS*4);
  float* list_w        = (float*)alloc(MAXROWS*4);
  int* tok_e           = (int*)alloc((size_t)4096*2*4);
  float* tok_w         = (float*)alloc((size_t)4096*2*4);
  size_t base_end = off;                                           // ~92 MB
  _Float16* gu_wt      = (_Float16*)alloc((size_t)8*4096*1024*2);  // 67 MB
  _Float16* down_wt    = (_Float16*)alloc((size_t)8*1024*2048*2);  // 34 MB
  const int big = (ws_size >= off) ? 1 : 0;                        // need ~193 MB for hot path
  (void)base_end;

  int* counts = meta;
  int* offs   = meta + 8;
  int* flag   = meta + 25;
  int* dflag  = meta + 26;

  _Float16* h_hi   = hpair;
  _Float16* h_lo   = hpair + (size_t)4096*1024;
  _Float16* qkv_hi = qkvpair;
  _Float16* qkv_lo = qkvpair + (size_t)4096*3072;
  _Float16* vth    = (_Float16*)x1;                     // 8 MB
  _Float16* vtl    = vth + (size_t)64*64*1024;          // 8 MB
  _Float16* ahi    = hpair;                             // aout hi (h dead)
  _Float16* alo    = hpair + (size_t)4096*1024;         // aout lo
  _Float16* h2     = qkvpair;                           // qkv dead after attn
  _Float16* act    = qkvpair + (size_t)4096*1024;
  _Float16* slotbuf= hpair;                             // aout dead after o-proj

  hipMemsetAsync(meta, 0, 32*sizeof(int), stream);
  k_detect<<<dim3(1), dim3(64), 0, stream>>>((const uint32_t*)x, dflag);
  k_trans2<<<dim3(48, 16, 1), 256, 0, stream>>>(qkvw, qkv_wt, 1024, 3072, dflag);
  k_trans2<<<dim3(16, 16, 1), 256, 0, stream>>>(ow, o_wt, 1024, 1024, dflag);
  if (big){
    k_trans2<<<dim3(64, 16, 8), 256, 0, stream>>>(guw, gu_wt, 1024, 4096, dflag);
    k_trans2<<<dim3(16, 32, 8), 256, 0, stream>>>(dww, down_wt, 2048, 1024, dflag);
  }
  k_maskchk<<<dim3(1024), 256, 0, stream>>>(mask, flag, dflag);
  k_rms1<<<dim3(4096), 256, 0, stream>>>(x, ln1, h_hi, h_lo, dflag);
  k_gemm_hl<0><<<dim3(24, 32), 256, 0, stream>>>(h_hi, h_lo, qkv_wt, nullptr, qkv_hi, qkv_lo,
                                                 nullptr, 3072, 1024, dflag);
  k_vt<<<dim3(16, 64), 256, 0, stream>>>(qkv_hi, qkv_lo, vth, vtl);
  k_attn<<<dim3(8, 64), 256, 0, stream>>>(qkv_hi, qkv_lo, vth, vtl, mask, flag, ahi, alo, dflag);
  k_gemm_hl<1><<<dim3(8, 32), 256, 0, stream>>>(ahi, alo, o_wt, x1, nullptr, nullptr,
                                                x, 1024, 1024, dflag);
  k_rms2_router<<<dim3(4096), 256, 0, stream>>>(x1, ln2, rw, h2, tok_e, tok_w, dflag);
  k_route<<<dim3(1), dim3(1024), 0, stream>>>(tok_e, tok_w, counts, offs, list_ts, list_w);
  if (big){
    k_gemm_gu_t<<<dim3(32, 72), 256, 0, stream>>>(h2, gu_wt, act, list_ts, counts, offs);
    k_gemm_down_t<<<dim3(8, 72), 256, 0, stream>>>(act, down_wt, slotbuf, list_ts, list_w, counts, offs);
  } else {
    k_gemm_gu<<<dim3(32, 72), 256, 0, stream>>>(h2, guw, act, list_ts, counts, offs, dflag);
    k_gemm_down<<<dim3(8, 72), 256, 0, stream>>>(act, dww, slotbuf, list_ts, list_w, counts, offs, dflag);
  }
  k_final<<<dim3(4096), 256, 0, stream>>>(x1, slotbuf, d_out, dflag);
}

// Round 6
// 773.330 us; speedup vs baseline: 1.1897x; 1.0009x over previous
//
#include <hip/hip_runtime.h>
#include <cstdint>
#include <cmath>

// Problem constants (B=4, S=1024)
#define T_TOK 4096
#define H_DIM 1024
#define QKV_N 3072
#define S_LEN 1024
#define INTER_DIM 2048
#define MAXROWS 9216   // 2*T + 8*127 padding, rounded

typedef unsigned short u16;
using f32x4 = __attribute__((ext_vector_type(4))) float;
using h16x8 = __attribute__((ext_vector_type(8))) _Float16;
using h16x4 = __attribute__((ext_vector_type(4))) _Float16;
using i32x4 = __attribute__((ext_vector_type(4))) int;
using u16x4 = __attribute__((ext_vector_type(4))) u16;
using u16x8 = __attribute__((ext_vector_type(8))) u16;

__device__ __forceinline__ float bf2f(u16 u){ return __uint_as_float(((uint32_t)u)<<16); }
__device__ __forceinline__ u16 f2bf(float f){
  uint32_t x = __float_as_uint(f);
  uint32_t r = x + 0x7FFFu + ((x>>16)&1u);
  return (u16)(r>>16);
}
__device__ __forceinline__ f32x4 mfma16(h16x8 a, h16x8 b, f32x4 c){
  return __builtin_amdgcn_mfma_f32_16x16x32_f16(a,b,c,0,0,0);
}
__device__ __forceinline__ float rsqrt_acc(float v){
  float r = rsqrtf(v);
  r = r*(1.5f - 0.5f*v*r*r);
  r = r*(1.5f - 0.5f*v*r*r);
  return r;
}
// dual-dtype scalar input read
__device__ __forceinline__ float ldin(const void* p, size_t i, int is32){
  return is32 ? ((const float*)p)[i] : bf2f(((const u16*)p)[i]);
}
// swizzled k-slot for stride-40 B tiles (legacy path)
__device__ __forceinline__ int kslot_sw(int k, int noct){
  return (k&7) | (((k>>3) ^ (noct&3))<<3);
}
// async global->LDS, 16B per lane; lds base must be wave-uniform, lanes land at base+lane*16
__device__ __forceinline__ void gll16(const void* g, void* l){
  __builtin_amdgcn_global_load_lds(
      (const __attribute__((address_space(1))) void*)g,
      (__attribute__((address_space(3))) void*)l, 16, 0, 0);
}

// ---------------- dtype detection: fp32 exponent fields of N(0,1) data ----------------
__global__ void k_detect(const uint32_t* __restrict__ x, int* __restrict__ dflag){
  uint32_t u = x[threadIdx.x];
  int e = (u>>23)&0xFF;
  int ok = (e>=103 && e<=150);            // |f| in [2^-24, 2^23]
  unsigned long long m = __ballot(ok);
  if (threadIdx.x==0) *dflag = (__popcll(m) >= 48) ? 1 : 0;
}

// ---------------- vectorized transpose + cast to f16: src [R][C] -> dst [C][R] ------
// 64x64 tiles; conflict-free LDS (stride 65); 16B global loads/stores
__global__ __launch_bounds__(256) void k_trans2(const void* __restrict__ src,
    _Float16* __restrict__ dst, int R, int C, const int* __restrict__ df){
  const int is32 = *df;
  __shared__ _Float16 t[64][65];
  size_t bo = (size_t)blockIdx.z * R * C;
  int c0 = blockIdx.x<<6, r0 = blockIdx.y<<6;
  int ty = threadIdx.x>>3, tx = threadIdx.x&7;   // ty 0..31, tx 0..7
  #pragma unroll
  for (int rr=0; rr<2; rr++){
    int r = rr*32 + ty;
    size_t gi = bo + (size_t)(r0+r)*C + c0 + tx*8;
    _Float16 v[8];
    if (is32){
      f32x4 a0 = *(const f32x4*)&((const float*)src)[gi];
      f32x4 a1 = *(const f32x4*)&((const float*)src)[gi+4];
      #pragma unroll
      for (int i=0;i<4;i++){ v[i]=(_Float16)a0[i]; v[4+i]=(_Float16)a1[i]; }
    } else {
      u16x8 a = *(const u16x8*)&((const u16*)src)[gi];
      #pragma unroll
      for (int i=0;i<8;i++) v[i]=(_Float16)bf2f(a[i]);
    }
    #pragma unroll
    for (int i=0;i<8;i++) t[r][tx*8+i] = v[i];
  }
  __syncthreads();
  #pragma unroll
  for (int rr=0; rr<2; rr++){
    int n = rr*32 + ty;
    h16x8 v;
    #pragma unroll
    for (int i=0;i<8;i++) v[i] = t[tx*8+i][n];
    *(h16x8*)&dst[bo + (size_t)(c0+n)*R + r0 + tx*8] = v;
  }
}

// ---------------- mask all-zero check ----------------
__global__ __launch_bounds__(256) void k_maskchk(const void* __restrict__ m, int* __restrict__ flag,
                                                 const int* __restrict__ df){
  const int is32 = *df;
  int i = (blockIdx.x*256 + threadIdx.x)*4;
  int nz = 0;
  if (is32){
    f32x4 v = *(const f32x4*)&((const float*)m)[i];
    nz = (v[0]!=0.f)||(v[1]!=0.f)||(v[2]!=0.f)||(v[3]!=0.f);
  } else {
    u16x4 v = *(const u16x4*)&((const u16*)m)[i];
    nz = ((v[0]|v[1]|v[2]|v[3]) & 0x7FFF) != 0;
  }
  if (nz) atomicOr(flag, 1);
}

// ---------------- RMSNorm #1: x -> pre-split f16 hi/lo h ----------------
__global__ __launch_bounds__(256) void k_rms1(const void* __restrict__ x, const void* __restrict__ w,
                                              _Float16* __restrict__ hhi, _Float16* __restrict__ hlo,
                                              const int* __restrict__ df){
  const int is32 = *df;
  int t = blockIdx.x, tid = threadIdx.x;
  size_t base = (size_t)t*H_DIM + tid*4;
  float f[4];
  #pragma unroll
  for (int m=0;m<4;m++) f[m] = ldin(x, base+m, is32);
  float ss = f[0]*f[0] + f[1]*f[1] + f[2]*f[2] + f[3]*f[3];
  #pragma unroll
  for (int off=32; off>0; off>>=1) ss += __shfl_down(ss, off, 64);
  __shared__ float red[4];
  if ((tid & 63) == 0) red[tid>>6] = ss;
  __syncthreads();
  float rstd = rsqrt_acc((red[0]+red[1]+red[2]+red[3]) * (1.0f/H_DIM) + 1e-6f);
  h16x4 oh, ol;
  #pragma unroll
  for (int m=0;m<4;m++){
    float v = f[m]*rstd*ldin(w, tid*4+m, is32);
    _Float16 hh = (_Float16)v;
    oh[m] = hh;
    ol[m] = (_Float16)(v - (float)hh);
  }
  *(h16x4*)&hhi[base] = oh;
  *(h16x4*)&hlo[base] = ol;
}

// ---------------- high-precision GEMM: pre-split f16 hi/lo A, f16 B^T --------------
// BK=32, double-buffered LDS, prefetch-before-compute pipeline (one barrier/K-step),
// both-sides chunk swizzle chunk^=(row>>1)&3 -> 2-way (free) LDS reads.
// EPI==0: write C as f16 hi/lo pair. EPI==1: fp32 C with residual add.
template<int EPI>
__global__ __launch_bounds__(256) void k_gemm_hl(const _Float16* __restrict__ Ah,
    const _Float16* __restrict__ Al, const _Float16* __restrict__ Bt,
    float* __restrict__ C, _Float16* __restrict__ Chi, _Float16* __restrict__ Clo,
    const void* __restrict__ res, int N, int K, const int* __restrict__ df){
  const int is32 = (EPI==1) ? *df : 0;
  __shared__ __align__(16) _Float16 AhS[2][128*32];
  __shared__ __align__(16) _Float16 AlS[2][128*32];
  __shared__ __align__(16) _Float16 Bs[2][128*32];
  int tid = threadIdx.x, lane = tid&63, wvx = tid>>6;
  int wr = wvx>>1, wc = wvx&1, quad = lane>>4, lrow = lane&15;
  int m0 = blockIdx.y<<7, n0 = blockIdx.x<<7;
  // staging geometry: thread covers row srow (+64 for second half), swizzled chunk csw
  int srow = tid>>2;                  // 0..63
  int csw  = (tid&3) ^ ((srow>>1)&3);
  const _Float16* a0h = &Ah[(size_t)(m0+srow)*K + csw*8];
  const _Float16* a1h = &Ah[(size_t)(m0+64+srow)*K + csw*8];
  const _Float16* a0l = &Al[(size_t)(m0+srow)*K + csw*8];
  const _Float16* a1l = &Al[(size_t)(m0+64+srow)*K + csw*8];
  const _Float16* b0  = &Bt[(size_t)(n0+srow)*K + csw*8];
  const _Float16* b1  = &Bt[(size_t)(n0+64+srow)*K + csw*8];
  auto stage = [&](int bb, int k0){
    gll16(a0h + k0, &AhS[bb][wvx*512]);
    gll16(a1h + k0, &AhS[bb][2048 + wvx*512]);
    gll16(a0l + k0, &AlS[bb][wvx*512]);
    gll16(a1l + k0, &AlS[bb][2048 + wvx*512]);
    gll16(b0  + k0, &Bs[bb][wvx*512]);
    gll16(b1  + k0, &Bs[bb][2048 + wvx*512]);
  };
  f32x4 acc[4][4] = {};
  stage(0, 0);
  __syncthreads();
  int cur = 0;
  int co = (quad ^ ((lrow>>1)&3))*8;
  for (int k0=0; k0<K; k0+=32){
    if (k0 + 32 < K) stage(cur^1, k0+32);
    h16x8 ah[4], al[4], bb[4];
    #pragma unroll
    for (int i=0;i<4;i++){
      int ra = (wr*64 + i*16 + lrow)*32;
      ah[i] = *(const h16x8*)&AhS[cur][ra + co];
      al[i] = *(const h16x8*)&AlS[cur][ra + co];
    }
    #pragma unroll
    for (int j=0;j<4;j++) bb[j] = *(const h16x8*)&Bs[cur][(wc*64 + j*16 + lrow)*32 + co];
    #pragma unroll
    for (int i=0;i<4;i++)
      #pragma unroll
      for (int j=0;j<4;j++){
        acc[i][j] = mfma16(ah[i], bb[j], acc[i][j]);
        acc[i][j] = mfma16(al[i], bb[j], acc[i][j]);
      }
    __syncthreads();   // drains this iter's prefetch (had full compute to land); P/C swap
    cur ^= 1;
  }
  #pragma unroll
  for (int i=0;i<4;i++)
    #pragma unroll
    for (int j=0;j<4;j++){
      int col = n0 + wc*64 + j*16 + lrow;
      #pragma unroll
      for (int r=0;r<4;r++){
        int row = m0 + wr*64 + i*16 + quad*4 + r;
        size_t idx = (size_t)row*N + col;
        float v = acc[i][j][r];
        if (EPI==1){
          v += ldin(res, idx, is32);
          C[idx] = v;
        } else {
          _Float16 hh = (_Float16)v;
          Chi[idx] = hh;
          Clo[idx] = (_Float16)(v - (float)hh);
        }
      }
    }
}

// ---------------- V^T prep: qkv hi/lo V-slice -> [bh][64 d][1024 keys] f16 hi/lo ----
__global__ __launch_bounds__(256) void k_vt(const _Float16* __restrict__ qh,
    const _Float16* __restrict__ ql, _Float16* __restrict__ vth, _Float16* __restrict__ vtl){
  __shared__ _Float16 th[64][72];
  __shared__ _Float16 tl[64][72];
  int bh = blockIdx.y;           // 0..63
  int b = bh>>4, h = bh&15;
  int key0 = blockIdx.x<<6;      // 16 tiles of 64 keys
  size_t tok0 = (size_t)b*S_LEN;
  int ty = threadIdx.x>>3, tx = threadIdx.x&7;  // ty 0..31, tx 0..7
  #pragma unroll
  for (int rr=0; rr<2; rr++){
    int r = rr*32 + ty;          // key within tile
    size_t gi = (tok0 + key0 + r)*(size_t)QKV_N + 2048 + h*64 + tx*8;
    h16x8 vh_ = *(const h16x8*)&qh[gi];
    h16x8 vl_ = *(const h16x8*)&ql[gi];
    #pragma unroll
    for (int i=0;i<8;i++){ th[r][tx*8+i] = vh_[i]; tl[r][tx*8+i] = vl_[i]; }
  }
  __syncthreads();
  size_t dbase = (size_t)bh*64*1024;
  #pragma unroll
  for (int rr=0; rr<2; rr++){
    int d = rr*32 + ty;
    h16x8 oh, ol;
    #pragma unroll
    for (int i=0;i<8;i++){ oh[i] = th[tx*8+i][d]; ol[i] = tl[tx*8+i][d]; }
    *(h16x8*)&vth[dbase + (size_t)d*1024 + key0 + tx*8] = oh;
    *(h16x8*)&vtl[dbase + (size_t)d*1024 + key0 + tx*8] = ol;
  }
}

// ---------------- flash attention v3: KVBLK=64, reg-prefetch staging, swizzled LDS --
// LDS pool 64KB: Khi[64k][64d] 8KB, Klo 8KB, Vth[64d][64k] 8KB, Vtl 8KB,
//                Phi[128r][64k] 16KB, Plo 16KB. Q staged through pool[0..16383] once.
__global__ __launch_bounds__(256, 2) void k_attn(const _Float16* __restrict__ qkvh,
    const _Float16* __restrict__ qkvl, const _Float16* __restrict__ vth_g,
    const _Float16* __restrict__ vtl_g, const void* __restrict__ mask,
    const int* __restrict__ mflag, _Float16* __restrict__ ohi, _Float16* __restrict__ olo,
    const int* __restrict__ df){
  const int is32 = *df;
  __shared__ __align__(16) _Float16 pool[32768];   // 64 KB
  _Float16* Khi = pool;            // [64 key][64 d], row-XOR swizzled
  _Float16* Klo = pool + 4096;
  _Float16* Vth = pool + 8192;     // [64 d][64 key], row-XOR swizzled
  _Float16* Vtl = pool + 12288;
  _Float16* Phi = pool + 16384;    // [128 row][64 key], row-XOR swizzled
  _Float16* Plo = pool + 24576;
  int qt = blockIdx.x, bh = blockIdx.y;
  int b = bh>>4, h = bh&15;
  int tid = threadIdx.x, lane = tid&63, wvx = tid>>6, quad = lane>>4, lrow = lane&15;
  size_t tok0 = (size_t)b*S_LEN;
  int q0 = qt<<7;
  // ---- stage Q hi/lo (32KB) into pool, pull fragments into registers ----
  {
    int r = tid>>2, cg = (tid&3)*8;
    #pragma unroll
    for (int p=0;p<2;p++)
      #pragma unroll
      for (int g=0;g<2;g++){
        size_t src = (tok0 + q0 + g*64 + r)*(size_t)QKV_N + h*64 + p*32 + cg;
        gll16(&qkvh[src], &pool[p*4096 + g*2048 + wvx*512]);
        gll16(&qkvl[src], &pool[8192 + p*4096 + g*2048 + wvx*512]);
      }
  }
  __syncthreads();
  h16x8 qfh[2][2], qfl[2][2];
  #pragma unroll
  for (int p=0;p<2;p++)
    #pragma unroll
    for (int i=0;i<2;i++){
      qfh[p][i] = *(const h16x8*)&pool[(p*128 + wvx*32 + i*16 + lrow)*32 + quad*8];
      qfl[p][i] = *(const h16x8*)&pool[8192 + (p*128 + wvx*32 + i*16 + lrow)*32 + quad*8];
    }
  int useMask = *mflag;
  float mrun[2][4], lrun[2][4];
  f32x4 oacc[2][4] = {};
  #pragma unroll
  for (int i=0;i<2;i++)
    #pragma unroll
    for (int r=0;r<4;r++){ mrun[i][r] = -INFINITY; lrun[i][r] = 0.f; }
  size_t vbase = (size_t)bh*64*1024;
  // per-thread staging geometry: chunk it covers rows it*32+(tid>>3), 8 halfs at (tid&7)*8
  int krow = tid>>3;                    // 0..31
  int c8   = (tid&7)*8;
  int rsw  = ((tid>>3)&7)<<3;           // store-side row XOR swizzle
  int fsw  = (lrow&7)<<3;               // fragment-read row XOR swizzle
  size_t ksrc0 = (tok0 + krow)*(size_t)QKV_N + 1024 + h*64 + c8;
  size_t vsrc0 = vbase + (size_t)krow*1024 + c8;
  h16x8 kh_r[2], kl_r[2], vh_r[2], vl_r[2];
  // prefetch tile 0 into regs
  {
    size_t ks0 = ksrc0, ks1 = ksrc0 + (size_t)32*QKV_N;
    kh_r[0] = *(const h16x8*)&qkvh[ks0];  kl_r[0] = *(const h16x8*)&qkvl[ks0];
    kh_r[1] = *(const h16x8*)&qkvh[ks1];  kl_r[1] = *(const h16x8*)&qkvl[ks1];
    size_t vs0 = vsrc0, vs1 = vsrc0 + 32*1024;
    vh_r[0] = *(const h16x8*)&vth_g[vs0]; vl_r[0] = *(const h16x8*)&vtl_g[vs0];
    vh_r[1] = *(const h16x8*)&vth_g[vs1]; vl_r[1] = *(const h16x8*)&vtl_g[vs1];
  }
  __syncthreads();   // Q-frag reads done everywhere; pool reusable

  for (int kt=0; kt<16; kt++){
    int key0 = kt*64;
    // store staged K/V regs -> LDS (swizzled, conflict-free 16B stripes)
    {
      int o0 = (tid*8) ^ rsw, o1 = (2048 + tid*8) ^ rsw;
      *(h16x8*)&Khi[o0] = kh_r[0];  *(h16x8*)&Khi[o1] = kh_r[1];
      *(h16x8*)&Klo[o0] = kl_r[0];  *(h16x8*)&Klo[o1] = kl_r[1];
      *(h16x8*)&Vth[o0] = vh_r[0];  *(h16x8*)&Vth[o1] = vh_r[1];
      *(h16x8*)&Vtl[o0] = vl_r[0];  *(h16x8*)&Vtl[o1] = vl_r[1];
    }
    // prefetch tile kt+1 into regs (hides under the whole compute phase)
    if (kt < 15){
      size_t ks0 = ksrc0 + (size_t)(key0+64)*QKV_N, ks1 = ks0 + (size_t)32*QKV_N;
      kh_r[0] = *(const h16x8*)&qkvh[ks0];  kl_r[0] = *(const h16x8*)&qkvl[ks0];
      kh_r[1] = *(const h16x8*)&qkvh[ks1];  kl_r[1] = *(const h16x8*)&qkvl[ks1];
      size_t vs0 = vsrc0 + (key0+64), vs1 = vs0 + 32*1024;
      vh_r[0] = *(const h16x8*)&vth_g[vs0]; vl_r[0] = *(const h16x8*)&vtl_g[vs0];
      vh_r[1] = *(const h16x8*)&vth_g[vs1]; vl_r[1] = *(const h16x8*)&vtl_g[vs1];
    }
    __syncthreads();   // K/V tile visible
    // ---- QK^T ----
    f32x4 sacc[2][4] = {};
    __builtin_amdgcn_s_setprio(1);
    #pragma unroll
    for (int p=0;p<2;p++){
      h16x8 kh[4], kl[4];
      #pragma unroll
      for (int j=0;j<4;j++){
        int kidx = ((j*16+lrow)*64 + p*32 + quad*8) ^ fsw;
        kh[j] = *(const h16x8*)&Khi[kidx];
        kl[j] = *(const h16x8*)&Klo[kidx];
      }
      #pragma unroll
      for (int i=0;i<2;i++)
        #pragma unroll
        for (int j=0;j<4;j++){
          sacc[i][j] = mfma16(qfh[p][i], kh[j], sacc[i][j]);
          sacc[i][j] = mfma16(qfh[p][i], kl[j], sacc[i][j]);
          sacc[i][j] = mfma16(qfl[p][i], kh[j], sacc[i][j]);
        }
    }
    __builtin_amdgcn_s_setprio(0);
    // ---- online softmax over 64 keys ----
    #pragma unroll
    for (int i=0;i<2;i++){
      #pragma unroll
      for (int r=0;r<4;r++){
        int qrow = q0 + wvx*32 + i*16 + quad*4 + r;
        float s[4];
        #pragma unroll
        for (int j=0;j<4;j++){
          float sv = sacc[i][j][r] * 0.125f;
          if (useMask) sv += ldin(mask, (size_t)qrow*S_LEN + key0 + j*16 + lrow, is32);
          s[j] = sv;
        }
        float mx = fmaxf(fmaxf(s[0],s[1]), fmaxf(s[2],s[3]));
        #pragma unroll
        for (int mm=1; mm<=8; mm<<=1) mx = fmaxf(mx, __shfl_xor(mx, mm, 64));
        float mnew = fmaxf(mrun[i][r], mx);
        float alpha = __expf(mrun[i][r] - mnew);
        float ps = 0.f;
        #pragma unroll
        for (int j=0;j<4;j++){
          float p = __expf(s[j] - mnew);
          s[j] = p;
          ps += p;
        }
        #pragma unroll
        for (int mm=1; mm<=8; mm<<=1) ps += __shfl_xor(ps, mm, 64);
        lrun[i][r] = lrun[i][r]*alpha + ps;
        mrun[i][r] = mnew;
        #pragma unroll
        for (int jd=0;jd<4;jd++) oacc[i][jd][r] *= alpha;
        int prow = wvx*32 + i*16 + quad*4 + r;
        int pswz = (prow&7)<<3;
        #pragma unroll
        for (int j=0;j<4;j++){
          int pidx = (prow*64 + j*16 + lrow) ^ pswz;
          float pv = s[j];
          _Float16 ph = (_Float16)pv;
          Phi[pidx] = ph;
          Plo[pidx] = (_Float16)(pv - (float)ph);
        }
      }
    }
    __syncthreads();   // P visible; K reads done
    // ---- PV ----
    {
      h16x8 pf[2][2], pl[2][2];
      #pragma unroll
      for (int i=0;i<2;i++)
        #pragma unroll
        for (int ks=0;ks<2;ks++){
          int pidx = ((wvx*32 + i*16 + lrow)*64 + ks*32 + quad*8) ^ fsw;
          pf[i][ks] = *(const h16x8*)&Phi[pidx];
          pl[i][ks] = *(const h16x8*)&Plo[pidx];
        }
      __builtin_amdgcn_s_setprio(1);
      #pragma unroll
      for (int ks=0;ks<2;ks++){
        h16x8 vh[4], vl[4];
        #pragma unroll
        for (int jd=0;jd<4;jd++){
          int vidx = ((jd*16+lrow)*64 + ks*32 + quad*8) ^ fsw;
          vh[jd] = *(const h16x8*)&Vth[vidx];
          vl[jd] = *(const h16x8*)&Vtl[vidx];
        }
        #pragma unroll
        for (int i=0;i<2;i++)
          #pragma unroll
          for (int jd=0;jd<4;jd++){
            oacc[i][jd] = mfma16(pf[i][ks], vh[jd], oacc[i][jd]);
            oacc[i][jd] = mfma16(pf[i][ks], vl[jd], oacc[i][jd]);
            oacc[i][jd] = mfma16(pl[i][ks], vh[jd], oacc[i][jd]);
          }
      }
      __builtin_amdgcn_s_setprio(0);
    }
    __syncthreads();   // V/P reads done; next iter may overwrite
  }
  #pragma unroll
  for (int i=0;i<2;i++)
    #pragma unroll
    for (int j=0;j<4;j++)
      #pragma unroll
      for (int r=0;r<4;r++){
        int row = q0 + wvx*32 + i*16 + quad*4 + r;
        int col = h*64 + j*16 + lrow;
        size_t idx = (tok0 + row)*H_DIM + col;
        float v = oacc[i][j][r] / lrun[i][r];
        _Float16 hh = (_Float16)v;
        ohi[idx] = hh;
        olo[idx] = (_Float16)(v - (float)hh);
      }
}

// ---------------- RMSNorm #2 + router (fp32 logits, top-2; NO global atomics) ------
__global__ __launch_bounds__(256) void k_rms2_router(const float* __restrict__ x1, const void* __restrict__ w,
    const void* __restrict__ rw, _Float16* __restrict__ h2,
    int* __restrict__ tok_e, float* __restrict__ tok_w,
    const int* __restrict__ df){
  const int is32 = *df;
  int t = blockIdx.x, tid = threadIdx.x;
  f32x4 v = *(const f32x4*)&x1[(size_t)t*H_DIM + tid*4];
  float ss = v[0]*v[0]+v[1]*v[1]+v[2]*v[2]+v[3]*v[3];
  #pragma unroll
  for (int off=32; off>0; off>>=1) ss += __shfl_down(ss, off, 64);
  __shared__ float red[4];
  __shared__ float lgs[32];
  if ((tid&63)==0) red[tid>>6] = ss;
  __syncthreads();
  float rstd = rsqrt_acc((red[0]+red[1]+red[2]+red[3])*(1.0f/H_DIM) + 1e-6f);
  float hv[4];
  h16x4 hst;
  #pragma unroll
  for (int m=0;m<4;m++){ hv[m] = v[m]*rstd*ldin(w, tid*4+m, is32); hst[m] = (_Float16)hv[m]; }
  *(h16x4*)&h2[(size_t)t*H_DIM + tid*4] = hst;
  float part[8] = {0,0,0,0,0,0,0,0};
  #pragma unroll
  for (int m=0;m<4;m++){
    size_t c = (size_t)(tid*4 + m)*8;
    #pragma unroll
    for (int e=0;e<8;e++) part[e] += hv[m]*ldin(rw, c+e, is32);
  }
  #pragma unroll
  for (int e=0;e<8;e++){
    #pragma unroll
    for (int off=32; off>0; off>>=1) part[e] += __shfl_down(part[e], off, 64);
  }
  if ((tid&63)==0){
    #pragma unroll
    for (int e=0;e<8;e++) lgs[(tid>>6)*8 + e] = part[e];
  }
  __syncthreads();
  if (tid==0){
    float lg[8];
    #pragma unroll
    for (int e=0;e<8;e++) lg[e] = lgs[e] + lgs[8+e] + lgs[16+e] + lgs[24+e];
    int e0 = 0;
    #pragma unroll
    for (int e=1;e<8;e++) if (lg[e] > lg[e0]) e0 = e;
    int e1 = (e0==0) ? 1 : 0;
    #pragma unroll
    for (int e=0;e<8;e++) if (e != e0 && lg[e] > lg[e1]) e1 = e;
    float d = expf(lg[e1] - lg[e0]);
    float w0 = 1.0f/(1.0f + d);
    float w1 = d * w0;
    tok_e[t*2] = e0; tok_e[t*2+1] = e1;
    tok_w[t*2] = w0; tok_w[t*2+1] = w1;
  }
}

// ---------------- single-block routing: counts + offsets + compact lists -----------
// 1024 threads x 8 slots each; register counting + shfl reduce (no global atomics);
// scatter via LDS atomics (8 counters on 8 distinct banks).
__global__ __launch_bounds__(1024) void k_route(const int* __restrict__ tok_e,
    const float* __restrict__ tok_w, int* __restrict__ counts, int* __restrict__ offs,
    int* __restrict__ list_ts, float* __restrict__ list_w){
  __shared__ int scnt[8];
  __shared__ int sfill[8];
  int tid = threadIdx.x;
  if (tid < 8) scnt[tid] = 0;
  __syncthreads();
  int te0,te1,te2,te3,te4,te5,te6,te7;
  float tw0,tw1,tw2,tw3,tw4,tw5,tw6,tw7;
  i32x4 ea = *(const i32x4*)&tok_e[tid*8];
  i32x4 eb = *(const i32x4*)&tok_e[tid*8+4];
  f32x4 wa = *(const f32x4*)&tok_w[tid*8];
  f32x4 wb = *(const f32x4*)&tok_w[tid*8+4];
  te0=ea[0]; te1=ea[1]; te2=ea[2]; te3=ea[3];
  te4=eb[0]; te5=eb[1]; te6=eb[2]; te7=eb[3];
  tw0=wa[0]; tw1=wa[1]; tw2=wa[2]; tw3=wa[3];
  tw4=wb[0]; tw5=wb[1]; tw6=wb[2]; tw7=wb[3];
  #pragma unroll
  for (int q=0;q<8;q++){
    int v = (te0==q)+(te1==q)+(te2==q)+(te3==q)+(te4==q)+(te5==q)+(te6==q)+(te7==q);
    #pragma unroll
    for (int off=32; off>0; off>>=1) v += __shfl_down(v, off, 64);
    if ((tid&63)==0 && v) atomicAdd(&scnt[q], v);   // 16 waves x 8 LDS atomics
  }
  __syncthreads();
  if (tid==0){
    int o = 0;
    #pragma unroll
    for (int e=0;e<8;e++){
      counts[e] = scnt[e];
      offs[e] = o;
      sfill[e] = o;
      o += (scnt[e] + 127) & ~127;
    }
    offs[8] = o;
  }
  __syncthreads();
  int p;
  p = atomicAdd(&sfill[te0],1); list_ts[p]=tid*8+0; list_w[p]=tw0;
  p = atomicAdd(&sfill[te1],1); list_ts[p]=tid*8+1; list_w[p]=tw1;
  p = atomicAdd(&sfill[te2],1); list_ts[p]=tid*8+2; list_w[p]=tw2;
  p = atomicAdd(&sfill[te3],1); list_ts[p]=tid*8+3; list_w[p]=tw3;
  p = atomicAdd(&sfill[te4],1); list_ts[p]=tid*8+4; list_w[p]=tw4;
  p = atomicAdd(&sfill[te5],1); list_ts[p]=tid*8+5; list_w[p]=tw5;
  p = atomicAdd(&sfill[te6],1); list_ts[p]=tid*8+6; list_w[p]=tw6;
  p = atomicAdd(&sfill[te7],1); list_ts[p]=tid*8+7; list_w[p]=tw7;
}

// ======== HOT PATH: pre-transposed f16 weights + global_load_lds staging ========

// gate+up GEMM, B^T [e][n=4096][k=1024] f16; tile 128m x (64 gate + 64 up), BK=32,
// double-buffered prefetch pipeline + both-sides chunk swizzle ((row>>1)&3)
__global__ __launch_bounds__(256) void k_gemm_gu_t(const _Float16* __restrict__ h2,
    const _Float16* __restrict__ gwt, _Float16* __restrict__ act, const int* __restrict__ list_ts,
    const int* __restrict__ counts, const int* __restrict__ offs){
  int m0 = blockIdx.y<<7;
  if (m0 >= offs[8]) return;
  int e = 0;
  while (m0 >= offs[e+1]) e++;
  int base = offs[e], cnt = counts[e];
  if (m0 >= base + cnt) return;
  __shared__ __align__(16) _Float16 As[2][128*32], Bg[2][64*32], Bu[2][64*32];
  __shared__ int rowtok[128];
  int tid = threadIdx.x;
  if (tid < 128) rowtok[tid] = list_ts[min(m0 + tid, base + cnt - 1)] >> 1;
  __syncthreads();
  int lane = tid&63, wvx = tid>>6, wr = wvx>>1, wc = wvx&1, quad = lane>>4, lrow = lane&15;
  int n0 = blockIdx.x<<6;
  const _Float16* Bge = gwt + (size_t)e*4096*1024 + (size_t)n0*1024;
  const _Float16* Bue = gwt + (size_t)e*4096*1024 + (size_t)(2048+n0)*1024;
  int srow = tid>>2;                  // 0..63
  int csw  = (tid&3) ^ ((srow>>1)&3);
  // hoisted k0-independent row bases (gathered A rows, contiguous B rows)
  const _Float16* ar0 = &h2[(size_t)rowtok[srow   ]*H_DIM + csw*8];
  const _Float16* ar1 = &h2[(size_t)rowtok[64+srow]*H_DIM + csw*8];
  const _Float16* bg0 = Bge + (size_t)srow*1024 + csw*8;
  const _Float16* bu0 = Bue + (size_t)srow*1024 + csw*8;
  auto stage = [&](int bb, int k0){
    gll16(ar0 + k0, &As[bb][wvx*512]);
    gll16(ar1 + k0, &As[bb][2048 + wvx*512]);
    gll16(bg0 + k0, &Bg[bb][wvx*512]);
    gll16(bu0 + k0, &Bu[bb][wvx*512]);
  };
  f32x4 ag[4][2] = {}, au[4][2] = {};
  stage(0, 0);
  __syncthreads();
  int cur = 0;
  int co = (quad ^ ((lrow>>1)&3))*8;
  for (int k0=0; k0<1024; k0+=32){
    if (k0 < 992) stage(cur^1, k0+32);
    h16x8 a[4], bgf[2], buf_[2];
    #pragma unroll
    for (int i=0;i<4;i++) a[i] = *(const h16x8*)&As[cur][(wr*64 + i*16 + lrow)*32 + co];
    #pragma unroll
    for (int j=0;j<2;j++){
      bgf[j]  = *(const h16x8*)&Bg[cur][(wc*32 + j*16 + lrow)*32 + co];
      buf_[j] = *(const h16x8*)&Bu[cur][(wc*32 + j*16 + lrow)*32 + co];
    }
    #pragma unroll
    for (int i=0;i<4;i++)
      #pragma unroll
      for (int j=0;j<2;j++){
        ag[i][j] = mfma16(a[i], bgf[j],  ag[i][j]);
        au[i][j] = mfma16(a[i], buf_[j], au[i][j]);
      }
    __syncthreads();
    cur ^= 1;
  }
  #pragma unroll
  for (int i=0;i<4;i++)
    #pragma unroll
    for (int j=0;j<2;j++)
      #pragma unroll
      for (int r=0;r<4;r++){
        int row = m0 + wr*64 + i*16 + quad*4 + r;
        int col = n0 + wc*32 + j*16 + lrow;
        float g = ag[i][j][r], u = au[i][j][r];
        float sv = g / (1.0f + __expf(-g));
        act[(size_t)row*INTER_DIM + col] = (_Float16)(sv * u);
      }
}

// down GEMM, B^T [e][n=1024][k=2048] f16; tile 128x128, BK=32, double-buffered
// prefetch pipeline + both-sides swizzle ((row>>1)&3); scatter epilogue
__global__ __launch_bounds__(256) void k_gemm_down_t(const _Float16* __restrict__ act,
    const _Float16* __restrict__ dwt, _Float16* __restrict__ slotbuf, const int* __restrict__ list_ts,
    const float* __restrict__ list_w, const int* __restrict__ counts, const int* __restrict__ offs){
  int m0 = blockIdx.y<<7;
  if (m0 >= offs[8]) return;
  int e = 0;
  while (m0 >= offs[e+1]) e++;
  int base = offs[e], cnt = counts[e];
  if (m0 >= base + cnt) return;
  __shared__ __align__(16) _Float16 As[2][128*32], Bs[2][128*32];
  int tid = threadIdx.x, lane = tid&63, wvx = tid>>6;
  int wr = wvx>>1, wc = wvx&1, quad = lane>>4, lrow = lane&15;
  int n0 = blockIdx.x<<7;
  const _Float16* Be = dwt + (size_t)e*1024*2048 + (size_t)n0*2048;
  int srow = tid>>2;                  // 0..63
  int csw  = (tid&3) ^ ((srow>>1)&3);
  const _Float16* pa0 = &act[(size_t)(m0+srow)*INTER_DIM + csw*8];
  const _Float16* pa1 = &act[(size_t)(m0+64+srow)*INTER_DIM + csw*8];
  const _Float16* pb0 = Be + (size_t)srow*2048 + csw*8;
  const _Float16* pb1 = Be + (size_t)(64+srow)*2048 + csw*8;
  auto stage = [&](int bb, int k0){
    gll16(pa0 + k0, &As[bb][wvx*512]);
    gll16(pa1 + k0, &As[bb][2048 + wvx*512]);
    gll16(pb0 + k0, &Bs[bb][wvx*512]);
    gll16(pb1 + k0, &Bs[bb][2048 + wvx*512]);
  };
  f32x4 acc[4][4] = {};
  stage(0, 0);
  __syncthreads();
  int cur = 0;
  int co = (quad ^ ((lrow>>1)&3))*8;
  for (int k0=0; k0<2048; k0+=32){
    if (k0 < 2016) stage(cur^1, k0+32);
    h16x8 a[4], b[4];
    #pragma unroll
    for (int i=0;i<4;i++) a[i] = *(const h16x8*)&As[cur][(wr*64 + i*16 + lrow)*32 + co];
    #pragma unroll
    for (int j=0;j<4;j++) b[j] = *(const h16x8*)&Bs[cur][(wc*64 + j*16 + lrow)*32 + co];
    #pragma unroll
    for (int i=0;i<4;i++)
      #pragma unroll
      for (int j=0;j<4;j++)
        acc[i][j] = mfma16(a[i], b[j], acc[i][j]);
    __syncthreads();
    cur ^= 1;
  }
  #pragma unroll
  for (int i=0;i<4;i++)
    #pragma unroll
    for (int r=0;r<4;r++){
      int m = m0 + wr*64 + i*16 + quad*4 + r;
      if (m < base + cnt){
        int ts = list_ts[m];
        float wgt = list_w[m];
        #pragma unroll
        for (int j=0;j<4;j++){
          int col = n0 + wc*64 + j*16 + lrow;
          slotbuf[(size_t)ts*H_DIM + col] = (_Float16)(wgt * acc[i][j][r]);
        }
      }
    }
}

// ======== LEGACY PATH (ws too small for weight transposes) ========

__global__ __launch_bounds__(256) void k_gemm_gu(const _Float16* __restrict__ h2, const void* __restrict__ guw,
    _Float16* __restrict__ act, const int* __restrict__ list_ts,
    const int* __restrict__ counts, const int* __restrict__ offs, const int* __restrict__ df){
  const int is32 = *df;
  int m0 = blockIdx.y<<7;
  if (m0 >= offs[8]) return;
  int e = 0;
  while (m0 >= offs[e+1]) e++;
  int base = offs[e], cnt = counts[e];
  if (m0 >= base + cnt) return;
  __shared__ __align__(16) _Float16 As[128*32], Bg[64*40], Bu[64*40];
  __shared__ int rowtok[128];
  int tid = threadIdx.x;
  if (tid < 128){
    int mc = min(m0 + tid, base + cnt - 1);
    rowtok[tid] = list_ts[mc] >> 1;
  }
  __syncthreads();
  int lane = tid&63, wvx = tid>>6, wr = wvx>>1, wc = wvx&1, quad = lane>>4, lrow = lane&15;
  int n0 = blockIdx.x<<6;
  size_t ebase = (size_t)e*H_DIM*4096;
  f32x4 ag[4][2] = {}, au[4][2] = {};
  for (int k0=0; k0<1024; k0+=32){
    #pragma unroll
    for (int it=0; it<2; it++){
      int ch = it*256 + tid;
      int r = ch>>2, c = ch&3;
      *(i32x4*)&As[ch*8] = *(const i32x4*)&h2[(size_t)rowtok[r]*H_DIM + k0 + c*8];
    }
    {
      int k = tid>>3, g = tid&7;
      size_t rowb = ebase + (size_t)(k0+k)*4096;
      int ks = kslot_sw(k, g);
      _Float16 tg[8], tu[8];
      if (is32){
        const float* gf = (const float*)guw;
        f32x4 a0 = *(const f32x4*)&gf[rowb + n0 + g*8];
        f32x4 a1 = *(const f32x4*)&gf[rowb + n0 + g*8 + 4];
        f32x4 b0 = *(const f32x4*)&gf[rowb + 2048 + n0 + g*8];
        f32x4 b1 = *(const f32x4*)&gf[rowb + 2048 + n0 + g*8 + 4];
        #pragma unroll
        for (int i=0;i<4;i++){ tg[i]=(_Float16)a0[i]; tg[4+i]=(_Float16)a1[i];
                               tu[i]=(_Float16)b0[i]; tu[4+i]=(_Float16)b1[i]; }
      } else {
        const u16* gb = (const u16*)guw;
        u16x4 a0 = *(const u16x4*)&gb[rowb + n0 + g*8];
        u16x4 a1 = *(const u16x4*)&gb[rowb + n0 + g*8 + 4];
        u16x4 b0 = *(const u16x4*)&gb[rowb + 2048 + n0 + g*8];
        u16x4 b1 = *(const u16x4*)&gb[rowb + 2048 + n0 + g*8 + 4];
        #pragma unroll
        for (int i=0;i<4;i++){ tg[i]=(_Float16)bf2f(a0[i]); tg[4+i]=(_Float16)bf2f(a1[i]);
                               tu[i]=(_Float16)bf2f(b0[i]); tu[4+i]=(_Float16)bf2f(b1[i]); }
      }
      #pragma unroll
      for (int i=0;i<8;i++){
        int n = g*8 + i;
        Bg[n*40 + ks] = tg[i];
        Bu[n*40 + ks] = tu[i];
      }
    }
    __syncthreads();
    h16x8 a[4], bg[2], bu[2];
    #pragma unroll
    for (int i=0;i<4;i++) a[i] = *(const h16x8*)&As[(wr*64 + i*16 + lrow)*32 + quad*8];
    #pragma unroll
    for (int j=0;j<2;j++){
      int n = wc*32 + j*16 + lrow;
      int oct = (quad ^ ((n>>3)&3))*8;
      bg[j] = *(const h16x8*)&Bg[n*40 + oct];
      bu[j] = *(const h16x8*)&Bu[n*40 + oct];
    }
    #pragma unroll
    for (int i=0;i<4;i++)
      #pragma unroll
      for (int j=0;j<2;j++){
        ag[i][j] = mfma16(a[i], bg[j], ag[i][j]);
        au[i][j] = mfma16(a[i], bu[j], au[i][j]);
      }
    __syncthreads();
  }
  #pragma unroll
  for (int i=0;i<4;i++)
    #pragma unroll
    for (int j=0;j<2;j++)
      #pragma unroll
      for (int r=0;r<4;r++){
        int row = m0 + wr*64 + i*16 + quad*4 + r;
        int col = n0 + wc*32 + j*16 + lrow;
        float g = ag[i][j][r], u = au[i][j][r];
        float sv = g / (1.0f + __expf(-g));
        act[(size_t)row*INTER_DIM + col] = (_Float16)(sv * u);
      }
}

__global__ __launch_bounds__(256) void k_gemm_down(const _Float16* __restrict__ act, const void* __restrict__ dw,
    _Float16* __restrict__ slotbuf, const int* __restrict__ list_ts, const float* __restrict__ list_w,
    const int* __restrict__ counts, const int* __restrict__ offs, const int* __restrict__ df){
  const int is32 = *df;
  int m0 = blockIdx.y<<7;
  if (m0 >= offs[8]) return;
  int e = 0;
  while (m0 >= offs[e+1]) e++;
  int base = offs[e], cnt = counts[e];
  if (m0 >= base + cnt) return;
  __shared__ __align__(16) _Float16 As[128*32], Bs[128*40];
  int tid = threadIdx.x, lane = tid&63, wvx = tid>>6;
  int wr = wvx>>1, wc = wvx&1, quad = lane>>4, lrow = lane&15;
  int n0 = blockIdx.x<<7;
  size_t ebase = (size_t)e*INTER_DIM*H_DIM;
  f32x4 acc[4][4] = {};
  for (int k0=0; k0<2048; k0+=32){
    #pragma unroll
    for (int it=0; it<2; it++){
      int ch = it*256 + tid;
      int r = ch>>2, c = ch&3;
      *(i32x4*)&As[ch*8] = *(const i32x4*)&act[(size_t)(m0+r)*INTER_DIM + k0 + c*8];
    }
    {
      int k = tid>>3, g = tid&7;
      size_t rowb = ebase + (size_t)(k0+k)*H_DIM;
      int ks = kslot_sw(k, g);
      #pragma unroll
      for (int p=0;p<2;p++){
        _Float16 tb[8];
        if (is32){
          const float* bf = (const float*)dw;
          f32x4 a0 = *(const f32x4*)&bf[rowb + n0 + p*64 + g*8];
          f32x4 a1 = *(const f32x4*)&bf[rowb + n0 + p*64 + g*8 + 4];
          #pragma unroll
          for (int i=0;i<4;i++){ tb[i]=(_Float16)a0[i]; tb[4+i]=(_Float16)a1[i]; }
        } else {
          const u16* bb = (const u16*)dw;
          u16x4 a0 = *(const u16x4*)&bb[rowb + n0 + p*64 + g*8];
          u16x4 a1 = *(const u16x4*)&bb[rowb + n0 + p*64 + g*8 + 4];
          #pragma unroll
          for (int i=0;i<4;i++){ tb[i]=(_Float16)bf2f(a0[i]); tb[4+i]=(_Float16)bf2f(a1[i]); }
        }
        #pragma unroll
        for (int i=0;i<8;i++){
          int n = p*64 + g*8 + i;
          Bs[n*40 + ks] = tb[i];
        }
      }
    }
    __syncthreads();
    h16x8 a[4], b[4];
    #pragma unroll
    for (int i=0;i<4;i++) a[i] = *(const h16x8*)&As[(wr*64 + i*16 + lrow)*32 + quad*8];
    #pragma unroll
    for (int j=0;j<4;j++){
      int n = wc*64 + j*16 + lrow;
      b[j] = *(const h16x8*)&Bs[n*40 + ((quad ^ ((n>>3)&3))*8)];
    }
    #pragma unroll
    for (int i=0;i<4;i++)
      #pragma unroll
      for (int j=0;j<4;j++)
        acc[i][j] = mfma16(a[i], b[j], acc[i][j]);
    __syncthreads();
  }
  #pragma unroll
  for (int i=0;i<4;i++)
    #pragma unroll
    for (int r=0;r<4;r++){
      int m = m0 + wr*64 + i*16 + quad*4 + r;
      if (m < base + cnt){
        int ts = list_ts[m];
        float wgt = list_w[m];
        #pragma unroll
        for (int j=0;j<4;j++){
          int col = n0 + wc*64 + j*16 + lrow;
          slotbuf[(size_t)ts*H_DIM + col] = (_Float16)(wgt * acc[i][j][r]);
        }
      }
    }
}

// ---------------- final residual add -> dual-dtype out ----------------
__global__ __launch_bounds__(256) void k_final(const float* __restrict__ x1, const _Float16* __restrict__ slot,
                                               void* __restrict__ outv, const int* __restrict__ df){
  const int is32 = *df;
  int i4 = (blockIdx.x*256 + threadIdx.x)*4;
  int t = i4 >> 10, c = i4 & 1023;
  f32x4 a = *(const f32x4*)&x1[i4];
  h16x4 s0 = *(const h16x4*)&slot[(size_t)(t*2)*H_DIM + c];
  h16x4 s1 = *(const h16x4*)&slot[(size_t)(t*2+1)*H_DIM + c];
  if (is32){
    f32x4 o;
    #pragma unroll
    for (int m=0;m<4;m++) o[m] = a[m] + (float)s0[m] + (float)s1[m];
    *(f32x4*)&((float*)outv)[i4] = o;
  } else {
    u16x4 o;
    #pragma unroll
    for (int m=0;m<4;m++) o[m] = f2bf(a[m] + (float)s0[m] + (float)s1[m]);
    *(u16x4*)&((u16*)outv)[i4] = o;
  }
}

extern "C" void kernel_launch(void* const* d_in, const int* in_sizes, int n_in,
                              void* d_out, int out_size, void* d_ws, size_t ws_size,
                              hipStream_t stream){
  (void)in_sizes; (void)n_in; (void)out_size;
  const void* x    = d_in[0];
  const void* mask = d_in[1];
  const void* ln1  = d_in[2];
  const void* ln2  = d_in[3];
  const void* qkvw = d_in[4];
  const void* ow   = d_in[5];
  const void* rw   = d_in[6];
  const void* guw  = d_in[7];
  const void* dww  = d_in[8];

  char* ws = (char*)d_ws;
  size_t off = 0;
  auto alloc = [&](size_t b)->void*{ void* p = ws + off; off = (off + b + 255) & ~(size_t)255; return p; };
  int* meta            = (int*)alloc(32*sizeof(int));
  _Float16* qkv_wt     = (_Float16*)alloc((size_t)3072*1024*2);
  _Float16* o_wt       = (_Float16*)alloc((size_t)1024*1024*2);
  _Float16* hpair      = (_Float16*)alloc((size_t)2*4096*1024*2);  // h hi/lo; later aout hi/lo; later slotbuf
  _Float16* qkvpair    = (_Float16*)alloc((size_t)2*4096*3072*2);  // qkv hi/lo; later h2+act
  float* x1            = (float*)alloc((size_t)4096*1024*4);       // V^T hi/lo during attn; then x1
  int* list_ts         = (int*)alloc(MAXROWS*4);
  float* list_w        = (float*)alloc(MAXROWS*4);
  int* tok_e           = (int*)alloc((size_t)4096*2*4);
  float* tok_w         = (float*)alloc((size_t)4096*2*4);
  size_t base_end = off;                                           // ~92 MB
  _Float16* gu_wt      = (_Float16*)alloc((size_t)8*4096*1024*2);  // 67 MB
  _Float16* down_wt    = (_Float16*)alloc((size_t)8*1024*2048*2);  // 34 MB
  const int big = (ws_size >= off) ? 1 : 0;                        // need ~193 MB for hot path
  (void)base_end;

  int* counts = meta;
  int* offs   = meta + 8;
  int* flag   = meta + 25;
  int* dflag  = meta + 26;

  _Float16* h_hi   = hpair;
  _Float16* h_lo   = hpair + (size_t)4096*1024;
  _Float16* qkv_hi = qkvpair;
  _Float16* qkv_lo = qkvpair + (size_t)4096*3072;
  _Float16* vth    = (_Float16*)x1;                     // 8 MB
  _Float16* vtl    = vth + (size_t)64*64*1024;          // 8 MB
  _Float16* ahi    = hpair;                             // aout hi (h dead)
  _Float16* alo    = hpair + (size_t)4096*1024;         // aout lo
  _Float16* h2     = qkvpair;                           // qkv dead after attn
  _Float16* act    = qkvpair + (size_t)4096*1024;
  _Float16* slotbuf= hpair;                             // aout dead after o-proj

  hipMemsetAsync(meta, 0, 32*sizeof(int), stream);
  k_detect<<<dim3(1), dim3(64), 0, stream>>>((const uint32_t*)x, dflag);
  k_trans2<<<dim3(48, 16, 1), 256, 0, stream>>>(qkvw, qkv_wt, 1024, 3072, dflag);
  k_trans2<<<dim3(16, 16, 1), 256, 0, stream>>>(ow, o_wt, 1024, 1024, dflag);
  if (big){
    k_trans2<<<dim3(64, 16, 8), 256, 0, stream>>>(guw, gu_wt, 1024, 4096, dflag);
    k_trans2<<<dim3(16, 32, 8), 256, 0, stream>>>(dww, down_wt, 2048, 1024, dflag);
  }
  k_maskchk<<<dim3(1024), 256, 0, stream>>>(mask, flag, dflag);
  k_rms1<<<dim3(4096), 256, 0, stream>>>(x, ln1, h_hi, h_lo, dflag);
  k_gemm_hl<0><<<dim3(24, 32), 256, 0, stream>>>(h_hi, h_lo, qkv_wt, nullptr, qkv_hi, qkv_lo,
                                                 nullptr, 3072, 1024, dflag);
  k_vt<<<dim3(16, 64), 256, 0, stream>>>(qkv_hi, qkv_lo, vth, vtl);
  k_attn<<<dim3(8, 64), 256, 0, stream>>>(qkv_hi, qkv_lo, vth, vtl, mask, flag, ahi, alo, dflag);
  k_gemm_hl<1><<<dim3(8, 32), 256, 0, stream>>>(ahi, alo, o_wt, x1, nullptr, nullptr,
                                                x, 1024, 1024, dflag);
  k_rms2_router<<<dim3(4096), 256, 0, stream>>>(x1, ln2, rw, h2, tok_e, tok_w, dflag);
  k_route<<<dim3(1), dim3(1024), 0, stream>>>(tok_e, tok_w, counts, offs, list_ts, list_w);
  if (big){
    k_gemm_gu_t<<<dim3(32, 72), 256, 0, stream>>>(h2, gu_wt, act, list_ts, counts, offs);
    k_gemm_down_t<<<dim3(8, 72), 256, 0, stream>>>(act, down_wt, slotbuf, list_ts, list_w, counts, offs);
  } else {
    k_gemm_gu<<<dim3(32, 72), 256, 0, stream>>>(h2, guw, act, list_ts, counts, offs, dflag);
    k_gemm_down<<<dim3(8, 72), 256, 0, stream>>>(act, dww, slotbuf, list_ts, list_w, counts, offs, dflag);
  }
  k_final<<<dim3(4096), 256, 0, stream>>>(x1, slotbuf, d_out, dflag);
}